// Round 9
// baseline (396.793 us; speedup 1.0000x reference)
//
#include <hip/hip_runtime.h>

#define NPIX (512*512)

typedef __attribute__((ext_vector_type(8))) short short8;   // 8 bf16 in 4 VGPRs
typedef __attribute__((ext_vector_type(4))) float f32x4;    // MFMA accumulator

#define MFMA16(A, B, C) __builtin_amdgcn_mfma_f32_16x16x32_bf16((A), (B), (C), 0, 0, 0)

// JAX gelu(approximate=True): x * sigmoid(2*sqrt(2/pi)*(x+0.044715x^3)).
// R7: exact f32 div -> v_rcp_f32 (rel-err ~2^-22 << bf16 ulp).
__device__ __forceinline__ float gelu_f(float x) {
    float z = 1.5957691216057308f * (x + 0.044715f * x * x * x);
    return x * __builtin_amdgcn_rcpf(1.0f + __expf(-z));
}

// f32 -> bf16 bits (RNE)
__device__ __forceinline__ unsigned short bf16_rne(float x) {
    unsigned int b = __float_as_uint(x);
    unsigned int r = b + 0x7fffu + ((b >> 16) & 1u);
    return (unsigned short)(r >> 16);
}
__device__ __forceinline__ float bf16_tof(unsigned short h) {
    return __uint_as_float(((unsigned int)h) << 16);
}
__device__ __forceinline__ unsigned int bf16_split_pack(float x) {
    unsigned short hi = bf16_rne(x);
    unsigned short lo = bf16_rne(x - bf16_tof(hi));
    return (unsigned int)hi | ((unsigned int)lo << 16);
}
// unzip 8 split-packed u32 (hi|lo<<16 per elem) -> hi-short8 / lo-short8
__device__ __forceinline__ void unzip8(const unsigned int* w, short8& h, short8& l) {
    union { unsigned int u[4]; short8 v; } hh, ll;
    #pragma unroll
    for (int i = 0; i < 4; ++i) {
        hh.u[i] = (w[2*i] & 0xffffu) | (w[2*i+1] << 16);
        ll.u[i] = (w[2*i] >> 16) | (w[2*i+1] & 0xffff0000u);
    }
    h = hh.v; l = ll.v;
}

#define ASLAB ((size_t)16 * 4 * 2 * 64 * 48)   // shorts per (l,ax) in Am

// Vm u32 index: [p][y>>4][m][y&15][ri]  (R1: full-128B-line single-wave stores)
#define VM_IDX(p, yT, m, yL) (((((size_t)(p) * 32 + (yT)) * 16 + (m)) * 16 + (yL)) * 2)

// ---------------------------------------------------------------------------
// Merged setup + encoder: blocks 0..15 basis tables, 16..31 FFN weights,
// 32..287 spectral A-weights, 288..1311 encoder (h stored bf16).
// ---------------------------------------------------------------------------
__global__ __launch_bounds__(256) void k_setup(const float* __restrict__ W1, const float* __restrict__ W2,
                                               const float* __restrict__ Are, const float* __restrict__ Aim,
                                               const float* __restrict__ u, const float* __restrict__ xc,
                                               const float* __restrict__ We, const float* __restrict__ be,
                                               short* __restrict__ FbB, short* __restrict__ GbF,
                                               short* __restrict__ Wpk, short* __restrict__ Am,
                                               unsigned short* __restrict__ h) {
    int b = blockIdx.x;
    int t = threadIdx.x;
    if (b < 16) {
        int id = b * 256 + t;
        int lane = id & 63;
        int quad = lane >> 4, l15 = lane & 15;
        short* dst;
        int n0, nstep, o0, ostep;
        float wscale = 1.0f;
        if (id < 2048) {
            int nt = (id >> 6) & 1, kc = id >> 7;
            dst = FbB + id * 16;
            n0 = kc * 32 + quad * 8; nstep = 1;
            o0 = nt * 16 + l15;      ostep = 0;
        } else {
            int id2 = id - 2048;
            dst = GbF + id2 * 16;
            int tt = id2 >> 6;
            n0 = tt * 16 + l15;      nstep = 0;
            o0 = quad * 8;           ostep = 1;
            wscale = 1.0f / 512.0f;
        }
        #pragma unroll
        for (int j = 0; j < 8; ++j) {
            int n = n0 + nstep * j;
            int o = o0 + ostep * j;
            int m = o >> 1, ri = o & 1;
            int k = (n * m) & 511;
            float sv, cv;
            sincosf(6.283185307179586f * (1.0f / 512.0f) * (float)k, &sv, &cv);
            float v = ri ? -sv : cv;
            if (id >= 2048) v *= (m == 0 ? 1.0f : 2.0f) * wscale;
            unsigned short hi = bf16_rne(v);
            dst[j]     = (short)hi;
            dst[8 + j] = (short)bf16_rne(v - bf16_tof(hi));
        }
    } else if (b < 32) {
        int tid = (b - 16) * 256 + t;
        int lane = tid & 63;
        int kc = (tid >> 6) & 1;
        int mt = (tid >> 7) & 3;
        int wg = tid >> 9;
        int layer = wg >> 1, which = wg & 1;
        const float* Wsrc = (which ? W2 : W1) + (size_t)layer * 4096;
        int o  = mt * 16 + (lane & 15);
        int c0 = kc * 32 + ((lane >> 4) & 3) * 8;
        short* dst = Wpk + (size_t)tid * 16;
        #pragma unroll
        for (int j = 0; j < 8; ++j) {
            float x = Wsrc[o * 64 + c0 + j];
            unsigned short hi = bf16_rne(x);
            dst[j]     = (short)hi;
            dst[8 + j] = (short)bf16_rne(x - bf16_tof(hi));
        }
    } else if (b < 288) {
        int id = (b - 32) * 256 + t;
        int lane = id & 63;
        int kc  = (id >> 6) & 1;
        int mt  = (id >> 7) & 3;
        int m   = (id >> 9) & 15;
        int lax = id >> 13;
        int l = lax >> 1, ax = lax & 1;
        int o  = mt * 16 + (lane & 15);
        int i0 = kc * 32 + ((lane >> 4) & 3) * 8;
        short* dst = Am + (size_t)id * 48;
        #pragma unroll
        for (int j = 0; j < 8; ++j) {
            size_t src = (((size_t)(l * 64 + o) * 64 + (i0 + j)) * 16 + m) * 2 + ax;
            float ar = Are[src], ai = Aim[src];
            unsigned short hh;
            hh = bf16_rne(ar);  dst[j]      = (short)hh; dst[8 + j]  = (short)bf16_rne(ar - bf16_tof(hh));
            hh = bf16_rne(ai);  dst[16 + j] = (short)hh; dst[24 + j] = (short)bf16_rne(ai - bf16_tof(hh));
            hh = bf16_rne(-ai); dst[32 + j] = (short)hh; dst[40 + j] = (short)bf16_rne(-ai - bf16_tof(hh));
        }
    } else {
        // encoder: h[p][pix] = bf16(We.x + be)
        int pix = (b - 288) * 256 + t;
        float x0 = xc[pix], x1 = xc[NPIX + pix], uu = u[pix];
        #pragma unroll 8
        for (int p = 0; p < 64; ++p) {
            float v = We[p * 3] * x0 + We[p * 3 + 1] * x1 + We[p * 3 + 2] * uu + be[p];
            h[(size_t)p * NPIX + pix] = bf16_rne(v);
        }
    }
}

// ---------------------------------------------------------------------------
// Merged forward DFT, both axes, h in bf16. grid(64 p, 8 ntile, 2 axis).
// axis1: direct short8 row reads. axis0 (R2): coalesced uint4 tile loads +
// LDS transpose. R8: axis0 DOUBLE-BUFFERED T -> ONE barrier per chunk (was
// 2): write T[ch&1], sync, compute; readers of T[(ch-2)&1] proven drained
// at the previous barrier (in-wave lgkm waits precede barrier arrival).
// ---------------------------------------------------------------------------
__global__ __launch_bounds__(256) void k_fwd(const unsigned short* __restrict__ h, const short* __restrict__ FbB,
                                             float* __restrict__ VfH, float* __restrict__ VfW) {
    __shared__ unsigned short T[2][64 * 66];  // 2 x 8448 B
    int t = threadIdx.x;
    int p = blockIdx.x, ntb = blockIdx.y, axis = blockIdx.z;
    int wv = t >> 6, lane = t & 63, quad = lane >> 4, l15 = lane & 15;
    int n = ntb * 64 + wv * 16 + l15;
    int nL = wv * 16 + l15;
    f32x4 acc[2];
    acc[0] = (f32x4){0.f,0.f,0.f,0.f}; acc[1] = (f32x4){0.f,0.f,0.f,0.f};
    if (axis == 1) {
        #pragma unroll 4
        for (int kc = 0; kc < 16; ++kc) {
            int kb = kc * 32 + quad * 8;
            const unsigned short* hp = h + ((size_t)p * 512 + n) * 512 + kb;
            short8 Bv = *(const short8*)hp;
            #pragma unroll
            for (int mt = 0; mt < 2; ++mt) {
                const short8* ap = (const short8*)(FbB + (((kc * 2 + mt) * 64 + lane) << 4));
                short8 Ah = ap[0], Al = ap[1];
                acc[mt] = MFMA16(Ah, Bv, acc[mt]);
                acc[mt] = MFMA16(Al, Bv, acc[mt]);
            }
        }
    } else {
        int kp = t >> 3, c = t & 7;          // k-pair 0..31, n-oct 0..7
        for (int ch = 0; ch < 8; ++ch) {
            int k0 = ch * 64;
            const unsigned short* r0 = h + ((size_t)p * 512 + k0 + 2 * kp) * 512 + ntb * 64 + c * 8;
            uint4 a = *(const uint4*)r0;
            uint4 bq = *(const uint4*)(r0 + 512);
            unsigned int aw[4] = {a.x, a.y, a.z, a.w};
            unsigned int bw[4] = {bq.x, bq.y, bq.z, bq.w};
            unsigned short* Tb = T[ch & 1];
            #pragma unroll
            for (int i = 0; i < 4; ++i) {
                int n0 = c * 8 + 2 * i;
                *(unsigned int*)&Tb[n0 * 66 + 2 * kp]       = (aw[i] & 0xffffu) | (bw[i] << 16);
                *(unsigned int*)&Tb[(n0 + 1) * 66 + 2 * kp] = (aw[i] >> 16) | (bw[i] & 0xffff0000u);
            }
            __syncthreads();
            #pragma unroll
            for (int kcl = 0; kcl < 2; ++kcl) {
                int kc = ch * 2 + kcl;
                union { unsigned int w[4]; short8 v; } bb;
                #pragma unroll
                for (int d = 0; d < 4; ++d)
                    bb.w[d] = *(const unsigned int*)&Tb[nL * 66 + kcl * 32 + quad * 8 + 2 * d];
                #pragma unroll
                for (int mt = 0; mt < 2; ++mt) {
                    const short8* ap = (const short8*)(FbB + (((kc * 2 + mt) * 64 + lane) << 4));
                    short8 Ah = ap[0], Al = ap[1];
                    acc[mt] = MFMA16(Ah, bb.v, acc[mt]);
                    acc[mt] = MFMA16(Al, bb.v, acc[mt]);
                }
            }
        }
    }
    float* vp = (axis ? VfW : VfH) + (size_t)p * 32 * 512;
    #pragma unroll
    for (int mt = 0; mt < 2; ++mt)
        #pragma unroll
        for (int r = 0; r < 4; ++r)
            vp[(size_t)(mt * 16 + quad * 4 + r) * 512 + n] = acc[mt][r];
}

// ---------------------------------------------------------------------------
// Merged mode mixing, both axes. Epilogue writes Vm SPLIT-PACKED u32 in the
// [p][y>>4][m][y&15][ri] layout: one 128-B contiguous line per (o,r) store.
// grid 512 (axis = bid>>8; m = bid&15, otile = (bid>>4)&15), block 256.
// ---------------------------------------------------------------------------
__global__ __launch_bounds__(256) void k_mix2(const float* __restrict__ VfH, const float* __restrict__ VfW,
                                              const short* __restrict__ AmL,
                                              unsigned int* __restrict__ VmH, unsigned int* __restrict__ VmW) {
    __shared__ unsigned int BT[2 * 64 * 33];
    int bid = blockIdx.x;
    int axis = bid >> 8;
    int m  = bid & 15;
    int ot = (bid >> 4) & 15;
    const float* Vf = axis ? VfW : VfH;
    unsigned int* Vm = axis ? VmW : VmH;
    const short* Am = AmL + (size_t)axis * ASLAB;
    int t = threadIdx.x;
    #pragma unroll
    for (int it = 0; it < 16; ++it) {
        int idx = it * 256 + t;
        int oth = idx & 31, ri = (idx >> 5) & 1, i = idx >> 6;
        float v = Vf[((size_t)i * 32 + m * 2 + ri) * 512 + ot * 32 + oth];
        BT[(ri * 64 + i) * 33 + oth] = bf16_split_pack(v);
    }
    __syncthreads();
    int wv = t >> 6, lane = t & 63, quad = lane >> 4, l15 = lane & 15;
    int nt = wv & 1, mtp = wv >> 1;
    f32x4 aR[2], aI[2];
    aR[0]=(f32x4){0.f,0.f,0.f,0.f}; aR[1]=aR[0]; aI[0]=aR[0]; aI[1]=aR[0];
    #pragma unroll
    for (int kc = 0; kc < 2; ++kc) {
        short8 Brh, Brl, Bih, Bil;
        #pragma unroll
        for (int j = 0; j < 8; ++j) {
            int i = kc * 32 + quad * 8 + j;
            unsigned int br = BT[i * 33 + nt * 16 + l15];
            unsigned int bi = BT[(64 + i) * 33 + nt * 16 + l15];
            Brh[j] = (short)(br & 0xffffu); Brl[j] = (short)(br >> 16);
            Bih[j] = (short)(bi & 0xffffu); Bil[j] = (short)(bi >> 16);
        }
        #pragma unroll
        for (int mi = 0; mi < 2; ++mi) {
            int mt = mtp * 2 + mi;
            const short8* ap = (const short8*)(Am + ((size_t)(((m * 4 + mt) * 2 + kc) * 64 + lane)) * 48);
            short8 Arh = ap[0], Arl = ap[1], Aih = ap[2], Ail = ap[3], Anh = ap[4], Anl = ap[5];
            aR[mi] = MFMA16(Arh, Brh, aR[mi]);
            aR[mi] = MFMA16(Arl, Brh, aR[mi]);
            aR[mi] = MFMA16(Arh, Brl, aR[mi]);
            aR[mi] = MFMA16(Anh, Bih, aR[mi]);
            aR[mi] = MFMA16(Anl, Bih, aR[mi]);
            aR[mi] = MFMA16(Anh, Bil, aR[mi]);
            aI[mi] = MFMA16(Arh, Bih, aI[mi]);
            aI[mi] = MFMA16(Arl, Bih, aI[mi]);
            aI[mi] = MFMA16(Arh, Bil, aI[mi]);
            aI[mi] = MFMA16(Aih, Brh, aI[mi]);
            aI[mi] = MFMA16(Ail, Brh, aI[mi]);
            aI[mi] = MFMA16(Aih, Brl, aI[mi]);
        }
    }
    int yT = ot * 2 + nt;
    #pragma unroll
    for (int mi = 0; mi < 2; ++mi) {
        int o = (mtp * 2 + mi) * 16 + quad * 4;
        #pragma unroll
        for (int r = 0; r < 4; ++r) {
            uint2 v;
            v.x = bf16_split_pack(aR[mi][r]);
            v.y = bf16_split_pack(aI[mi][r]);
            *(uint2*)(Vm + VM_IDX(o + r, yT, m, l15)) = v;
        }
    }
}

// ---------------------------------------------------------------------------
// Fused inverse DFT -> s in [pix][ch] layout (R6).
// grid(32 xt, 32 yt): block = 16x16 pixel patch x ALL 64 channels.
// Results transposed through LDS with permuted pixel index pp=(r*16+x)*4+quad
// (store banks = perm mod 32, 2-way free), drained as FULL 128-B lines.
// ---------------------------------------------------------------------------
__global__ __launch_bounds__(256) void k_inv(const unsigned int* __restrict__ VmW, const unsigned int* __restrict__ VmH,
                                             const short* __restrict__ GbF, unsigned short* __restrict__ s) {
    __shared__ unsigned short sT[256 * 66];   // [pp][ch + pad], 33792 B
    int t = threadIdx.x;
    int xt = blockIdx.x, yt = blockIdx.y;
    int wv = t >> 6, lane = t & 63, quad = lane >> 4, l15 = lane & 15;
    const short8* gy = (const short8*)(GbF + ((yt * 64 + lane) << 4));
    short8 A1h = gy[0], A1l = gy[1];
    const short8* gx = (const short8*)(GbF + ((xt * 64 + lane) << 4));
    short8 B2h = gx[0], B2l = gx[1];
    int p0 = wv * 16;
    for (int pp = 0; pp < 16; ++pp) {
        int p = p0 + pp;
        unsigned int aw[8], bw[8];
        #pragma unroll
        for (int tt = 0; tt < 4; ++tt) {
            uint2 qa = *(const uint2*)(VmW + VM_IDX(p, yt, quad * 4 + tt, l15));
            uint2 qb = *(const uint2*)(VmH + VM_IDX(p, xt, quad * 4 + tt, l15));
            aw[2*tt] = qa.x; aw[2*tt+1] = qa.y;
            bw[2*tt] = qb.x; bw[2*tt+1] = qb.y;
        }
        short8 A2h, A2l, B1h, B1l;
        unzip8(aw, A2h, A2l);
        unzip8(bw, B1h, B1l);
        f32x4 acc = (f32x4){0.f,0.f,0.f,0.f};
        acc = MFMA16(A1h, B1h, acc);
        acc = MFMA16(A1l, B1h, acc);
        acc = MFMA16(A1h, B1l, acc);
        acc = MFMA16(A2h, B2h, acc);
        acc = MFMA16(A2l, B2h, acc);
        acc = MFMA16(A2h, B2l, acc);
        #pragma unroll
        for (int r = 0; r < 4; ++r)
            sT[(((r * 16 + l15) << 2) + quad) * 66 + p] = bf16_rne(acc[r]);
    }
    __syncthreads();
    #pragma unroll
    for (int it = 0; it < 8; ++it) {
        int ppix = it * 32 + (t >> 3);
        int part = t & 7;
        const unsigned int* lp = (const unsigned int*)&sT[ppix * 66 + part * 8];
        uint4 v; v.x = lp[0]; v.y = lp[1]; v.z = lp[2]; v.w = lp[3];
        int q = ppix & 3, rx = ppix >> 2;
        int xl = rx & 15, r = rx >> 4;
        int y = yt * 16 + q * 4 + r;
        int x = xt * 16 + xl;
        *(uint4*)(s + (((size_t)y * 512 + x) << 6) + part * 8) = v;
    }
}

// ---------------------------------------------------------------------------
// MFMA FFN: h(bf16) += gelu(W2.gelu(W1.s+b1)+b2). s is [pix][ch] (R6):
// GEMM1 B-frags are DIRECT short8 global loads; no staging, no pre-GEMM
// barrier. tB own-wave rows (no barrier epi1->GEMM2); oTb aliases tB
// (barrier before epi2). (256,4): no spills. R7: rcp-gelu.
// R8: 2-TILE PIPELINE, grid 1024 (R5 technique on R6 structure): both
// tiles' B-frags issued at kernel start; tile1's loads stream under tile0's
// full compute. Inter-tile barrier placed AFTER tile1's register-only GEMM1
// so it overlaps other waves' tile0 h-writes.
// ---------------------------------------------------------------------------
union FfnSmem {
    unsigned int  tB[128 * 33];     // 16896 B, GEMM1->GEMM2 bf16 pairs
    unsigned short oTb[64 * 136];   // 17408 B, epilogue2 bf16 transpose tile
    float         red[16 * 132];    // 8448 B, decoder partial sums
};

// One 128-px FFN tile. B-frags preloaded in registers. syncBeforeEpi1: fence
// prior tile's oTb readers before overwriting tB (aliases).
template <bool SYNC_BEFORE_EPI1>
__device__ __forceinline__ void ffn_tile(FfnSmem& u, int pixBase,
        const short8* bb0, const short8* bb1,
        const short* __restrict__ w1f, const float* __restrict__ b1v,
        const short* __restrict__ w2f, const float* __restrict__ b2v,
        unsigned short* __restrict__ out, const float* __restrict__ Wd,
        const float* __restrict__ bd, float* __restrict__ dout, int last) {
    int t = threadIdx.x;
    int lane15 = t & 15;
    int quad   = (t >> 4) & 3;
    int wv     = t >> 6;
    int oct = t & 15;
    int cg  = t >> 4;

    f32x4 acc[2][4];
    #pragma unroll
    for (int ns = 0; ns < 2; ++ns)
        #pragma unroll
        for (int mt = 0; mt < 4; ++mt) acc[ns][mt] = (f32x4){0.f, 0.f, 0.f, 0.f};

    // ---- GEMM1: 2-term, weights at use (register B-frags, no LDS) ----
    #pragma unroll
    for (int kc = 0; kc < 2; ++kc) {
        #pragma unroll
        for (int mt = 0; mt < 4; ++mt) {
            int s8 = mt * 2 + kc;
            const short8* wp = (const short8*)(w1f + (((size_t)s8 * 64 + (t & 63)) << 4));
            short8 wh = wp[0], wl = wp[1];
            acc[0][mt] = MFMA16(wh, bb0[kc], acc[0][mt]);
            acc[0][mt] = MFMA16(wl, bb0[kc], acc[0][mt]);
            acc[1][mt] = MFMA16(wh, bb1[kc], acc[1][mt]);
            acc[1][mt] = MFMA16(wl, bb1[kc], acc[1][mt]);
        }
    }

    if (SYNC_BEFORE_EPI1) __syncthreads();   // prior tile's oTb readers done

    // ---- epilogue1: gelu -> bf16 pairs -> tB (own-wave rows only) ----
    #pragma unroll
    for (int ns = 0; ns < 2; ++ns) {
        int row = wv * 32 + ns * 16 + lane15;
        #pragma unroll
        for (int mt = 0; mt < 4; ++mt) {
            const float* bp = b1v + mt * 16 + quad * 4;
            float g[4];
            #pragma unroll
            for (int r = 0; r < 4; ++r) g[r] = gelu_f(acc[ns][mt][r] + bp[r]);
            int cp = (mt * 16 + quad * 4) >> 1;
            u.tB[row * 33 + cp]     = (unsigned int)bf16_rne(g[0]) | ((unsigned int)bf16_rne(g[1]) << 16);
            u.tB[row * 33 + cp + 1] = (unsigned int)bf16_rne(g[2]) | ((unsigned int)bf16_rne(g[3]) << 16);
            acc[ns][mt] = (f32x4){0.f, 0.f, 0.f, 0.f};
        }
    }

    // NO barrier: GEMM2 reads only this wave's own rows, written above.

    // ---- GEMM2: 2-term, weights at use ----
    #pragma unroll
    for (int kc = 0; kc < 2; ++kc) {
        union { unsigned int w[4]; short8 v; } cb0, cb1;
        int row0 = wv * 32 + lane15;
        int row1 = wv * 32 + 16 + lane15;
        #pragma unroll
        for (int i = 0; i < 4; ++i) {
            cb0.w[i] = u.tB[row0 * 33 + kc * 16 + quad * 4 + i];
            cb1.w[i] = u.tB[row1 * 33 + kc * 16 + quad * 4 + i];
        }
        #pragma unroll
        for (int mt = 0; mt < 4; ++mt) {
            int s8 = mt * 2 + kc;
            const short8* wp = (const short8*)(w2f + (((size_t)s8 * 64 + (t & 63)) << 4));
            short8 wh = wp[0], wl = wp[1];
            acc[0][mt] = MFMA16(wh, cb0.v, acc[0][mt]);
            acc[0][mt] = MFMA16(wl, cb0.v, acc[0][mt]);
            acc[1][mt] = MFMA16(wh, cb1.v, acc[1][mt]);
            acc[1][mt] = MFMA16(wl, cb1.v, acc[1][mt]);
        }
    }

    // ---- h residual load (latency hidden by epilogue2 VALU) ----
    uint4 hr[4];
    #pragma unroll
    for (int j = 0; j < 4; ++j) {
        int c = cg + 16 * j;
        hr[j] = *(const uint4*)(out + (size_t)c * NPIX + pixBase + oct * 8);
    }

    __syncthreads();   // all waves done reading tB; oTb scatter may begin

    // ---- epilogue2: gelu -> bf16 oTb (aliases tB) ----
    #pragma unroll
    for (int ns = 0; ns < 2; ++ns) {
        int px = wv * 32 + ns * 16 + lane15;
        #pragma unroll
        for (int mt = 0; mt < 4; ++mt) {
            const float* bp = b2v + mt * 16 + quad * 4;
            #pragma unroll
            for (int r = 0; r < 4; ++r) {
                int c = mt * 16 + quad * 4 + r;
                u.oTb[c * 136 + px] = bf16_rne(gelu_f(acc[ns][mt][r] + bp[r]));
            }
        }
    }
    __syncthreads();

    if (!last) {
        // ---- h(bf16) += increment: (c,oct) units, uint4, full 256-B sectors/wave ----
        #pragma unroll
        for (int j = 0; j < 4; ++j) {
            int c = cg + 16 * j;
            uint4 gv = *(const uint4*)&u.oTb[c * 136 + oct * 8];
            unsigned int hw[4] = {hr[j].x, hr[j].y, hr[j].z, hr[j].w};
            unsigned int gw[4] = {gv.x, gv.y, gv.z, gv.w};
            uint4 o;
            unsigned int* op = &o.x;
            #pragma unroll
            for (int i = 0; i < 4; ++i) {
                float f0 = bf16_tof((unsigned short)(hw[i] & 0xffffu)) + bf16_tof((unsigned short)(gw[i] & 0xffffu));
                float f1 = bf16_tof((unsigned short)(hw[i] >> 16))     + bf16_tof((unsigned short)(gw[i] >> 16));
                op[i] = (unsigned int)bf16_rne(f0) | ((unsigned int)bf16_rne(f1) << 16);
            }
            *(uint4*)(out + (size_t)c * NPIX + pixBase + oct * 8) = o;
        }
    } else {
        // ---- fused decoder: dout = sum_c Wd[c]*(hres+gv) + bd ----
        float part[8] = {0.f,0.f,0.f,0.f,0.f,0.f,0.f,0.f};
        #pragma unroll
        for (int j = 0; j < 4; ++j) {
            int c = cg + 16 * j;
            float wd = Wd[c];
            uint4 gv = *(const uint4*)&u.oTb[c * 136 + oct * 8];
            unsigned int hw[4] = {hr[j].x, hr[j].y, hr[j].z, hr[j].w};
            unsigned int gw[4] = {gv.x, gv.y, gv.z, gv.w};
            #pragma unroll
            for (int i = 0; i < 4; ++i) {
                part[2*i]   += wd * (bf16_tof((unsigned short)(hw[i] & 0xffffu)) + bf16_tof((unsigned short)(gw[i] & 0xffffu)));
                part[2*i+1] += wd * (bf16_tof((unsigned short)(hw[i] >> 16))     + bf16_tof((unsigned short)(gw[i] >> 16)));
            }
        }
        __syncthreads();   // oTb reads done before red (aliases buffer) is written
        #pragma unroll
        for (int i = 0; i < 8; ++i)
            u.red[cg * 132 + oct * 8 + i] = part[i];
        __syncthreads();
        if (t < 128) {
            float sum = bd[0];
            #pragma unroll
            for (int gg = 0; gg < 16; ++gg)
                sum += u.red[gg * 132 + t];
            dout[pixBase + t] = sum;
        }
        __syncthreads();   // red reads done before next tile reuses buffer
    }
}

__global__ __launch_bounds__(256, 4) void k_ffn2m(const unsigned short* __restrict__ in, unsigned short* __restrict__ out,
                                                  const short* __restrict__ w1f, const float* __restrict__ b1v,
                                                  const short* __restrict__ w2f, const float* __restrict__ b2v,
                                                  const float* __restrict__ Wd, const float* __restrict__ bd,
                                                  float* __restrict__ dout, int last) {
    __shared__ __align__(16) FfnSmem u;
    int t = threadIdx.x;
    int lane15 = t & 15;
    int quad   = (t >> 4) & 3;
    int wv     = t >> 6;
    int pb0 = blockIdx.x * 128;
    int pb1 = pb0 + 1024 * 128;

    // ---- issue BOTH tiles' GEMM1 B-frags up front (tile1's loads stream
    //      under tile0's entire compute phase) ----
    short8 b00[2], b01[2], b10[2], b11[2];
    #pragma unroll
    for (int kc = 0; kc < 2; ++kc) {
        int col = kc * 32 + quad * 8;
        b00[kc] = *(const short8*)(in + (((size_t)(pb0 + wv * 32 + lane15)) << 6) + col);
        b01[kc] = *(const short8*)(in + (((size_t)(pb0 + wv * 32 + 16 + lane15)) << 6) + col);
        b10[kc] = *(const short8*)(in + (((size_t)(pb1 + wv * 32 + lane15)) << 6) + col);
        b11[kc] = *(const short8*)(in + (((size_t)(pb1 + wv * 32 + 16 + lane15)) << 6) + col);
    }

    ffn_tile<false>(u, pb0, b00, b01, w1f, b1v, w2f, b2v, out, Wd, bd, dout, last);
    // tile1: GEMM1 is register-only; its barrier (before epi1 tB write)
    // overlaps other waves' tile0 h-writes.
    ffn_tile<true>(u, pb1, b10, b11, w1f, b1v, w2f, b2v, out, Wd, bd, dout, last);
}

extern "C" void kernel_launch(void* const* d_in, const int* in_sizes, int n_in,
                              void* d_out, int out_size, void* d_ws, size_t ws_size,
                              hipStream_t stream) {
    (void)in_sizes; (void)n_in; (void)out_size; (void)ws_size;
    const float* u   = (const float*)d_in[0];
    const float* xc  = (const float*)d_in[1];
    const float* We  = (const float*)d_in[2];
    const float* be  = (const float*)d_in[3];
    const float* W1  = (const float*)d_in[4];
    const float* b1  = (const float*)d_in[5];
    const float* W2  = (const float*)d_in[6];
    const float* b2  = (const float*)d_in[7];
    const float* Are = (const float*)d_in[8];
    const float* Aim = (const float*)d_in[9];
    const float* Wd  = (const float*)d_in[10];
    const float* bd  = (const float*)d_in[11];

    // workspace layout, ~93 MB used
    char* ws = (char*)d_ws;
    unsigned short* h = (unsigned short*)ws;                  // 32 MB (bf16) [ch][pix]
    unsigned short* s = (unsigned short*)(ws + (size_t)33554432); // 32 MB (bf16) [pix][ch]
    float* VfH = (float*)(ws + (size_t)67108864);             // 4 MB: [64][32][512]
    float* VfW = VfH + (size_t)1048576;                       // 4 MB
    unsigned int* VmH = (unsigned int*)(VfW + 1048576);       // 4 MB split-packed
    unsigned int* VmW = VmH + (size_t)1048576;                // 4 MB
    short* FbB = (short*)(VmW + 1048576);                     // 64 KB
    short* GbF = FbB + 32768;                                 // 64 KB
    short* Am  = GbF + 32768;                                 // 6 MB
    short* Wpk = Am  + (size_t)65536 * 48;                    // 128 KB

    k_setup<<<1312, 256, 0, stream>>>(W1, W2, Are, Aim, u, xc, We, be,
                                      FbB, GbF, Wpk, Am, h);

    for (int l = 0; l < 4; ++l) {
        k_fwd<<<dim3(64, 8, 2), 256, 0, stream>>>(h, FbB, VfH, VfW);
        k_mix2<<<512, 256, 0, stream>>>(VfH, VfW, Am + (size_t)(l * 2) * ASLAB, VmH, VmW);
        k_inv<<<dim3(32, 32), 256, 0, stream>>>(VmW, VmH, GbF, s);
        k_ffn2m<<<1024, 256, 0, stream>>>(s, h,
                                          Wpk + (size_t)(l * 2 + 0) * 8192, b1 + (size_t)l * 64,
                                          Wpk + (size_t)(l * 2 + 1) * 8192, b2 + (size_t)l * 64,
                                          Wd, bd, (float*)d_out, (l == 3) ? 1 : 0);
    }
}

// Round 10
// 387.587 us; speedup vs baseline: 1.0238x; 1.0238x over previous
//
#include <hip/hip_runtime.h>

#define NPIX (512*512)

typedef __attribute__((ext_vector_type(8))) short short8;   // 8 bf16 in 4 VGPRs
typedef __attribute__((ext_vector_type(4))) float f32x4;    // MFMA accumulator

#define MFMA16(A, B, C) __builtin_amdgcn_mfma_f32_16x16x32_bf16((A), (B), (C), 0, 0, 0)

// JAX gelu(approximate=True): x * sigmoid(2*sqrt(2/pi)*(x+0.044715x^3)).
// R7: exact f32 div -> v_rcp_f32 (rel-err ~2^-22 << bf16 ulp).
__device__ __forceinline__ float gelu_f(float x) {
    float z = 1.5957691216057308f * (x + 0.044715f * x * x * x);
    return x * __builtin_amdgcn_rcpf(1.0f + __expf(-z));
}

// f32 -> bf16 bits (RNE)
__device__ __forceinline__ unsigned short bf16_rne(float x) {
    unsigned int b = __float_as_uint(x);
    unsigned int r = b + 0x7fffu + ((b >> 16) & 1u);
    return (unsigned short)(r >> 16);
}
__device__ __forceinline__ float bf16_tof(unsigned short h) {
    return __uint_as_float(((unsigned int)h) << 16);
}
__device__ __forceinline__ unsigned int bf16_split_pack(float x) {
    unsigned short hi = bf16_rne(x);
    unsigned short lo = bf16_rne(x - bf16_tof(hi));
    return (unsigned int)hi | ((unsigned int)lo << 16);
}
// unzip 8 split-packed u32 (hi|lo<<16 per elem) -> hi-short8 / lo-short8
__device__ __forceinline__ void unzip8(const unsigned int* w, short8& h, short8& l) {
    union { unsigned int u[4]; short8 v; } hh, ll;
    #pragma unroll
    for (int i = 0; i < 4; ++i) {
        hh.u[i] = (w[2*i] & 0xffffu) | (w[2*i+1] << 16);
        ll.u[i] = (w[2*i] >> 16) | (w[2*i+1] & 0xffff0000u);
    }
    h = hh.v; l = ll.v;
}

#define ASLAB ((size_t)16 * 4 * 2 * 64 * 48)   // shorts per (l,ax) in Am

// Vm u32 index: [p][y>>4][m][y&15][ri]  (R1: full-128B-line single-wave stores)
#define VM_IDX(p, yT, m, yL) (((((size_t)(p) * 32 + (yT)) * 16 + (m)) * 16 + (yL)) * 2)

// ---------------------------------------------------------------------------
// Merged setup + encoder: blocks 0..15 basis tables, 16..31 FFN weights,
// 32..287 spectral A-weights, 288..1311 encoder (h stored bf16).
// ---------------------------------------------------------------------------
__global__ __launch_bounds__(256) void k_setup(const float* __restrict__ W1, const float* __restrict__ W2,
                                               const float* __restrict__ Are, const float* __restrict__ Aim,
                                               const float* __restrict__ u, const float* __restrict__ xc,
                                               const float* __restrict__ We, const float* __restrict__ be,
                                               short* __restrict__ FbB, short* __restrict__ GbF,
                                               short* __restrict__ Wpk, short* __restrict__ Am,
                                               unsigned short* __restrict__ h) {
    int b = blockIdx.x;
    int t = threadIdx.x;
    if (b < 16) {
        int id = b * 256 + t;
        int lane = id & 63;
        int quad = lane >> 4, l15 = lane & 15;
        short* dst;
        int n0, nstep, o0, ostep;
        float wscale = 1.0f;
        if (id < 2048) {
            int nt = (id >> 6) & 1, kc = id >> 7;
            dst = FbB + id * 16;
            n0 = kc * 32 + quad * 8; nstep = 1;
            o0 = nt * 16 + l15;      ostep = 0;
        } else {
            int id2 = id - 2048;
            dst = GbF + id2 * 16;
            int tt = id2 >> 6;
            n0 = tt * 16 + l15;      nstep = 0;
            o0 = quad * 8;           ostep = 1;
            wscale = 1.0f / 512.0f;
        }
        #pragma unroll
        for (int j = 0; j < 8; ++j) {
            int n = n0 + nstep * j;
            int o = o0 + ostep * j;
            int m = o >> 1, ri = o & 1;
            int k = (n * m) & 511;
            float sv, cv;
            sincosf(6.283185307179586f * (1.0f / 512.0f) * (float)k, &sv, &cv);
            float v = ri ? -sv : cv;
            if (id >= 2048) v *= (m == 0 ? 1.0f : 2.0f) * wscale;
            unsigned short hi = bf16_rne(v);
            dst[j]     = (short)hi;
            dst[8 + j] = (short)bf16_rne(v - bf16_tof(hi));
        }
    } else if (b < 32) {
        int tid = (b - 16) * 256 + t;
        int lane = tid & 63;
        int kc = (tid >> 6) & 1;
        int mt = (tid >> 7) & 3;
        int wg = tid >> 9;
        int layer = wg >> 1, which = wg & 1;
        const float* Wsrc = (which ? W2 : W1) + (size_t)layer * 4096;
        int o  = mt * 16 + (lane & 15);
        int c0 = kc * 32 + ((lane >> 4) & 3) * 8;
        short* dst = Wpk + (size_t)tid * 16;
        #pragma unroll
        for (int j = 0; j < 8; ++j) {
            float x = Wsrc[o * 64 + c0 + j];
            unsigned short hi = bf16_rne(x);
            dst[j]     = (short)hi;
            dst[8 + j] = (short)bf16_rne(x - bf16_tof(hi));
        }
    } else if (b < 288) {
        int id = (b - 32) * 256 + t;
        int lane = id & 63;
        int kc  = (id >> 6) & 1;
        int mt  = (id >> 7) & 3;
        int m   = (id >> 9) & 15;
        int lax = id >> 13;
        int l = lax >> 1, ax = lax & 1;
        int o  = mt * 16 + (lane & 15);
        int i0 = kc * 32 + ((lane >> 4) & 3) * 8;
        short* dst = Am + (size_t)id * 48;
        #pragma unroll
        for (int j = 0; j < 8; ++j) {
            size_t src = (((size_t)(l * 64 + o) * 64 + (i0 + j)) * 16 + m) * 2 + ax;
            float ar = Are[src], ai = Aim[src];
            unsigned short hh;
            hh = bf16_rne(ar);  dst[j]      = (short)hh; dst[8 + j]  = (short)bf16_rne(ar - bf16_tof(hh));
            hh = bf16_rne(ai);  dst[16 + j] = (short)hh; dst[24 + j] = (short)bf16_rne(ai - bf16_tof(hh));
            hh = bf16_rne(-ai); dst[32 + j] = (short)hh; dst[40 + j] = (short)bf16_rne(-ai - bf16_tof(hh));
        }
    } else {
        // encoder: h[p][pix] = bf16(We.x + be)
        int pix = (b - 288) * 256 + t;
        float x0 = xc[pix], x1 = xc[NPIX + pix], uu = u[pix];
        #pragma unroll 8
        for (int p = 0; p < 64; ++p) {
            float v = We[p * 3] * x0 + We[p * 3 + 1] * x1 + We[p * 3 + 2] * uu + be[p];
            h[(size_t)p * NPIX + pix] = bf16_rne(v);
        }
    }
}

// ---------------------------------------------------------------------------
// Merged forward DFT, both axes, h in bf16. grid(64 p, 8 ntile, 2 axis).
// axis1: direct short8 row reads. axis0 (R2): coalesced uint4 tile loads +
// LDS transpose. R8 (kept in R9): axis0 double-buffered T -> ONE barrier per
// chunk; readers of T[(ch-2)&1] proven drained at the previous barrier.
// ---------------------------------------------------------------------------
__global__ __launch_bounds__(256) void k_fwd(const unsigned short* __restrict__ h, const short* __restrict__ FbB,
                                             float* __restrict__ VfH, float* __restrict__ VfW) {
    __shared__ unsigned short T[2][64 * 66];  // 2 x 8448 B
    int t = threadIdx.x;
    int p = blockIdx.x, ntb = blockIdx.y, axis = blockIdx.z;
    int wv = t >> 6, lane = t & 63, quad = lane >> 4, l15 = lane & 15;
    int n = ntb * 64 + wv * 16 + l15;
    int nL = wv * 16 + l15;
    f32x4 acc[2];
    acc[0] = (f32x4){0.f,0.f,0.f,0.f}; acc[1] = (f32x4){0.f,0.f,0.f,0.f};
    if (axis == 1) {
        #pragma unroll 4
        for (int kc = 0; kc < 16; ++kc) {
            int kb = kc * 32 + quad * 8;
            const unsigned short* hp = h + ((size_t)p * 512 + n) * 512 + kb;
            short8 Bv = *(const short8*)hp;
            #pragma unroll
            for (int mt = 0; mt < 2; ++mt) {
                const short8* ap = (const short8*)(FbB + (((kc * 2 + mt) * 64 + lane) << 4));
                short8 Ah = ap[0], Al = ap[1];
                acc[mt] = MFMA16(Ah, Bv, acc[mt]);
                acc[mt] = MFMA16(Al, Bv, acc[mt]);
            }
        }
    } else {
        int kp = t >> 3, c = t & 7;          // k-pair 0..31, n-oct 0..7
        for (int ch = 0; ch < 8; ++ch) {
            int k0 = ch * 64;
            const unsigned short* r0 = h + ((size_t)p * 512 + k0 + 2 * kp) * 512 + ntb * 64 + c * 8;
            uint4 a = *(const uint4*)r0;
            uint4 bq = *(const uint4*)(r0 + 512);
            unsigned int aw[4] = {a.x, a.y, a.z, a.w};
            unsigned int bw[4] = {bq.x, bq.y, bq.z, bq.w};
            unsigned short* Tb = T[ch & 1];
            #pragma unroll
            for (int i = 0; i < 4; ++i) {
                int n0 = c * 8 + 2 * i;
                *(unsigned int*)&Tb[n0 * 66 + 2 * kp]       = (aw[i] & 0xffffu) | (bw[i] << 16);
                *(unsigned int*)&Tb[(n0 + 1) * 66 + 2 * kp] = (aw[i] >> 16) | (bw[i] & 0xffff0000u);
            }
            __syncthreads();
            #pragma unroll
            for (int kcl = 0; kcl < 2; ++kcl) {
                int kc = ch * 2 + kcl;
                union { unsigned int w[4]; short8 v; } bb;
                #pragma unroll
                for (int d = 0; d < 4; ++d)
                    bb.w[d] = *(const unsigned int*)&Tb[nL * 66 + kcl * 32 + quad * 8 + 2 * d];
                #pragma unroll
                for (int mt = 0; mt < 2; ++mt) {
                    const short8* ap = (const short8*)(FbB + (((kc * 2 + mt) * 64 + lane) << 4));
                    short8 Ah = ap[0], Al = ap[1];
                    acc[mt] = MFMA16(Ah, bb.v, acc[mt]);
                    acc[mt] = MFMA16(Al, bb.v, acc[mt]);
                }
            }
        }
    }
    float* vp = (axis ? VfW : VfH) + (size_t)p * 32 * 512;
    #pragma unroll
    for (int mt = 0; mt < 2; ++mt)
        #pragma unroll
        for (int r = 0; r < 4; ++r)
            vp[(size_t)(mt * 16 + quad * 4 + r) * 512 + n] = acc[mt][r];
}

// ---------------------------------------------------------------------------
// Merged mode mixing, both axes. Epilogue writes Vm SPLIT-PACKED u32 in the
// [p][y>>4][m][y&15][ri] layout: one 128-B contiguous line per (o,r) store.
// grid 512 (axis = bid>>8; m = bid&15, otile = (bid>>4)&15), block 256.
// ---------------------------------------------------------------------------
__global__ __launch_bounds__(256) void k_mix2(const float* __restrict__ VfH, const float* __restrict__ VfW,
                                              const short* __restrict__ AmL,
                                              unsigned int* __restrict__ VmH, unsigned int* __restrict__ VmW) {
    __shared__ unsigned int BT[2 * 64 * 33];
    int bid = blockIdx.x;
    int axis = bid >> 8;
    int m  = bid & 15;
    int ot = (bid >> 4) & 15;
    const float* Vf = axis ? VfW : VfH;
    unsigned int* Vm = axis ? VmW : VmH;
    const short* Am = AmL + (size_t)axis * ASLAB;
    int t = threadIdx.x;
    #pragma unroll
    for (int it = 0; it < 16; ++it) {
        int idx = it * 256 + t;
        int oth = idx & 31, ri = (idx >> 5) & 1, i = idx >> 6;
        float v = Vf[((size_t)i * 32 + m * 2 + ri) * 512 + ot * 32 + oth];
        BT[(ri * 64 + i) * 33 + oth] = bf16_split_pack(v);
    }
    __syncthreads();
    int wv = t >> 6, lane = t & 63, quad = lane >> 4, l15 = lane & 15;
    int nt = wv & 1, mtp = wv >> 1;
    f32x4 aR[2], aI[2];
    aR[0]=(f32x4){0.f,0.f,0.f,0.f}; aR[1]=aR[0]; aI[0]=aR[0]; aI[1]=aR[0];
    #pragma unroll
    for (int kc = 0; kc < 2; ++kc) {
        short8 Brh, Brl, Bih, Bil;
        #pragma unroll
        for (int j = 0; j < 8; ++j) {
            int i = kc * 32 + quad * 8 + j;
            unsigned int br = BT[i * 33 + nt * 16 + l15];
            unsigned int bi = BT[(64 + i) * 33 + nt * 16 + l15];
            Brh[j] = (short)(br & 0xffffu); Brl[j] = (short)(br >> 16);
            Bih[j] = (short)(bi & 0xffffu); Bil[j] = (short)(bi >> 16);
        }
        #pragma unroll
        for (int mi = 0; mi < 2; ++mi) {
            int mt = mtp * 2 + mi;
            const short8* ap = (const short8*)(Am + ((size_t)(((m * 4 + mt) * 2 + kc) * 64 + lane)) * 48);
            short8 Arh = ap[0], Arl = ap[1], Aih = ap[2], Ail = ap[3], Anh = ap[4], Anl = ap[5];
            aR[mi] = MFMA16(Arh, Brh, aR[mi]);
            aR[mi] = MFMA16(Arl, Brh, aR[mi]);
            aR[mi] = MFMA16(Arh, Brl, aR[mi]);
            aR[mi] = MFMA16(Anh, Bih, aR[mi]);
            aR[mi] = MFMA16(Anl, Bih, aR[mi]);
            aR[mi] = MFMA16(Anh, Bil, aR[mi]);
            aI[mi] = MFMA16(Arh, Bih, aI[mi]);
            aI[mi] = MFMA16(Arl, Bih, aI[mi]);
            aI[mi] = MFMA16(Arh, Bil, aI[mi]);
            aI[mi] = MFMA16(Aih, Brh, aI[mi]);
            aI[mi] = MFMA16(Ail, Brh, aI[mi]);
            aI[mi] = MFMA16(Aih, Brl, aI[mi]);
        }
    }
    int yT = ot * 2 + nt;
    #pragma unroll
    for (int mi = 0; mi < 2; ++mi) {
        int o = (mtp * 2 + mi) * 16 + quad * 4;
        #pragma unroll
        for (int r = 0; r < 4; ++r) {
            uint2 v;
            v.x = bf16_split_pack(aR[mi][r]);
            v.y = bf16_split_pack(aI[mi][r]);
            *(uint2*)(Vm + VM_IDX(o + r, yT, m, l15)) = v;
        }
    }
}

// ---------------------------------------------------------------------------
// Fused inverse DFT -> s in [pix][ch] layout (R6).
// grid(32 xt, 32 yt): block = 16x16 pixel patch x ALL 64 channels.
// Results transposed through LDS with permuted pixel index pp=(r*16+x)*4+quad
// (store banks = perm mod 32, 2-way free), drained as FULL 128-B lines.
// ---------------------------------------------------------------------------
__global__ __launch_bounds__(256) void k_inv(const unsigned int* __restrict__ VmW, const unsigned int* __restrict__ VmH,
                                             const short* __restrict__ GbF, unsigned short* __restrict__ s) {
    __shared__ unsigned short sT[256 * 66];   // [pp][ch + pad], 33792 B
    int t = threadIdx.x;
    int xt = blockIdx.x, yt = blockIdx.y;
    int wv = t >> 6, lane = t & 63, quad = lane >> 4, l15 = lane & 15;
    const short8* gy = (const short8*)(GbF + ((yt * 64 + lane) << 4));
    short8 A1h = gy[0], A1l = gy[1];
    const short8* gx = (const short8*)(GbF + ((xt * 64 + lane) << 4));
    short8 B2h = gx[0], B2l = gx[1];
    int p0 = wv * 16;
    for (int pp = 0; pp < 16; ++pp) {
        int p = p0 + pp;
        unsigned int aw[8], bw[8];
        #pragma unroll
        for (int tt = 0; tt < 4; ++tt) {
            uint2 qa = *(const uint2*)(VmW + VM_IDX(p, yt, quad * 4 + tt, l15));
            uint2 qb = *(const uint2*)(VmH + VM_IDX(p, xt, quad * 4 + tt, l15));
            aw[2*tt] = qa.x; aw[2*tt+1] = qa.y;
            bw[2*tt] = qb.x; bw[2*tt+1] = qb.y;
        }
        short8 A2h, A2l, B1h, B1l;
        unzip8(aw, A2h, A2l);
        unzip8(bw, B1h, B1l);
        f32x4 acc = (f32x4){0.f,0.f,0.f,0.f};
        acc = MFMA16(A1h, B1h, acc);
        acc = MFMA16(A1l, B1h, acc);
        acc = MFMA16(A1h, B1l, acc);
        acc = MFMA16(A2h, B2h, acc);
        acc = MFMA16(A2l, B2h, acc);
        acc = MFMA16(A2h, B2l, acc);
        #pragma unroll
        for (int r = 0; r < 4; ++r)
            sT[(((r * 16 + l15) << 2) + quad) * 66 + p] = bf16_rne(acc[r]);
    }
    __syncthreads();
    #pragma unroll
    for (int it = 0; it < 8; ++it) {
        int ppix = it * 32 + (t >> 3);
        int part = t & 7;
        const unsigned int* lp = (const unsigned int*)&sT[ppix * 66 + part * 8];
        uint4 v; v.x = lp[0]; v.y = lp[1]; v.z = lp[2]; v.w = lp[3];
        int q = ppix & 3, rx = ppix >> 2;
        int xl = rx & 15, r = rx >> 4;
        int y = yt * 16 + q * 4 + r;
        int x = xt * 16 + xl;
        *(uint4*)(s + (((size_t)y * 512 + x) << 6) + part * 8) = v;
    }
}

// ---------------------------------------------------------------------------
// MFMA FFN, 128-px tile (grid 2048): h(bf16) += gelu(W2.gelu(W1.s+b1)+b2).
// R9: REVERTED to R7 single-tile form. R8's explicit 2-tile pipeline
// regressed ~10-13 µs normalized: R6's staging-free structure has NO
// pre-GEMM barrier, so waves already drift/overlap implicitly; R8 only
// added +32 VGPR held across a tile + 2 extra barriers.
// s is [pix][ch]: GEMM1 B-frags direct short8 global loads. tB own-wave
// rows (no barrier epi1->GEMM2); oTb aliases tB (barrier before epi2).
// (256,4): ~52 VGPR, no spills. rcp-gelu (R7).
// ---------------------------------------------------------------------------
union FfnSmem {
    unsigned int  tB[128 * 33];     // 16896 B, GEMM1->GEMM2 bf16 pairs
    unsigned short oTb[64 * 136];   // 17408 B, epilogue2 bf16 transpose tile
    float         red[16 * 132];    // 8448 B, decoder partial sums
};

__global__ __launch_bounds__(256, 4) void k_ffn2m(const unsigned short* __restrict__ in, unsigned short* __restrict__ out,
                                                  const short* __restrict__ w1f, const float* __restrict__ b1v,
                                                  const short* __restrict__ w2f, const float* __restrict__ b2v,
                                                  const float* __restrict__ Wd, const float* __restrict__ bd,
                                                  float* __restrict__ dout, int last) {
    __shared__ __align__(16) FfnSmem u;
    int t = threadIdx.x;
    int pixBase = blockIdx.x * 128;
    int lane15 = t & 15;
    int quad   = (t >> 4) & 3;
    int wv     = t >> 6;
    int oct = t & 15;                          // store pixel oct 0..15
    int cg  = t >> 4;                          // store channel group 0..15

    // ---- GEMM1 B-fragments straight from global s[pix][ch] ----
    short8 bb0[2], bb1[2];
    #pragma unroll
    for (int kc = 0; kc < 2; ++kc) {
        int col = kc * 32 + quad * 8;
        bb0[kc] = *(const short8*)(in + (((size_t)(pixBase + wv * 32 + lane15)) << 6) + col);
        bb1[kc] = *(const short8*)(in + (((size_t)(pixBase + wv * 32 + 16 + lane15)) << 6) + col);
    }

    f32x4 acc[2][4];
    #pragma unroll
    for (int ns = 0; ns < 2; ++ns)
        #pragma unroll
        for (int mt = 0; mt < 4; ++mt) acc[ns][mt] = (f32x4){0.f, 0.f, 0.f, 0.f};

    // ---- GEMM1: 2-term, weights at use ----
    #pragma unroll
    for (int kc = 0; kc < 2; ++kc) {
        #pragma unroll
        for (int mt = 0; mt < 4; ++mt) {
            int s8 = mt * 2 + kc;
            const short8* wp = (const short8*)(w1f + (((size_t)s8 * 64 + (t & 63)) << 4));
            short8 wh = wp[0], wl = wp[1];
            acc[0][mt] = MFMA16(wh, bb0[kc], acc[0][mt]);
            acc[0][mt] = MFMA16(wl, bb0[kc], acc[0][mt]);
            acc[1][mt] = MFMA16(wh, bb1[kc], acc[1][mt]);
            acc[1][mt] = MFMA16(wl, bb1[kc], acc[1][mt]);
        }
    }

    // ---- epilogue1: gelu -> bf16 pairs -> tB (own-wave rows only) ----
    #pragma unroll
    for (int ns = 0; ns < 2; ++ns) {
        int row = wv * 32 + ns * 16 + lane15;
        #pragma unroll
        for (int mt = 0; mt < 4; ++mt) {
            const float* bp = b1v + mt * 16 + quad * 4;
            float g[4];
            #pragma unroll
            for (int r = 0; r < 4; ++r) g[r] = gelu_f(acc[ns][mt][r] + bp[r]);
            int cp = (mt * 16 + quad * 4) >> 1;
            u.tB[row * 33 + cp]     = (unsigned int)bf16_rne(g[0]) | ((unsigned int)bf16_rne(g[1]) << 16);
            u.tB[row * 33 + cp + 1] = (unsigned int)bf16_rne(g[2]) | ((unsigned int)bf16_rne(g[3]) << 16);
            acc[ns][mt] = (f32x4){0.f, 0.f, 0.f, 0.f};
        }
    }

    // NO barrier: GEMM2 reads only this wave's own rows, written above.

    // ---- GEMM2: 2-term, weights at use ----
    #pragma unroll
    for (int kc = 0; kc < 2; ++kc) {
        union { unsigned int w[4]; short8 v; } cb0, cb1;
        int row0 = wv * 32 + lane15;
        int row1 = wv * 32 + 16 + lane15;
        #pragma unroll
        for (int i = 0; i < 4; ++i) {
            cb0.w[i] = u.tB[row0 * 33 + kc * 16 + quad * 4 + i];
            cb1.w[i] = u.tB[row1 * 33 + kc * 16 + quad * 4 + i];
        }
        #pragma unroll
        for (int mt = 0; mt < 4; ++mt) {
            int s8 = mt * 2 + kc;
            const short8* wp = (const short8*)(w2f + (((size_t)s8 * 64 + (t & 63)) << 4));
            short8 wh = wp[0], wl = wp[1];
            acc[0][mt] = MFMA16(wh, cb0.v, acc[0][mt]);
            acc[0][mt] = MFMA16(wl, cb0.v, acc[0][mt]);
            acc[1][mt] = MFMA16(wh, cb1.v, acc[1][mt]);
            acc[1][mt] = MFMA16(wl, cb1.v, acc[1][mt]);
        }
    }

    // ---- h residual load (latency hidden by epilogue2 VALU) ----
    uint4 hr[4];
    #pragma unroll
    for (int j = 0; j < 4; ++j) {
        int c = cg + 16 * j;
        hr[j] = *(const uint4*)(out + (size_t)c * NPIX + pixBase + oct * 8);
    }

    __syncthreads();   // all waves done reading tB; oTb scatter may begin

    // ---- epilogue2: gelu -> bf16 oTb (aliases tB) ----
    #pragma unroll
    for (int ns = 0; ns < 2; ++ns) {
        int px = wv * 32 + ns * 16 + lane15;
        #pragma unroll
        for (int mt = 0; mt < 4; ++mt) {
            const float* bp = b2v + mt * 16 + quad * 4;
            #pragma unroll
            for (int r = 0; r < 4; ++r) {
                int c = mt * 16 + quad * 4 + r;
                u.oTb[c * 136 + px] = bf16_rne(gelu_f(acc[ns][mt][r] + bp[r]));
            }
        }
    }
    __syncthreads();

    if (!last) {
        // ---- h(bf16) += increment: (c,oct) units, uint4, full 256-B sectors/wave ----
        #pragma unroll
        for (int j = 0; j < 4; ++j) {
            int c = cg + 16 * j;
            uint4 gv = *(const uint4*)&u.oTb[c * 136 + oct * 8];
            unsigned int hw[4] = {hr[j].x, hr[j].y, hr[j].z, hr[j].w};
            unsigned int gw[4] = {gv.x, gv.y, gv.z, gv.w};
            uint4 o;
            unsigned int* op = &o.x;
            #pragma unroll
            for (int i = 0; i < 4; ++i) {
                float f0 = bf16_tof((unsigned short)(hw[i] & 0xffffu)) + bf16_tof((unsigned short)(gw[i] & 0xffffu));
                float f1 = bf16_tof((unsigned short)(hw[i] >> 16))     + bf16_tof((unsigned short)(gw[i] >> 16));
                op[i] = (unsigned int)bf16_rne(f0) | ((unsigned int)bf16_rne(f1) << 16);
            }
            *(uint4*)(out + (size_t)c * NPIX + pixBase + oct * 8) = o;
        }
    } else {
        // ---- fused decoder: dout = sum_c Wd[c]*(hres+gv) + bd ----
        float part[8] = {0.f,0.f,0.f,0.f,0.f,0.f,0.f,0.f};
        #pragma unroll
        for (int j = 0; j < 4; ++j) {
            int c = cg + 16 * j;
            float wd = Wd[c];
            uint4 gv = *(const uint4*)&u.oTb[c * 136 + oct * 8];
            unsigned int hw[4] = {hr[j].x, hr[j].y, hr[j].z, hr[j].w};
            unsigned int gw[4] = {gv.x, gv.y, gv.z, gv.w};
            #pragma unroll
            for (int i = 0; i < 4; ++i) {
                part[2*i]   += wd * (bf16_tof((unsigned short)(hw[i] & 0xffffu)) + bf16_tof((unsigned short)(gw[i] & 0xffffu)));
                part[2*i+1] += wd * (bf16_tof((unsigned short)(hw[i] >> 16))     + bf16_tof((unsigned short)(gw[i] >> 16)));
            }
        }
        __syncthreads();   // oTb reads done before red (aliases buffer) is written
        #pragma unroll
        for (int i = 0; i < 8; ++i)
            u.red[cg * 132 + oct * 8 + i] = part[i];
        __syncthreads();
        if (t < 128) {
            float sum = bd[0];
            #pragma unroll
            for (int gg = 0; gg < 16; ++gg)
                sum += u.red[gg * 132 + t];
            dout[pixBase + t] = sum;
        }
    }
}

extern "C" void kernel_launch(void* const* d_in, const int* in_sizes, int n_in,
                              void* d_out, int out_size, void* d_ws, size_t ws_size,
                              hipStream_t stream) {
    (void)in_sizes; (void)n_in; (void)out_size; (void)ws_size;
    const float* u   = (const float*)d_in[0];
    const float* xc  = (const float*)d_in[1];
    const float* We  = (const float*)d_in[2];
    const float* be  = (const float*)d_in[3];
    const float* W1  = (const float*)d_in[4];
    const float* b1  = (const float*)d_in[5];
    const float* W2  = (const float*)d_in[6];
    const float* b2  = (const float*)d_in[7];
    const float* Are = (const float*)d_in[8];
    const float* Aim = (const float*)d_in[9];
    const float* Wd  = (const float*)d_in[10];
    const float* bd  = (const float*)d_in[11];

    // workspace layout, ~93 MB used
    char* ws = (char*)d_ws;
    unsigned short* h = (unsigned short*)ws;                  // 32 MB (bf16) [ch][pix]
    unsigned short* s = (unsigned short*)(ws + (size_t)33554432); // 32 MB (bf16) [pix][ch]
    float* VfH = (float*)(ws + (size_t)67108864);             // 4 MB: [64][32][512]
    float* VfW = VfH + (size_t)1048576;                       // 4 MB
    unsigned int* VmH = (unsigned int*)(VfW + 1048576);       // 4 MB split-packed
    unsigned int* VmW = VmH + (size_t)1048576;                // 4 MB
    short* FbB = (short*)(VmW + 1048576);                     // 64 KB
    short* GbF = FbB + 32768;                                 // 64 KB
    short* Am  = GbF + 32768;                                 // 6 MB
    short* Wpk = Am  + (size_t)65536 * 48;                    // 128 KB

    k_setup<<<1312, 256, 0, stream>>>(W1, W2, Are, Aim, u, xc, We, be,
                                      FbB, GbF, Wpk, Am, h);

    for (int l = 0; l < 4; ++l) {
        k_fwd<<<dim3(64, 8, 2), 256, 0, stream>>>(h, FbB, VfH, VfW);
        k_mix2<<<512, 256, 0, stream>>>(VfH, VfW, Am + (size_t)(l * 2) * ASLAB, VmH, VmW);
        k_inv<<<dim3(32, 32), 256, 0, stream>>>(VmW, VmH, GbF, s);
        k_ffn2m<<<2048, 256, 0, stream>>>(s, h,
                                          Wpk + (size_t)(l * 2 + 0) * 8192, b1 + (size_t)l * 64,
                                          Wpk + (size_t)(l * 2 + 1) * 8192, b2 + (size_t)l * 64,
                                          Wd, bd, (float*)d_out, (l == 3) ? 1 : 0);
    }
}

// Round 12
// 383.526 us; speedup vs baseline: 1.0346x; 1.0106x over previous
//
#include <hip/hip_runtime.h>

#define NPIX (512*512)

typedef __attribute__((ext_vector_type(8))) short short8;   // 8 bf16 in 4 VGPRs
typedef __attribute__((ext_vector_type(4))) float f32x4;    // MFMA accumulator

#define MFMA16(A, B, C) __builtin_amdgcn_mfma_f32_16x16x32_bf16((A), (B), (C), 0, 0, 0)

// JAX gelu(approximate=True): x * sigmoid(2*sqrt(2/pi)*(x+0.044715x^3)).
// R7: exact f32 div -> v_rcp_f32 (rel-err ~2^-22 << bf16 ulp).
__device__ __forceinline__ float gelu_f(float x) {
    float z = 1.5957691216057308f * (x + 0.044715f * x * x * x);
    return x * __builtin_amdgcn_rcpf(1.0f + __expf(-z));
}

// f32 -> bf16 bits (RNE)
__device__ __forceinline__ unsigned short bf16_rne(float x) {
    unsigned int b = __float_as_uint(x);
    unsigned int r = b + 0x7fffu + ((b >> 16) & 1u);
    return (unsigned short)(r >> 16);
}
__device__ __forceinline__ float bf16_tof(unsigned short h) {
    return __uint_as_float(((unsigned int)h) << 16);
}
// R10: packed 2xf32 -> 2xbf16 (RNE) in ONE VALU op. D[15:0]=bf16(lo),
// D[31:16]=bf16(hi). No builtin on gfx950 -> inline asm (T12 recipe).
__device__ __forceinline__ unsigned int cvt_pk_bf16(float lo, float hi) {
    unsigned int r;
    asm("v_cvt_pk_bf16_f32 %0, %1, %2" : "=v"(r) : "v"(lo), "v"(hi));
    return r;
}
__device__ __forceinline__ unsigned int bf16_split_pack(float x) {
    unsigned short hi = bf16_rne(x);
    unsigned short lo = bf16_rne(x - bf16_tof(hi));
    return (unsigned int)hi | ((unsigned int)lo << 16);
}
// unzip 8 split-packed u32 (hi|lo<<16 per elem) -> hi-short8 / lo-short8
__device__ __forceinline__ void unzip8(const unsigned int* w, short8& h, short8& l) {
    union { unsigned int u[4]; short8 v; } hh, ll;
    #pragma unroll
    for (int i = 0; i < 4; ++i) {
        hh.u[i] = (w[2*i] & 0xffffu) | (w[2*i+1] << 16);
        ll.u[i] = (w[2*i] >> 16) | (w[2*i+1] & 0xffff0000u);
    }
    h = hh.v; l = ll.v;
}

#define ASLAB ((size_t)16 * 4 * 2 * 64 * 48)   // shorts per (l,ax) in Am

// Vm u32 index: [p][y>>4][m][y&15][ri]  (R1: full-128B-line single-wave stores)
#define VM_IDX(p, yT, m, yL) (((((size_t)(p) * 32 + (yT)) * 16 + (m)) * 16 + (yL)) * 2)

// ---------------------------------------------------------------------------
// Merged setup + encoder: blocks 0..15 basis tables, 16..31 FFN weights,
// 32..287 spectral A-weights, 288..1311 encoder (h stored bf16).
// ---------------------------------------------------------------------------
__global__ __launch_bounds__(256) void k_setup(const float* __restrict__ W1, const float* __restrict__ W2,
                                               const float* __restrict__ Are, const float* __restrict__ Aim,
                                               const float* __restrict__ u, const float* __restrict__ xc,
                                               const float* __restrict__ We, const float* __restrict__ be,
                                               short* __restrict__ FbB, short* __restrict__ GbF,
                                               short* __restrict__ Wpk, short* __restrict__ Am,
                                               unsigned short* __restrict__ h) {
    int b = blockIdx.x;
    int t = threadIdx.x;
    if (b < 16) {
        int id = b * 256 + t;
        int lane = id & 63;
        int quad = lane >> 4, l15 = lane & 15;
        short* dst;
        int n0, nstep, o0, ostep;
        float wscale = 1.0f;
        if (id < 2048) {
            int nt = (id >> 6) & 1, kc = id >> 7;
            dst = FbB + id * 16;
            n0 = kc * 32 + quad * 8; nstep = 1;
            o0 = nt * 16 + l15;      ostep = 0;
        } else {
            int id2 = id - 2048;
            dst = GbF + id2 * 16;
            int tt = id2 >> 6;
            n0 = tt * 16 + l15;      nstep = 0;
            o0 = quad * 8;           ostep = 1;
            wscale = 1.0f / 512.0f;
        }
        #pragma unroll
        for (int j = 0; j < 8; ++j) {
            int n = n0 + nstep * j;
            int o = o0 + ostep * j;
            int m = o >> 1, ri = o & 1;
            int k = (n * m) & 511;
            float sv, cv;
            sincosf(6.283185307179586f * (1.0f / 512.0f) * (float)k, &sv, &cv);
            float v = ri ? -sv : cv;
            if (id >= 2048) v *= (m == 0 ? 1.0f : 2.0f) * wscale;
            unsigned short hi = bf16_rne(v);
            dst[j]     = (short)hi;
            dst[8 + j] = (short)bf16_rne(v - bf16_tof(hi));
        }
    } else if (b < 32) {
        int tid = (b - 16) * 256 + t;
        int lane = tid & 63;
        int kc = (tid >> 6) & 1;
        int mt = (tid >> 7) & 3;
        int wg = tid >> 9;
        int layer = wg >> 1, which = wg & 1;
        const float* Wsrc = (which ? W2 : W1) + (size_t)layer * 4096;
        int o  = mt * 16 + (lane & 15);
        int c0 = kc * 32 + ((lane >> 4) & 3) * 8;
        short* dst = Wpk + (size_t)tid * 16;
        #pragma unroll
        for (int j = 0; j < 8; ++j) {
            float x = Wsrc[o * 64 + c0 + j];
            unsigned short hi = bf16_rne(x);
            dst[j]     = (short)hi;
            dst[8 + j] = (short)bf16_rne(x - bf16_tof(hi));
        }
    } else if (b < 288) {
        int id = (b - 32) * 256 + t;
        int lane = id & 63;
        int kc  = (id >> 6) & 1;
        int mt  = (id >> 7) & 3;
        int m   = (id >> 9) & 15;
        int lax = id >> 13;
        int l = lax >> 1, ax = lax & 1;
        int o  = mt * 16 + (lane & 15);
        int i0 = kc * 32 + ((lane >> 4) & 3) * 8;
        short* dst = Am + (size_t)id * 48;
        #pragma unroll
        for (int j = 0; j < 8; ++j) {
            size_t src = (((size_t)(l * 64 + o) * 64 + (i0 + j)) * 16 + m) * 2 + ax;
            float ar = Are[src], ai = Aim[src];
            unsigned short hh;
            hh = bf16_rne(ar);  dst[j]      = (short)hh; dst[8 + j]  = (short)bf16_rne(ar - bf16_tof(hh));
            hh = bf16_rne(ai);  dst[16 + j] = (short)hh; dst[24 + j] = (short)bf16_rne(ai - bf16_tof(hh));
            hh = bf16_rne(-ai); dst[32 + j] = (short)hh; dst[40 + j] = (short)bf16_rne(-ai - bf16_tof(hh));
        }
    } else {
        // encoder: h[p][pix] = bf16(We.x + be)
        int pix = (b - 288) * 256 + t;
        float x0 = xc[pix], x1 = xc[NPIX + pix], uu = u[pix];
        #pragma unroll 8
        for (int p = 0; p < 64; ++p) {
            float v = We[p * 3] * x0 + We[p * 3 + 1] * x1 + We[p * 3 + 2] * uu + be[p];
            h[(size_t)p * NPIX + pix] = bf16_rne(v);
        }
    }
}

// ---------------------------------------------------------------------------
// Merged forward DFT, both axes, h in bf16. grid(64 p, 8 ntile, 2 axis).
// axis1: direct short8 row reads. axis0 (R2): coalesced uint4 tile loads +
// LDS transpose. R8 (kept): axis0 double-buffered T -> ONE barrier per
// chunk; readers of T[(ch-2)&1] proven drained at the previous barrier.
// ---------------------------------------------------------------------------
__global__ __launch_bounds__(256) void k_fwd(const unsigned short* __restrict__ h, const short* __restrict__ FbB,
                                             float* __restrict__ VfH, float* __restrict__ VfW) {
    __shared__ unsigned short T[2][64 * 66];  // 2 x 8448 B
    int t = threadIdx.x;
    int p = blockIdx.x, ntb = blockIdx.y, axis = blockIdx.z;
    int wv = t >> 6, lane = t & 63, quad = lane >> 4, l15 = lane & 15;
    int n = ntb * 64 + wv * 16 + l15;
    int nL = wv * 16 + l15;
    f32x4 acc[2];
    acc[0] = (f32x4){0.f,0.f,0.f,0.f}; acc[1] = (f32x4){0.f,0.f,0.f,0.f};
    if (axis == 1) {
        #pragma unroll 4
        for (int kc = 0; kc < 16; ++kc) {
            int kb = kc * 32 + quad * 8;
            const unsigned short* hp = h + ((size_t)p * 512 + n) * 512 + kb;
            short8 Bv = *(const short8*)hp;
            #pragma unroll
            for (int mt = 0; mt < 2; ++mt) {
                const short8* ap = (const short8*)(FbB + (((kc * 2 + mt) * 64 + lane) << 4));
                short8 Ah = ap[0], Al = ap[1];
                acc[mt] = MFMA16(Ah, Bv, acc[mt]);
                acc[mt] = MFMA16(Al, Bv, acc[mt]);
            }
        }
    } else {
        int kp = t >> 3, c = t & 7;          // k-pair 0..31, n-oct 0..7
        for (int ch = 0; ch < 8; ++ch) {
            int k0 = ch * 64;
            const unsigned short* r0 = h + ((size_t)p * 512 + k0 + 2 * kp) * 512 + ntb * 64 + c * 8;
            uint4 a = *(const uint4*)r0;
            uint4 bq = *(const uint4*)(r0 + 512);
            unsigned int aw[4] = {a.x, a.y, a.z, a.w};
            unsigned int bw[4] = {bq.x, bq.y, bq.z, bq.w};
            unsigned short* Tb = T[ch & 1];
            #pragma unroll
            for (int i = 0; i < 4; ++i) {
                int n0 = c * 8 + 2 * i;
                *(unsigned int*)&Tb[n0 * 66 + 2 * kp]       = (aw[i] & 0xffffu) | (bw[i] << 16);
                *(unsigned int*)&Tb[(n0 + 1) * 66 + 2 * kp] = (aw[i] >> 16) | (bw[i] & 0xffff0000u);
            }
            __syncthreads();
            #pragma unroll
            for (int kcl = 0; kcl < 2; ++kcl) {
                int kc = ch * 2 + kcl;
                union { unsigned int w[4]; short8 v; } bb;
                #pragma unroll
                for (int d = 0; d < 4; ++d)
                    bb.w[d] = *(const unsigned int*)&Tb[nL * 66 + kcl * 32 + quad * 8 + 2 * d];
                #pragma unroll
                for (int mt = 0; mt < 2; ++mt) {
                    const short8* ap = (const short8*)(FbB + (((kc * 2 + mt) * 64 + lane) << 4));
                    short8 Ah = ap[0], Al = ap[1];
                    acc[mt] = MFMA16(Ah, bb.v, acc[mt]);
                    acc[mt] = MFMA16(Al, bb.v, acc[mt]);
                }
            }
        }
    }
    float* vp = (axis ? VfW : VfH) + (size_t)p * 32 * 512;
    #pragma unroll
    for (int mt = 0; mt < 2; ++mt)
        #pragma unroll
        for (int r = 0; r < 4; ++r)
            vp[(size_t)(mt * 16 + quad * 4 + r) * 512 + n] = acc[mt][r];
}

// ---------------------------------------------------------------------------
// Merged mode mixing, both axes. Epilogue writes Vm SPLIT-PACKED u32 in the
// [p][y>>4][m][y&15][ri] layout: one 128-B contiguous line per (o,r) store.
// grid 512 (axis = bid>>8; m = bid&15, otile = (bid>>4)&15), block 256.
// ---------------------------------------------------------------------------
__global__ __launch_bounds__(256) void k_mix2(const float* __restrict__ VfH, const float* __restrict__ VfW,
                                              const short* __restrict__ AmL,
                                              unsigned int* __restrict__ VmH, unsigned int* __restrict__ VmW) {
    __shared__ unsigned int BT[2 * 64 * 33];
    int bid = blockIdx.x;
    int axis = bid >> 8;
    int m  = bid & 15;
    int ot = (bid >> 4) & 15;
    const float* Vf = axis ? VfW : VfH;
    unsigned int* Vm = axis ? VmW : VmH;
    const short* Am = AmL + (size_t)axis * ASLAB;
    int t = threadIdx.x;
    #pragma unroll
    for (int it = 0; it < 16; ++it) {
        int idx = it * 256 + t;
        int oth = idx & 31, ri = (idx >> 5) & 1, i = idx >> 6;
        float v = Vf[((size_t)i * 32 + m * 2 + ri) * 512 + ot * 32 + oth];
        BT[(ri * 64 + i) * 33 + oth] = bf16_split_pack(v);
    }
    __syncthreads();
    int wv = t >> 6, lane = t & 63, quad = lane >> 4, l15 = lane & 15;
    int nt = wv & 1, mtp = wv >> 1;
    f32x4 aR[2], aI[2];
    aR[0]=(f32x4){0.f,0.f,0.f,0.f}; aR[1]=aR[0]; aI[0]=aR[0]; aI[1]=aR[0];
    #pragma unroll
    for (int kc = 0; kc < 2; ++kc) {
        short8 Brh, Brl, Bih, Bil;
        #pragma unroll
        for (int j = 0; j < 8; ++j) {
            int i = kc * 32 + quad * 8 + j;
            unsigned int br = BT[i * 33 + nt * 16 + l15];
            unsigned int bi = BT[(64 + i) * 33 + nt * 16 + l15];
            Brh[j] = (short)(br & 0xffffu); Brl[j] = (short)(br >> 16);
            Bih[j] = (short)(bi & 0xffffu); Bil[j] = (short)(bi >> 16);
        }
        #pragma unroll
        for (int mi = 0; mi < 2; ++mi) {
            int mt = mtp * 2 + mi;
            const short8* ap = (const short8*)(Am + ((size_t)(((m * 4 + mt) * 2 + kc) * 64 + lane)) * 48);
            short8 Arh = ap[0], Arl = ap[1], Aih = ap[2], Ail = ap[3], Anh = ap[4], Anl = ap[5];
            aR[mi] = MFMA16(Arh, Brh, aR[mi]);
            aR[mi] = MFMA16(Arl, Brh, aR[mi]);
            aR[mi] = MFMA16(Arh, Brl, aR[mi]);
            aR[mi] = MFMA16(Anh, Bih, aR[mi]);
            aR[mi] = MFMA16(Anl, Bih, aR[mi]);
            aR[mi] = MFMA16(Anh, Bil, aR[mi]);
            aI[mi] = MFMA16(Arh, Bih, aI[mi]);
            aI[mi] = MFMA16(Arl, Bih, aI[mi]);
            aI[mi] = MFMA16(Arh, Bil, aI[mi]);
            aI[mi] = MFMA16(Aih, Brh, aI[mi]);
            aI[mi] = MFMA16(Ail, Brh, aI[mi]);
            aI[mi] = MFMA16(Aih, Brl, aI[mi]);
        }
    }
    int yT = ot * 2 + nt;
    #pragma unroll
    for (int mi = 0; mi < 2; ++mi) {
        int o = (mtp * 2 + mi) * 16 + quad * 4;
        #pragma unroll
        for (int r = 0; r < 4; ++r) {
            uint2 v;
            v.x = bf16_split_pack(aR[mi][r]);
            v.y = bf16_split_pack(aI[mi][r]);
            *(uint2*)(Vm + VM_IDX(o + r, yT, m, l15)) = v;
        }
    }
}

// ---------------------------------------------------------------------------
// Fused inverse DFT -> s in [pix][ch] layout (R6).
// grid(32 xt, 32 yt): block = 16x16 pixel patch x ALL 64 channels.
// Results transposed through LDS with permuted pixel index pp=(r*16+x)*4+quad
// (store banks = perm mod 32, 2-way free), drained as FULL 128-B lines.
// ---------------------------------------------------------------------------
__global__ __launch_bounds__(256) void k_inv(const unsigned int* __restrict__ VmW, const unsigned int* __restrict__ VmH,
                                             const short* __restrict__ GbF, unsigned short* __restrict__ s) {
    __shared__ unsigned short sT[256 * 66];   // [pp][ch + pad], 33792 B
    int t = threadIdx.x;
    int xt = blockIdx.x, yt = blockIdx.y;
    int wv = t >> 6, lane = t & 63, quad = lane >> 4, l15 = lane & 15;
    const short8* gy = (const short8*)(GbF + ((yt * 64 + lane) << 4));
    short8 A1h = gy[0], A1l = gy[1];
    const short8* gx = (const short8*)(GbF + ((xt * 64 + lane) << 4));
    short8 B2h = gx[0], B2l = gx[1];
    int p0 = wv * 16;
    for (int pp = 0; pp < 16; ++pp) {
        int p = p0 + pp;
        unsigned int aw[8], bw[8];
        #pragma unroll
        for (int tt = 0; tt < 4; ++tt) {
            uint2 qa = *(const uint2*)(VmW + VM_IDX(p, yt, quad * 4 + tt, l15));
            uint2 qb = *(const uint2*)(VmH + VM_IDX(p, xt, quad * 4 + tt, l15));
            aw[2*tt] = qa.x; aw[2*tt+1] = qa.y;
            bw[2*tt] = qb.x; bw[2*tt+1] = qb.y;
        }
        short8 A2h, A2l, B1h, B1l;
        unzip8(aw, A2h, A2l);
        unzip8(bw, B1h, B1l);
        f32x4 acc = (f32x4){0.f,0.f,0.f,0.f};
        acc = MFMA16(A1h, B1h, acc);
        acc = MFMA16(A1l, B1h, acc);
        acc = MFMA16(A1h, B1l, acc);
        acc = MFMA16(A2h, B2h, acc);
        acc = MFMA16(A2l, B2h, acc);
        acc = MFMA16(A2h, B2l, acc);
        #pragma unroll
        for (int r = 0; r < 4; ++r)
            sT[(((r * 16 + l15) << 2) + quad) * 66 + p] = bf16_rne(acc[r]);
    }
    __syncthreads();
    #pragma unroll
    for (int it = 0; it < 8; ++it) {
        int ppix = it * 32 + (t >> 3);
        int part = t & 7;
        const unsigned int* lp = (const unsigned int*)&sT[ppix * 66 + part * 8];
        uint4 v; v.x = lp[0]; v.y = lp[1]; v.z = lp[2]; v.w = lp[3];
        int q = ppix & 3, rx = ppix >> 2;
        int xl = rx & 15, r = rx >> 4;
        int y = yt * 16 + q * 4 + r;
        int x = xt * 16 + xl;
        *(uint4*)(s + (((size_t)y * 512 + x) << 6) + part * 8) = v;
    }
}

// ---------------------------------------------------------------------------
// MFMA FFN, 128-px tile (grid 2048): h(bf16) += gelu(W2.gelu(W1.s+b1)+b2).
// R9 structure (single-tile, no pre-GEMM barrier). s is [pix][ch]: GEMM1
// B-frags direct short8 global loads. tB own-wave rows (no barrier
// epi1->GEMM2); oTb aliases tB (barrier before epi2). (256,4), rcp-gelu.
// R10: v_cvt_pk_bf16_f32 for epi1 tB words and h-increment packs
// (1 op per bf16-pair vs ~7-op bit-trick sequence).
// ---------------------------------------------------------------------------
union FfnSmem {
    unsigned int  tB[128 * 33];     // 16896 B, GEMM1->GEMM2 bf16 pairs
    unsigned short oTb[64 * 136];   // 17408 B, epilogue2 bf16 transpose tile
    float         red[16 * 132];    // 8448 B, decoder partial sums
};

__global__ __launch_bounds__(256, 4) void k_ffn2m(const unsigned short* __restrict__ in, unsigned short* __restrict__ out,
                                                  const short* __restrict__ w1f, const float* __restrict__ b1v,
                                                  const short* __restrict__ w2f, const float* __restrict__ b2v,
                                                  const float* __restrict__ Wd, const float* __restrict__ bd,
                                                  float* __restrict__ dout, int last) {
    __shared__ __align__(16) FfnSmem u;
    int t = threadIdx.x;
    int pixBase = blockIdx.x * 128;
    int lane15 = t & 15;
    int quad   = (t >> 4) & 3;
    int wv     = t >> 6;
    int oct = t & 15;                          // store pixel oct 0..15
    int cg  = t >> 4;                          // store channel group 0..15

    // ---- GEMM1 B-fragments straight from global s[pix][ch] ----
    short8 bb0[2], bb1[2];
    #pragma unroll
    for (int kc = 0; kc < 2; ++kc) {
        int col = kc * 32 + quad * 8;
        bb0[kc] = *(const short8*)(in + (((size_t)(pixBase + wv * 32 + lane15)) << 6) + col);
        bb1[kc] = *(const short8*)(in + (((size_t)(pixBase + wv * 32 + 16 + lane15)) << 6) + col);
    }

    f32x4 acc[2][4];
    #pragma unroll
    for (int ns = 0; ns < 2; ++ns)
        #pragma unroll
        for (int mt = 0; mt < 4; ++mt) acc[ns][mt] = (f32x4){0.f, 0.f, 0.f, 0.f};

    // ---- GEMM1: 2-term, weights at use ----
    #pragma unroll
    for (int kc = 0; kc < 2; ++kc) {
        #pragma unroll
        for (int mt = 0; mt < 4; ++mt) {
            int s8 = mt * 2 + kc;
            const short8* wp = (const short8*)(w1f + (((size_t)s8 * 64 + (t & 63)) << 4));
            short8 wh = wp[0], wl = wp[1];
            acc[0][mt] = MFMA16(wh, bb0[kc], acc[0][mt]);
            acc[0][mt] = MFMA16(wl, bb0[kc], acc[0][mt]);
            acc[1][mt] = MFMA16(wh, bb1[kc], acc[1][mt]);
            acc[1][mt] = MFMA16(wl, bb1[kc], acc[1][mt]);
        }
    }

    // ---- epilogue1: gelu -> cvt_pk bf16 pairs -> tB (own-wave rows only) ----
    #pragma unroll
    for (int ns = 0; ns < 2; ++ns) {
        int row = wv * 32 + ns * 16 + lane15;
        #pragma unroll
        for (int mt = 0; mt < 4; ++mt) {
            const float* bp = b1v + mt * 16 + quad * 4;
            float g[4];
            #pragma unroll
            for (int r = 0; r < 4; ++r) g[r] = gelu_f(acc[ns][mt][r] + bp[r]);
            int cp = (mt * 16 + quad * 4) >> 1;
            u.tB[row * 33 + cp]     = cvt_pk_bf16(g[0], g[1]);
            u.tB[row * 33 + cp + 1] = cvt_pk_bf16(g[2], g[3]);
            acc[ns][mt] = (f32x4){0.f, 0.f, 0.f, 0.f};
        }
    }

    // NO barrier: GEMM2 reads only this wave's own rows, written above.

    // ---- GEMM2: 2-term, weights at use ----
    #pragma unroll
    for (int kc = 0; kc < 2; ++kc) {
        union { unsigned int w[4]; short8 v; } cb0, cb1;
        int row0 = wv * 32 + lane15;
        int row1 = wv * 32 + 16 + lane15;
        #pragma unroll
        for (int i = 0; i < 4; ++i) {
            cb0.w[i] = u.tB[row0 * 33 + kc * 16 + quad * 4 + i];
            cb1.w[i] = u.tB[row1 * 33 + kc * 16 + quad * 4 + i];
        }
        #pragma unroll
        for (int mt = 0; mt < 4; ++mt) {
            int s8 = mt * 2 + kc;
            const short8* wp = (const short8*)(w2f + (((size_t)s8 * 64 + (t & 63)) << 4));
            short8 wh = wp[0], wl = wp[1];
            acc[0][mt] = MFMA16(wh, cb0.v, acc[0][mt]);
            acc[0][mt] = MFMA16(wl, cb0.v, acc[0][mt]);
            acc[1][mt] = MFMA16(wh, cb1.v, acc[1][mt]);
            acc[1][mt] = MFMA16(wl, cb1.v, acc[1][mt]);
        }
    }

    // ---- h residual load (latency hidden by epilogue2 VALU) ----
    uint4 hr[4];
    #pragma unroll
    for (int j = 0; j < 4; ++j) {
        int c = cg + 16 * j;
        hr[j] = *(const uint4*)(out + (size_t)c * NPIX + pixBase + oct * 8);
    }

    __syncthreads();   // all waves done reading tB; oTb scatter may begin

    // ---- epilogue2: gelu -> bf16 oTb (aliases tB) ----
    #pragma unroll
    for (int ns = 0; ns < 2; ++ns) {
        int px = wv * 32 + ns * 16 + lane15;
        #pragma unroll
        for (int mt = 0; mt < 4; ++mt) {
            const float* bp = b2v + mt * 16 + quad * 4;
            #pragma unroll
            for (int r = 0; r < 4; ++r) {
                int c = mt * 16 + quad * 4 + r;
                u.oTb[c * 136 + px] = bf16_rne(gelu_f(acc[ns][mt][r] + bp[r]));
            }
        }
    }
    __syncthreads();

    if (!last) {
        // ---- h(bf16) += increment: (c,oct) units, uint4, full 256-B sectors/wave ----
        #pragma unroll
        for (int j = 0; j < 4; ++j) {
            int c = cg + 16 * j;
            uint4 gv = *(const uint4*)&u.oTb[c * 136 + oct * 8];
            unsigned int hw[4] = {hr[j].x, hr[j].y, hr[j].z, hr[j].w};
            unsigned int gw[4] = {gv.x, gv.y, gv.z, gv.w};
            uint4 o;
            unsigned int* op = &o.x;
            #pragma unroll
            for (int i = 0; i < 4; ++i) {
                float f0 = bf16_tof((unsigned short)(hw[i] & 0xffffu)) + bf16_tof((unsigned short)(gw[i] & 0xffffu));
                float f1 = bf16_tof((unsigned short)(hw[i] >> 16))     + bf16_tof((unsigned short)(gw[i] >> 16));
                op[i] = cvt_pk_bf16(f0, f1);
            }
            *(uint4*)(out + (size_t)c * NPIX + pixBase + oct * 8) = o;
        }
    } else {
        // ---- fused decoder: dout = sum_c Wd[c]*(hres+gv) + bd ----
        float part[8] = {0.f,0.f,0.f,0.f,0.f,0.f,0.f,0.f};
        #pragma unroll
        for (int j = 0; j < 4; ++j) {
            int c = cg + 16 * j;
            float wd = Wd[c];
            uint4 gv = *(const uint4*)&u.oTb[c * 136 + oct * 8];
            unsigned int hw[4] = {hr[j].x, hr[j].y, hr[j].z, hr[j].w};
            unsigned int gw[4] = {gv.x, gv.y, gv.z, gv.w};
            #pragma unroll
            for (int i = 0; i < 4; ++i) {
                part[2*i]   += wd * (bf16_tof((unsigned short)(hw[i] & 0xffffu)) + bf16_tof((unsigned short)(gw[i] & 0xffffu)));
                part[2*i+1] += wd * (bf16_tof((unsigned short)(hw[i] >> 16))     + bf16_tof((unsigned short)(gw[i] >> 16)));
            }
        }
        __syncthreads();   // oTb reads done before red (aliases buffer) is written
        #pragma unroll
        for (int i = 0; i < 8; ++i)
            u.red[cg * 132 + oct * 8 + i] = part[i];
        __syncthreads();
        if (t < 128) {
            float sum = bd[0];
            #pragma unroll
            for (int gg = 0; gg < 16; ++gg)
                sum += u.red[gg * 132 + t];
            dout[pixBase + t] = sum;
        }
    }
}

extern "C" void kernel_launch(void* const* d_in, const int* in_sizes, int n_in,
                              void* d_out, int out_size, void* d_ws, size_t ws_size,
                              hipStream_t stream) {
    (void)in_sizes; (void)n_in; (void)out_size; (void)ws_size;
    const float* u   = (const float*)d_in[0];
    const float* xc  = (const float*)d_in[1];
    const float* We  = (const float*)d_in[2];
    const float* be  = (const float*)d_in[3];
    const float* W1  = (const float*)d_in[4];
    const float* b1  = (const float*)d_in[5];
    const float* W2  = (const float*)d_in[6];
    const float* b2  = (const float*)d_in[7];
    const float* Are = (const float*)d_in[8];
    const float* Aim = (const float*)d_in[9];
    const float* Wd  = (const float*)d_in[10];
    const float* bd  = (const float*)d_in[11];

    // workspace layout, ~93 MB used
    char* ws = (char*)d_ws;
    unsigned short* h = (unsigned short*)ws;                  // 32 MB (bf16) [ch][pix]
    unsigned short* s = (unsigned short*)(ws + (size_t)33554432); // 32 MB (bf16) [pix][ch]
    float* VfH = (float*)(ws + (size_t)67108864);             // 4 MB: [64][32][512]
    float* VfW = VfH + (size_t)1048576;                       // 4 MB
    unsigned int* VmH = (unsigned int*)(VfW + 1048576);       // 4 MB split-packed
    unsigned int* VmW = VmH + (size_t)1048576;                // 4 MB
    short* FbB = (short*)(VmW + 1048576);                     // 64 KB
    short* GbF = FbB + 32768;                                 // 64 KB
    short* Am  = GbF + 32768;                                 // 6 MB
    short* Wpk = Am  + (size_t)65536 * 48;                    // 128 KB

    k_setup<<<1312, 256, 0, stream>>>(W1, W2, Are, Aim, u, xc, We, be,
                                      FbB, GbF, Wpk, Am, h);

    for (int l = 0; l < 4; ++l) {
        k_fwd<<<dim3(64, 8, 2), 256, 0, stream>>>(h, FbB, VfH, VfW);
        k_mix2<<<512, 256, 0, stream>>>(VfH, VfW, Am + (size_t)(l * 2) * ASLAB, VmH, VmW);
        k_inv<<<dim3(32, 32), 256, 0, stream>>>(VmW, VmH, GbF, s);
        k_ffn2m<<<2048, 256, 0, stream>>>(s, h,
                                          Wpk + (size_t)(l * 2 + 0) * 8192, b1 + (size_t)l * 64,
                                          Wpk + (size_t)(l * 2 + 1) * 8192, b2 + (size_t)l * 64,
                                          Wd, bd, (float*)d_out, (l == 3) ? 1 : 0);
    }
}

// Round 13
// 381.591 us; speedup vs baseline: 1.0398x; 1.0051x over previous
//
#include <hip/hip_runtime.h>

#define NPIX (512*512)

typedef __attribute__((ext_vector_type(8))) short short8;   // 8 bf16 in 4 VGPRs
typedef __attribute__((ext_vector_type(4))) float f32x4;    // MFMA accumulator

#define MFMA16(A, B, C) __builtin_amdgcn_mfma_f32_16x16x32_bf16((A), (B), (C), 0, 0, 0)

// JAX gelu(approximate=True): x * sigmoid(2*sqrt(2/pi)*(x+0.044715x^3)).
// R7: exact f32 div -> v_rcp_f32 (rel-err ~2^-22 << bf16 ulp).
__device__ __forceinline__ float gelu_f(float x) {
    float z = 1.5957691216057308f * (x + 0.044715f * x * x * x);
    return x * __builtin_amdgcn_rcpf(1.0f + __expf(-z));
}

// f32 -> bf16 bits (RNE), bit-trick (k_setup only; launch-once)
__device__ __forceinline__ unsigned short bf16_rne(float x) {
    unsigned int b = __float_as_uint(x);
    unsigned int r = b + 0x7fffu + ((b >> 16) & 1u);
    return (unsigned short)(r >> 16);
}
__device__ __forceinline__ float bf16_tof(unsigned short h) {
    return __uint_as_float(((unsigned int)h) << 16);
}
// R10: packed 2xf32 -> 2xbf16 (RNE) in ONE VALU op. D[15:0]=bf16(lo),
// D[31:16]=bf16(hi). R12 validated bit-exact vs bit-trick (absmax canary).
__device__ __forceinline__ unsigned int cvt_pk_bf16(float lo, float hi) {
    unsigned int r;
    asm("v_cvt_pk_bf16_f32 %0, %1, %2" : "=v"(r) : "v"(lo), "v"(hi));
    return r;
}
// R12: 1-op scalar rne via cvt_pk (low 16 bits)
__device__ __forceinline__ unsigned short bf16_rne1(float x) {
    return (unsigned short)(cvt_pk_bf16(x, x) & 0xffffu);
}
// R12: split-pack (hi | lo<<16) in 4 ops (was 10): final cvt_pk's low16 =
// bf16(v) = hi, high16 = bf16(v - tof(hi)) = lo -- exactly the format.
__device__ __forceinline__ unsigned int bf16_split_pack(float v) {
    unsigned int t = cvt_pk_bf16(v, v);
    float f_hi = __uint_as_float(t << 16);
    return cvt_pk_bf16(v, v - f_hi);
}
// unzip 8 split-packed u32 (hi|lo<<16 per elem) -> hi-short8 / lo-short8
__device__ __forceinline__ void unzip8(const unsigned int* w, short8& h, short8& l) {
    union { unsigned int u[4]; short8 v; } hh, ll;
    #pragma unroll
    for (int i = 0; i < 4; ++i) {
        hh.u[i] = (w[2*i] & 0xffffu) | (w[2*i+1] << 16);
        ll.u[i] = (w[2*i] >> 16) | (w[2*i+1] & 0xffff0000u);
    }
    h = hh.v; l = ll.v;
}

#define ASLAB ((size_t)16 * 4 * 2 * 64 * 48)   // shorts per (l,ax) in Am

// Vm u32 index: [p][y>>4][m][y&15][ri]  (R1: full-128B-line single-wave stores)
#define VM_IDX(p, yT, m, yL) (((((size_t)(p) * 32 + (yT)) * 16 + (m)) * 16 + (yL)) * 2)

// ---------------------------------------------------------------------------
// Merged setup + encoder: blocks 0..15 basis tables, 16..31 FFN weights,
// 32..287 spectral A-weights, 288..1311 encoder (h stored bf16).
// ---------------------------------------------------------------------------
__global__ __launch_bounds__(256) void k_setup(const float* __restrict__ W1, const float* __restrict__ W2,
                                               const float* __restrict__ Are, const float* __restrict__ Aim,
                                               const float* __restrict__ u, const float* __restrict__ xc,
                                               const float* __restrict__ We, const float* __restrict__ be,
                                               short* __restrict__ FbB, short* __restrict__ GbF,
                                               short* __restrict__ Wpk, short* __restrict__ Am,
                                               unsigned short* __restrict__ h) {
    int b = blockIdx.x;
    int t = threadIdx.x;
    if (b < 16) {
        int id = b * 256 + t;
        int lane = id & 63;
        int quad = lane >> 4, l15 = lane & 15;
        short* dst;
        int n0, nstep, o0, ostep;
        float wscale = 1.0f;
        if (id < 2048) {
            int nt = (id >> 6) & 1, kc = id >> 7;
            dst = FbB + id * 16;
            n0 = kc * 32 + quad * 8; nstep = 1;
            o0 = nt * 16 + l15;      ostep = 0;
        } else {
            int id2 = id - 2048;
            dst = GbF + id2 * 16;
            int tt = id2 >> 6;
            n0 = tt * 16 + l15;      nstep = 0;
            o0 = quad * 8;           ostep = 1;
            wscale = 1.0f / 512.0f;
        }
        #pragma unroll
        for (int j = 0; j < 8; ++j) {
            int n = n0 + nstep * j;
            int o = o0 + ostep * j;
            int m = o >> 1, ri = o & 1;
            int k = (n * m) & 511;
            float sv, cv;
            sincosf(6.283185307179586f * (1.0f / 512.0f) * (float)k, &sv, &cv);
            float v = ri ? -sv : cv;
            if (id >= 2048) v *= (m == 0 ? 1.0f : 2.0f) * wscale;
            unsigned short hi = bf16_rne(v);
            dst[j]     = (short)hi;
            dst[8 + j] = (short)bf16_rne(v - bf16_tof(hi));
        }
    } else if (b < 32) {
        int tid = (b - 16) * 256 + t;
        int lane = tid & 63;
        int kc = (tid >> 6) & 1;
        int mt = (tid >> 7) & 3;
        int wg = tid >> 9;
        int layer = wg >> 1, which = wg & 1;
        const float* Wsrc = (which ? W2 : W1) + (size_t)layer * 4096;
        int o  = mt * 16 + (lane & 15);
        int c0 = kc * 32 + ((lane >> 4) & 3) * 8;
        short* dst = Wpk + (size_t)tid * 16;
        #pragma unroll
        for (int j = 0; j < 8; ++j) {
            float x = Wsrc[o * 64 + c0 + j];
            unsigned short hi = bf16_rne(x);
            dst[j]     = (short)hi;
            dst[8 + j] = (short)bf16_rne(x - bf16_tof(hi));
        }
    } else if (b < 288) {
        int id = (b - 32) * 256 + t;
        int lane = id & 63;
        int kc  = (id >> 6) & 1;
        int mt  = (id >> 7) & 3;
        int m   = (id >> 9) & 15;
        int lax = id >> 13;
        int l = lax >> 1, ax = lax & 1;
        int o  = mt * 16 + (lane & 15);
        int i0 = kc * 32 + ((lane >> 4) & 3) * 8;
        short* dst = Am + (size_t)id * 48;
        #pragma unroll
        for (int j = 0; j < 8; ++j) {
            size_t src = (((size_t)(l * 64 + o) * 64 + (i0 + j)) * 16 + m) * 2 + ax;
            float ar = Are[src], ai = Aim[src];
            unsigned short hh;
            hh = bf16_rne(ar);  dst[j]      = (short)hh; dst[8 + j]  = (short)bf16_rne(ar - bf16_tof(hh));
            hh = bf16_rne(ai);  dst[16 + j] = (short)hh; dst[24 + j] = (short)bf16_rne(ai - bf16_tof(hh));
            hh = bf16_rne(-ai); dst[32 + j] = (short)hh; dst[40 + j] = (short)bf16_rne(-ai - bf16_tof(hh));
        }
    } else {
        // encoder: h[p][pix] = bf16(We.x + be)
        int pix = (b - 288) * 256 + t;
        float x0 = xc[pix], x1 = xc[NPIX + pix], uu = u[pix];
        #pragma unroll 8
        for (int p = 0; p < 64; ++p) {
            float v = We[p * 3] * x0 + We[p * 3 + 1] * x1 + We[p * 3 + 2] * uu + be[p];
            h[(size_t)p * NPIX + pix] = bf16_rne(v);
        }
    }
}

// ---------------------------------------------------------------------------
// Merged forward DFT, both axes, h in bf16. grid(64 p, 8 ntile, 2 axis).
// axis1: direct short8 row reads. axis0 (R2): coalesced uint4 tile loads +
// LDS transpose. R8 (kept): axis0 double-buffered T -> ONE barrier per
// chunk; readers of T[(ch-2)&1] proven drained at the previous barrier.
// ---------------------------------------------------------------------------
__global__ __launch_bounds__(256) void k_fwd(const unsigned short* __restrict__ h, const short* __restrict__ FbB,
                                             float* __restrict__ VfH, float* __restrict__ VfW) {
    __shared__ unsigned short T[2][64 * 66];  // 2 x 8448 B
    int t = threadIdx.x;
    int p = blockIdx.x, ntb = blockIdx.y, axis = blockIdx.z;
    int wv = t >> 6, lane = t & 63, quad = lane >> 4, l15 = lane & 15;
    int n = ntb * 64 + wv * 16 + l15;
    int nL = wv * 16 + l15;
    f32x4 acc[2];
    acc[0] = (f32x4){0.f,0.f,0.f,0.f}; acc[1] = (f32x4){0.f,0.f,0.f,0.f};
    if (axis == 1) {
        #pragma unroll 4
        for (int kc = 0; kc < 16; ++kc) {
            int kb = kc * 32 + quad * 8;
            const unsigned short* hp = h + ((size_t)p * 512 + n) * 512 + kb;
            short8 Bv = *(const short8*)hp;
            #pragma unroll
            for (int mt = 0; mt < 2; ++mt) {
                const short8* ap = (const short8*)(FbB + (((kc * 2 + mt) * 64 + lane) << 4));
                short8 Ah = ap[0], Al = ap[1];
                acc[mt] = MFMA16(Ah, Bv, acc[mt]);
                acc[mt] = MFMA16(Al, Bv, acc[mt]);
            }
        }
    } else {
        int kp = t >> 3, c = t & 7;          // k-pair 0..31, n-oct 0..7
        for (int ch = 0; ch < 8; ++ch) {
            int k0 = ch * 64;
            const unsigned short* r0 = h + ((size_t)p * 512 + k0 + 2 * kp) * 512 + ntb * 64 + c * 8;
            uint4 a = *(const uint4*)r0;
            uint4 bq = *(const uint4*)(r0 + 512);
            unsigned int aw[4] = {a.x, a.y, a.z, a.w};
            unsigned int bw[4] = {bq.x, bq.y, bq.z, bq.w};
            unsigned short* Tb = T[ch & 1];
            #pragma unroll
            for (int i = 0; i < 4; ++i) {
                int n0 = c * 8 + 2 * i;
                *(unsigned int*)&Tb[n0 * 66 + 2 * kp]       = (aw[i] & 0xffffu) | (bw[i] << 16);
                *(unsigned int*)&Tb[(n0 + 1) * 66 + 2 * kp] = (aw[i] >> 16) | (bw[i] & 0xffff0000u);
            }
            __syncthreads();
            #pragma unroll
            for (int kcl = 0; kcl < 2; ++kcl) {
                int kc = ch * 2 + kcl;
                union { unsigned int w[4]; short8 v; } bb;
                #pragma unroll
                for (int d = 0; d < 4; ++d)
                    bb.w[d] = *(const unsigned int*)&Tb[nL * 66 + kcl * 32 + quad * 8 + 2 * d];
                #pragma unroll
                for (int mt = 0; mt < 2; ++mt) {
                    const short8* ap = (const short8*)(FbB + (((kc * 2 + mt) * 64 + lane) << 4));
                    short8 Ah = ap[0], Al = ap[1];
                    acc[mt] = MFMA16(Ah, bb.v, acc[mt]);
                    acc[mt] = MFMA16(Al, bb.v, acc[mt]);
                }
            }
        }
    }
    float* vp = (axis ? VfW : VfH) + (size_t)p * 32 * 512;
    #pragma unroll
    for (int mt = 0; mt < 2; ++mt)
        #pragma unroll
        for (int r = 0; r < 4; ++r)
            vp[(size_t)(mt * 16 + quad * 4 + r) * 512 + n] = acc[mt][r];
}

// ---------------------------------------------------------------------------
// Merged mode mixing, both axes. Epilogue writes Vm SPLIT-PACKED u32 in the
// [p][y>>4][m][y&15][ri] layout: one 128-B contiguous line per (o,r) store.
// grid 512 (axis = bid>>8; m = bid&15, otile = (bid>>4)&15), block 256.
// R12: split_pack via cvt_pk (4 ops, was 10) in staging + epilogue.
// ---------------------------------------------------------------------------
__global__ __launch_bounds__(256) void k_mix2(const float* __restrict__ VfH, const float* __restrict__ VfW,
                                              const short* __restrict__ AmL,
                                              unsigned int* __restrict__ VmH, unsigned int* __restrict__ VmW) {
    __shared__ unsigned int BT[2 * 64 * 33];
    int bid = blockIdx.x;
    int axis = bid >> 8;
    int m  = bid & 15;
    int ot = (bid >> 4) & 15;
    const float* Vf = axis ? VfW : VfH;
    unsigned int* Vm = axis ? VmW : VmH;
    const short* Am = AmL + (size_t)axis * ASLAB;
    int t = threadIdx.x;
    #pragma unroll
    for (int it = 0; it < 16; ++it) {
        int idx = it * 256 + t;
        int oth = idx & 31, ri = (idx >> 5) & 1, i = idx >> 6;
        float v = Vf[((size_t)i * 32 + m * 2 + ri) * 512 + ot * 32 + oth];
        BT[(ri * 64 + i) * 33 + oth] = bf16_split_pack(v);
    }
    __syncthreads();
    int wv = t >> 6, lane = t & 63, quad = lane >> 4, l15 = lane & 15;
    int nt = wv & 1, mtp = wv >> 1;
    f32x4 aR[2], aI[2];
    aR[0]=(f32x4){0.f,0.f,0.f,0.f}; aR[1]=aR[0]; aI[0]=aR[0]; aI[1]=aR[0];
    #pragma unroll
    for (int kc = 0; kc < 2; ++kc) {
        short8 Brh, Brl, Bih, Bil;
        #pragma unroll
        for (int j = 0; j < 8; ++j) {
            int i = kc * 32 + quad * 8 + j;
            unsigned int br = BT[i * 33 + nt * 16 + l15];
            unsigned int bi = BT[(64 + i) * 33 + nt * 16 + l15];
            Brh[j] = (short)(br & 0xffffu); Brl[j] = (short)(br >> 16);
            Bih[j] = (short)(bi & 0xffffu); Bil[j] = (short)(bi >> 16);
        }
        #pragma unroll
        for (int mi = 0; mi < 2; ++mi) {
            int mt = mtp * 2 + mi;
            const short8* ap = (const short8*)(Am + ((size_t)(((m * 4 + mt) * 2 + kc) * 64 + lane)) * 48);
            short8 Arh = ap[0], Arl = ap[1], Aih = ap[2], Ail = ap[3], Anh = ap[4], Anl = ap[5];
            aR[mi] = MFMA16(Arh, Brh, aR[mi]);
            aR[mi] = MFMA16(Arl, Brh, aR[mi]);
            aR[mi] = MFMA16(Arh, Brl, aR[mi]);
            aR[mi] = MFMA16(Anh, Bih, aR[mi]);
            aR[mi] = MFMA16(Anl, Bih, aR[mi]);
            aR[mi] = MFMA16(Anh, Bil, aR[mi]);
            aI[mi] = MFMA16(Arh, Bih, aI[mi]);
            aI[mi] = MFMA16(Arl, Bih, aI[mi]);
            aI[mi] = MFMA16(Arh, Bil, aI[mi]);
            aI[mi] = MFMA16(Aih, Brh, aI[mi]);
            aI[mi] = MFMA16(Ail, Brh, aI[mi]);
            aI[mi] = MFMA16(Aih, Brl, aI[mi]);
        }
    }
    int yT = ot * 2 + nt;
    #pragma unroll
    for (int mi = 0; mi < 2; ++mi) {
        int o = (mtp * 2 + mi) * 16 + quad * 4;
        #pragma unroll
        for (int r = 0; r < 4; ++r) {
            uint2 v;
            v.x = bf16_split_pack(aR[mi][r]);
            v.y = bf16_split_pack(aI[mi][r]);
            *(uint2*)(Vm + VM_IDX(o + r, yT, m, l15)) = v;
        }
    }
}

// ---------------------------------------------------------------------------
// Fused inverse DFT -> s in [pix][ch] layout (R6).
// grid(32 xt, 32 yt): block = 16x16 pixel patch x ALL 64 channels.
// Results transposed through LDS with permuted pixel index pp=(r*16+x)*4+quad
// (store banks = perm mod 32, 2-way free), drained as FULL 128-B lines.
// R12: 1-op cvt_pk rne for sT stores (was 3-op bit-trick, 64/thread).
// ---------------------------------------------------------------------------
__global__ __launch_bounds__(256) void k_inv(const unsigned int* __restrict__ VmW, const unsigned int* __restrict__ VmH,
                                             const short* __restrict__ GbF, unsigned short* __restrict__ s) {
    __shared__ unsigned short sT[256 * 66];   // [pp][ch + pad], 33792 B
    int t = threadIdx.x;
    int xt = blockIdx.x, yt = blockIdx.y;
    int wv = t >> 6, lane = t & 63, quad = lane >> 4, l15 = lane & 15;
    const short8* gy = (const short8*)(GbF + ((yt * 64 + lane) << 4));
    short8 A1h = gy[0], A1l = gy[1];
    const short8* gx = (const short8*)(GbF + ((xt * 64 + lane) << 4));
    short8 B2h = gx[0], B2l = gx[1];
    int p0 = wv * 16;
    for (int pp = 0; pp < 16; ++pp) {
        int p = p0 + pp;
        unsigned int aw[8], bw[8];
        #pragma unroll
        for (int tt = 0; tt < 4; ++tt) {
            uint2 qa = *(const uint2*)(VmW + VM_IDX(p, yt, quad * 4 + tt, l15));
            uint2 qb = *(const uint2*)(VmH + VM_IDX(p, xt, quad * 4 + tt, l15));
            aw[2*tt] = qa.x; aw[2*tt+1] = qa.y;
            bw[2*tt] = qb.x; bw[2*tt+1] = qb.y;
        }
        short8 A2h, A2l, B1h, B1l;
        unzip8(aw, A2h, A2l);
        unzip8(bw, B1h, B1l);
        f32x4 acc = (f32x4){0.f,0.f,0.f,0.f};
        acc = MFMA16(A1h, B1h, acc);
        acc = MFMA16(A1l, B1h, acc);
        acc = MFMA16(A1h, B1l, acc);
        acc = MFMA16(A2h, B2h, acc);
        acc = MFMA16(A2l, B2h, acc);
        acc = MFMA16(A2h, B2l, acc);
        #pragma unroll
        for (int r = 0; r < 4; ++r)
            sT[(((r * 16 + l15) << 2) + quad) * 66 + p] = bf16_rne1(acc[r]);
    }
    __syncthreads();
    #pragma unroll
    for (int it = 0; it < 8; ++it) {
        int ppix = it * 32 + (t >> 3);
        int part = t & 7;
        const unsigned int* lp = (const unsigned int*)&sT[ppix * 66 + part * 8];
        uint4 v; v.x = lp[0]; v.y = lp[1]; v.z = lp[2]; v.w = lp[3];
        int q = ppix & 3, rx = ppix >> 2;
        int xl = rx & 15, r = rx >> 4;
        int y = yt * 16 + q * 4 + r;
        int x = xt * 16 + xl;
        *(uint4*)(s + (((size_t)y * 512 + x) << 6) + part * 8) = v;
    }
}

// ---------------------------------------------------------------------------
// MFMA FFN, 128-px tile (grid 2048): h(bf16) += gelu(W2.gelu(W1.s+b1)+b2).
// R9 structure (single-tile, no pre-GEMM barrier). s is [pix][ch]: GEMM1
// B-frags direct short8 global loads. tB own-wave rows (no barrier
// epi1->GEMM2); oTb aliases tB (barrier before epi2). (256,4), rcp-gelu.
// R10: cvt_pk for epi1 tB words and h-increment. R12: 1-op rne for epi2 oTb.
// ---------------------------------------------------------------------------
union FfnSmem {
    unsigned int  tB[128 * 33];     // 16896 B, GEMM1->GEMM2 bf16 pairs
    unsigned short oTb[64 * 136];   // 17408 B, epilogue2 bf16 transpose tile
    float         red[16 * 132];    // 8448 B, decoder partial sums
};

__global__ __launch_bounds__(256, 4) void k_ffn2m(const unsigned short* __restrict__ in, unsigned short* __restrict__ out,
                                                  const short* __restrict__ w1f, const float* __restrict__ b1v,
                                                  const short* __restrict__ w2f, const float* __restrict__ b2v,
                                                  const float* __restrict__ Wd, const float* __restrict__ bd,
                                                  float* __restrict__ dout, int last) {
    __shared__ __align__(16) FfnSmem u;
    int t = threadIdx.x;
    int pixBase = blockIdx.x * 128;
    int lane15 = t & 15;
    int quad   = (t >> 4) & 3;
    int wv     = t >> 6;
    int oct = t & 15;                          // store pixel oct 0..15
    int cg  = t >> 4;                          // store channel group 0..15

    // ---- GEMM1 B-fragments straight from global s[pix][ch] ----
    short8 bb0[2], bb1[2];
    #pragma unroll
    for (int kc = 0; kc < 2; ++kc) {
        int col = kc * 32 + quad * 8;
        bb0[kc] = *(const short8*)(in + (((size_t)(pixBase + wv * 32 + lane15)) << 6) + col);
        bb1[kc] = *(const short8*)(in + (((size_t)(pixBase + wv * 32 + 16 + lane15)) << 6) + col);
    }

    f32x4 acc[2][4];
    #pragma unroll
    for (int ns = 0; ns < 2; ++ns)
        #pragma unroll
        for (int mt = 0; mt < 4; ++mt) acc[ns][mt] = (f32x4){0.f, 0.f, 0.f, 0.f};

    // ---- GEMM1: 2-term, weights at use ----
    #pragma unroll
    for (int kc = 0; kc < 2; ++kc) {
        #pragma unroll
        for (int mt = 0; mt < 4; ++mt) {
            int s8 = mt * 2 + kc;
            const short8* wp = (const short8*)(w1f + (((size_t)s8 * 64 + (t & 63)) << 4));
            short8 wh = wp[0], wl = wp[1];
            acc[0][mt] = MFMA16(wh, bb0[kc], acc[0][mt]);
            acc[0][mt] = MFMA16(wl, bb0[kc], acc[0][mt]);
            acc[1][mt] = MFMA16(wh, bb1[kc], acc[1][mt]);
            acc[1][mt] = MFMA16(wl, bb1[kc], acc[1][mt]);
        }
    }

    // ---- epilogue1: gelu -> cvt_pk bf16 pairs -> tB (own-wave rows only) ----
    #pragma unroll
    for (int ns = 0; ns < 2; ++ns) {
        int row = wv * 32 + ns * 16 + lane15;
        #pragma unroll
        for (int mt = 0; mt < 4; ++mt) {
            const float* bp = b1v + mt * 16 + quad * 4;
            float g[4];
            #pragma unroll
            for (int r = 0; r < 4; ++r) g[r] = gelu_f(acc[ns][mt][r] + bp[r]);
            int cp = (mt * 16 + quad * 4) >> 1;
            u.tB[row * 33 + cp]     = cvt_pk_bf16(g[0], g[1]);
            u.tB[row * 33 + cp + 1] = cvt_pk_bf16(g[2], g[3]);
            acc[ns][mt] = (f32x4){0.f, 0.f, 0.f, 0.f};
        }
    }

    // NO barrier: GEMM2 reads only this wave's own rows, written above.

    // ---- GEMM2: 2-term, weights at use ----
    #pragma unroll
    for (int kc = 0; kc < 2; ++kc) {
        union { unsigned int w[4]; short8 v; } cb0, cb1;
        int row0 = wv * 32 + lane15;
        int row1 = wv * 32 + 16 + lane15;
        #pragma unroll
        for (int i = 0; i < 4; ++i) {
            cb0.w[i] = u.tB[row0 * 33 + kc * 16 + quad * 4 + i];
            cb1.w[i] = u.tB[row1 * 33 + kc * 16 + quad * 4 + i];
        }
        #pragma unroll
        for (int mt = 0; mt < 4; ++mt) {
            int s8 = mt * 2 + kc;
            const short8* wp = (const short8*)(w2f + (((size_t)s8 * 64 + (t & 63)) << 4));
            short8 wh = wp[0], wl = wp[1];
            acc[0][mt] = MFMA16(wh, cb0.v, acc[0][mt]);
            acc[0][mt] = MFMA16(wl, cb0.v, acc[0][mt]);
            acc[1][mt] = MFMA16(wh, cb1.v, acc[1][mt]);
            acc[1][mt] = MFMA16(wl, cb1.v, acc[1][mt]);
        }
    }

    // ---- h residual load (latency hidden by epilogue2 VALU) ----
    uint4 hr[4];
    #pragma unroll
    for (int j = 0; j < 4; ++j) {
        int c = cg + 16 * j;
        hr[j] = *(const uint4*)(out + (size_t)c * NPIX + pixBase + oct * 8);
    }

    __syncthreads();   // all waves done reading tB; oTb scatter may begin

    // ---- epilogue2: gelu -> bf16 oTb (aliases tB) ----
    #pragma unroll
    for (int ns = 0; ns < 2; ++ns) {
        int px = wv * 32 + ns * 16 + lane15;
        #pragma unroll
        for (int mt = 0; mt < 4; ++mt) {
            const float* bp = b2v + mt * 16 + quad * 4;
            #pragma unroll
            for (int r = 0; r < 4; ++r) {
                int c = mt * 16 + quad * 4 + r;
                u.oTb[c * 136 + px] = bf16_rne1(gelu_f(acc[ns][mt][r] + bp[r]));
            }
        }
    }
    __syncthreads();

    if (!last) {
        // ---- h(bf16) += increment: (c,oct) units, uint4, full 256-B sectors/wave ----
        #pragma unroll
        for (int j = 0; j < 4; ++j) {
            int c = cg + 16 * j;
            uint4 gv = *(const uint4*)&u.oTb[c * 136 + oct * 8];
            unsigned int hw[4] = {hr[j].x, hr[j].y, hr[j].z, hr[j].w};
            unsigned int gw[4] = {gv.x, gv.y, gv.z, gv.w};
            uint4 o;
            unsigned int* op = &o.x;
            #pragma unroll
            for (int i = 0; i < 4; ++i) {
                float f0 = bf16_tof((unsigned short)(hw[i] & 0xffffu)) + bf16_tof((unsigned short)(gw[i] & 0xffffu));
                float f1 = bf16_tof((unsigned short)(hw[i] >> 16))     + bf16_tof((unsigned short)(gw[i] >> 16));
                op[i] = cvt_pk_bf16(f0, f1);
            }
            *(uint4*)(out + (size_t)c * NPIX + pixBase + oct * 8) = o;
        }
    } else {
        // ---- fused decoder: dout = sum_c Wd[c]*(hres+gv) + bd ----
        float part[8] = {0.f,0.f,0.f,0.f,0.f,0.f,0.f,0.f};
        #pragma unroll
        for (int j = 0; j < 4; ++j) {
            int c = cg + 16 * j;
            float wd = Wd[c];
            uint4 gv = *(const uint4*)&u.oTb[c * 136 + oct * 8];
            unsigned int hw[4] = {hr[j].x, hr[j].y, hr[j].z, hr[j].w};
            unsigned int gw[4] = {gv.x, gv.y, gv.z, gv.w};
            #pragma unroll
            for (int i = 0; i < 4; ++i) {
                part[2*i]   += wd * (bf16_tof((unsigned short)(hw[i] & 0xffffu)) + bf16_tof((unsigned short)(gw[i] & 0xffffu)));
                part[2*i+1] += wd * (bf16_tof((unsigned short)(hw[i] >> 16))     + bf16_tof((unsigned short)(gw[i] >> 16)));
            }
        }
        __syncthreads();   // oTb reads done before red (aliases buffer) is written
        #pragma unroll
        for (int i = 0; i < 8; ++i)
            u.red[cg * 132 + oct * 8 + i] = part[i];
        __syncthreads();
        if (t < 128) {
            float sum = bd[0];
            #pragma unroll
            for (int gg = 0; gg < 16; ++gg)
                sum += u.red[gg * 132 + t];
            dout[pixBase + t] = sum;
        }
    }
}

extern "C" void kernel_launch(void* const* d_in, const int* in_sizes, int n_in,
                              void* d_out, int out_size, void* d_ws, size_t ws_size,
                              hipStream_t stream) {
    (void)in_sizes; (void)n_in; (void)out_size; (void)ws_size;
    const float* u   = (const float*)d_in[0];
    const float* xc  = (const float*)d_in[1];
    const float* We  = (const float*)d_in[2];
    const float* be  = (const float*)d_in[3];
    const float* W1  = (const float*)d_in[4];
    const float* b1  = (const float*)d_in[5];
    const float* W2  = (const float*)d_in[6];
    const float* b2  = (const float*)d_in[7];
    const float* Are = (const float*)d_in[8];
    const float* Aim = (const float*)d_in[9];
    const float* Wd  = (const float*)d_in[10];
    const float* bd  = (const float*)d_in[11];

    // workspace layout, ~93 MB used
    char* ws = (char*)d_ws;
    unsigned short* h = (unsigned short*)ws;                  // 32 MB (bf16) [ch][pix]
    unsigned short* s = (unsigned short*)(ws + (size_t)33554432); // 32 MB (bf16) [pix][ch]
    float* VfH = (float*)(ws + (size_t)67108864);             // 4 MB: [64][32][512]
    float* VfW = VfH + (size_t)1048576;                       // 4 MB
    unsigned int* VmH = (unsigned int*)(VfW + 1048576);       // 4 MB split-packed
    unsigned int* VmW = VmH + (size_t)1048576;                // 4 MB
    short* FbB = (short*)(VmW + 1048576);                     // 64 KB
    short* GbF = FbB + 32768;                                 // 64 KB
    short* Am  = GbF + 32768;                                 // 6 MB
    short* Wpk = Am  + (size_t)65536 * 48;                    // 128 KB

    k_setup<<<1312, 256, 0, stream>>>(W1, W2, Are, Aim, u, xc, We, be,
                                      FbB, GbF, Wpk, Am, h);

    for (int l = 0; l < 4; ++l) {
        k_fwd<<<dim3(64, 8, 2), 256, 0, stream>>>(h, FbB, VfH, VfW);
        k_mix2<<<512, 256, 0, stream>>>(VfH, VfW, Am + (size_t)(l * 2) * ASLAB, VmH, VmW);
        k_inv<<<dim3(32, 32), 256, 0, stream>>>(VmW, VmH, GbF, s);
        k_ffn2m<<<2048, 256, 0, stream>>>(s, h,
                                          Wpk + (size_t)(l * 2 + 0) * 8192, b1 + (size_t)l * 64,
                                          Wpk + (size_t)(l * 2 + 1) * 8192, b2 + (size_t)l * 64,
                                          Wd, bd, (float*)d_out, (l == 3) ? 1 : 0);
    }
}

// Round 14
// 378.857 us; speedup vs baseline: 1.0473x; 1.0072x over previous
//
#include <hip/hip_runtime.h>

#define NPIX (512*512)

typedef __attribute__((ext_vector_type(8))) short short8;   // 8 bf16 in 4 VGPRs
typedef __attribute__((ext_vector_type(4))) float f32x4;    // MFMA accumulator

#define MFMA16(A, B, C) __builtin_amdgcn_mfma_f32_16x16x32_bf16((A), (B), (C), 0, 0, 0)

// JAX gelu(approximate=True): x * sigmoid(2*sqrt(2/pi)*(x+0.044715x^3)).
// R7: exact f32 div -> v_rcp_f32 (rel-err ~2^-22 << bf16 ulp).
__device__ __forceinline__ float gelu_f(float x) {
    float z = 1.5957691216057308f * (x + 0.044715f * x * x * x);
    return x * __builtin_amdgcn_rcpf(1.0f + __expf(-z));
}

// f32 -> bf16 bits (RNE), bit-trick (k_setup only; launch-once)
__device__ __forceinline__ unsigned short bf16_rne(float x) {
    unsigned int b = __float_as_uint(x);
    unsigned int r = b + 0x7fffu + ((b >> 16) & 1u);
    return (unsigned short)(r >> 16);
}
__device__ __forceinline__ float bf16_tof(unsigned short h) {
    return __uint_as_float(((unsigned int)h) << 16);
}
// R10: packed 2xf32 -> 2xbf16 (RNE) in ONE VALU op. D[15:0]=bf16(lo),
// D[31:16]=bf16(hi). R12 validated bit-exact vs bit-trick (absmax canary).
__device__ __forceinline__ unsigned int cvt_pk_bf16(float lo, float hi) {
    unsigned int r;
    asm("v_cvt_pk_bf16_f32 %0, %1, %2" : "=v"(r) : "v"(lo), "v"(hi));
    return r;
}
// R12: 1-op scalar rne via cvt_pk (low 16 bits)
__device__ __forceinline__ unsigned short bf16_rne1(float x) {
    return (unsigned short)(cvt_pk_bf16(x, x) & 0xffffu);
}
// R12: split-pack (hi | lo<<16) in 4 ops (was 10): final cvt_pk's low16 =
// bf16(v) = hi, high16 = bf16(v - tof(hi)) = lo -- exactly the format.
__device__ __forceinline__ unsigned int bf16_split_pack(float v) {
    unsigned int t = cvt_pk_bf16(v, v);
    float f_hi = __uint_as_float(t << 16);
    return cvt_pk_bf16(v, v - f_hi);
}
// unzip 8 split-packed u32 (hi|lo<<16 per elem) -> hi-short8 / lo-short8
__device__ __forceinline__ void unzip8(const unsigned int* w, short8& h, short8& l) {
    union { unsigned int u[4]; short8 v; } hh, ll;
    #pragma unroll
    for (int i = 0; i < 4; ++i) {
        hh.u[i] = (w[2*i] & 0xffffu) | (w[2*i+1] << 16);
        ll.u[i] = (w[2*i] >> 16) | (w[2*i+1] & 0xffff0000u);
    }
    h = hh.v; l = ll.v;
}

#define ASLAB ((size_t)16 * 4 * 2 * 64 * 48)   // shorts per (l,ax) in Am

// Vm u32 index: [p][y>>4][m][y&15][ri]  (R1: full-128B-line single-wave stores)
#define VM_IDX(p, yT, m, yL) (((((size_t)(p) * 32 + (yT)) * 16 + (m)) * 16 + (yL)) * 2)

// ---------------------------------------------------------------------------
// Merged setup + encoder: blocks 0..15 basis tables, 16..31 FFN weights,
// 32..287 spectral A-weights, 288..1311 encoder (h stored bf16).
// ---------------------------------------------------------------------------
__global__ __launch_bounds__(256) void k_setup(const float* __restrict__ W1, const float* __restrict__ W2,
                                               const float* __restrict__ Are, const float* __restrict__ Aim,
                                               const float* __restrict__ u, const float* __restrict__ xc,
                                               const float* __restrict__ We, const float* __restrict__ be,
                                               short* __restrict__ FbB, short* __restrict__ GbF,
                                               short* __restrict__ Wpk, short* __restrict__ Am,
                                               unsigned short* __restrict__ h) {
    int b = blockIdx.x;
    int t = threadIdx.x;
    if (b < 16) {
        int id = b * 256 + t;
        int lane = id & 63;
        int quad = lane >> 4, l15 = lane & 15;
        short* dst;
        int n0, nstep, o0, ostep;
        float wscale = 1.0f;
        if (id < 2048) {
            int nt = (id >> 6) & 1, kc = id >> 7;
            dst = FbB + id * 16;
            n0 = kc * 32 + quad * 8; nstep = 1;
            o0 = nt * 16 + l15;      ostep = 0;
        } else {
            int id2 = id - 2048;
            dst = GbF + id2 * 16;
            int tt = id2 >> 6;
            n0 = tt * 16 + l15;      nstep = 0;
            o0 = quad * 8;           ostep = 1;
            wscale = 1.0f / 512.0f;
        }
        #pragma unroll
        for (int j = 0; j < 8; ++j) {
            int n = n0 + nstep * j;
            int o = o0 + ostep * j;
            int m = o >> 1, ri = o & 1;
            int k = (n * m) & 511;
            float sv, cv;
            sincosf(6.283185307179586f * (1.0f / 512.0f) * (float)k, &sv, &cv);
            float v = ri ? -sv : cv;
            if (id >= 2048) v *= (m == 0 ? 1.0f : 2.0f) * wscale;
            unsigned short hi = bf16_rne(v);
            dst[j]     = (short)hi;
            dst[8 + j] = (short)bf16_rne(v - bf16_tof(hi));
        }
    } else if (b < 32) {
        int tid = (b - 16) * 256 + t;
        int lane = tid & 63;
        int kc = (tid >> 6) & 1;
        int mt = (tid >> 7) & 3;
        int wg = tid >> 9;
        int layer = wg >> 1, which = wg & 1;
        const float* Wsrc = (which ? W2 : W1) + (size_t)layer * 4096;
        int o  = mt * 16 + (lane & 15);
        int c0 = kc * 32 + ((lane >> 4) & 3) * 8;
        short* dst = Wpk + (size_t)tid * 16;
        #pragma unroll
        for (int j = 0; j < 8; ++j) {
            float x = Wsrc[o * 64 + c0 + j];
            unsigned short hi = bf16_rne(x);
            dst[j]     = (short)hi;
            dst[8 + j] = (short)bf16_rne(x - bf16_tof(hi));
        }
    } else if (b < 288) {
        int id = (b - 32) * 256 + t;
        int lane = id & 63;
        int kc  = (id >> 6) & 1;
        int mt  = (id >> 7) & 3;
        int m   = (id >> 9) & 15;
        int lax = id >> 13;
        int l = lax >> 1, ax = lax & 1;
        int o  = mt * 16 + (lane & 15);
        int i0 = kc * 32 + ((lane >> 4) & 3) * 8;
        short* dst = Am + (size_t)id * 48;
        #pragma unroll
        for (int j = 0; j < 8; ++j) {
            size_t src = (((size_t)(l * 64 + o) * 64 + (i0 + j)) * 16 + m) * 2 + ax;
            float ar = Are[src], ai = Aim[src];
            unsigned short hh;
            hh = bf16_rne(ar);  dst[j]      = (short)hh; dst[8 + j]  = (short)bf16_rne(ar - bf16_tof(hh));
            hh = bf16_rne(ai);  dst[16 + j] = (short)hh; dst[24 + j] = (short)bf16_rne(ai - bf16_tof(hh));
            hh = bf16_rne(-ai); dst[32 + j] = (short)hh; dst[40 + j] = (short)bf16_rne(-ai - bf16_tof(hh));
        }
    } else {
        // encoder: h[p][pix] = bf16(We.x + be)
        int pix = (b - 288) * 256 + t;
        float x0 = xc[pix], x1 = xc[NPIX + pix], uu = u[pix];
        #pragma unroll 8
        for (int p = 0; p < 64; ++p) {
            float v = We[p * 3] * x0 + We[p * 3 + 1] * x1 + We[p * 3 + 2] * uu + be[p];
            h[(size_t)p * NPIX + pix] = bf16_rne(v);
        }
    }
}

// ---------------------------------------------------------------------------
// Merged forward DFT, both axes, h in bf16. R13: TWO CHANNELS (p) PER BLOCK,
// grid(32 p-pair, 8 ntile, 2 axis): each FbB A-fragment load now feeds 4
// MFMA (2 p x 2 split-terms) instead of 2 -- VMEM-issue per MFMA drops
// ~40% and two independent acc chains double ILP. axis0: one transpose
// tile per p (2 x 8448 B = 16.9 KB, single-buffered, 2 barriers/chunk --
// R8 dbuf was neutral, dropped to keep 8 blocks/CU).
// ---------------------------------------------------------------------------
__global__ __launch_bounds__(256) void k_fwd(const unsigned short* __restrict__ h, const short* __restrict__ FbB,
                                             float* __restrict__ VfH, float* __restrict__ VfW) {
    __shared__ unsigned short T[2][64 * 66];  // one tile per p, 2 x 8448 B
    int t = threadIdx.x;
    int ntb = blockIdx.y, axis = blockIdx.z;
    int p0 = blockIdx.x * 2;
    int wv = t >> 6, lane = t & 63, quad = lane >> 4, l15 = lane & 15;
    int n = ntb * 64 + wv * 16 + l15;
    int nL = wv * 16 + l15;
    f32x4 acc[2][2];   // [p][mt]
    #pragma unroll
    for (int pi = 0; pi < 2; ++pi)
        #pragma unroll
        for (int mt = 0; mt < 2; ++mt) acc[pi][mt] = (f32x4){0.f,0.f,0.f,0.f};
    if (axis == 1) {
        #pragma unroll 4
        for (int kc = 0; kc < 16; ++kc) {
            int kb = kc * 32 + quad * 8;
            short8 Bv0 = *(const short8*)(h + ((size_t)p0 * 512 + n) * 512 + kb);
            short8 Bv1 = *(const short8*)(h + ((size_t)(p0 + 1) * 512 + n) * 512 + kb);
            #pragma unroll
            for (int mt = 0; mt < 2; ++mt) {
                const short8* ap = (const short8*)(FbB + (((kc * 2 + mt) * 64 + lane) << 4));
                short8 Ah = ap[0], Al = ap[1];
                acc[0][mt] = MFMA16(Ah, Bv0, acc[0][mt]);
                acc[0][mt] = MFMA16(Al, Bv0, acc[0][mt]);
                acc[1][mt] = MFMA16(Ah, Bv1, acc[1][mt]);
                acc[1][mt] = MFMA16(Al, Bv1, acc[1][mt]);
            }
        }
    } else {
        int kp = t >> 3, c = t & 7;          // k-pair 0..31, n-oct 0..7
        for (int ch = 0; ch < 8; ++ch) {
            int k0 = ch * 64;
            const unsigned short* r0 = h + ((size_t)p0 * 512 + k0 + 2 * kp) * 512 + ntb * 64 + c * 8;
            const unsigned short* r1 = h + ((size_t)(p0 + 1) * 512 + k0 + 2 * kp) * 512 + ntb * 64 + c * 8;
            uint4 a0 = *(const uint4*)r0;
            uint4 b0 = *(const uint4*)(r0 + 512);
            uint4 a1 = *(const uint4*)r1;
            uint4 b1 = *(const uint4*)(r1 + 512);
            unsigned int aw0[4] = {a0.x, a0.y, a0.z, a0.w};
            unsigned int bw0[4] = {b0.x, b0.y, b0.z, b0.w};
            unsigned int aw1[4] = {a1.x, a1.y, a1.z, a1.w};
            unsigned int bw1[4] = {b1.x, b1.y, b1.z, b1.w};
            __syncthreads();                  // previous chunk fully consumed
            #pragma unroll
            for (int i = 0; i < 4; ++i) {
                int n0 = c * 8 + 2 * i;
                *(unsigned int*)&T[0][n0 * 66 + 2 * kp]       = (aw0[i] & 0xffffu) | (bw0[i] << 16);
                *(unsigned int*)&T[0][(n0 + 1) * 66 + 2 * kp] = (aw0[i] >> 16) | (bw0[i] & 0xffff0000u);
                *(unsigned int*)&T[1][n0 * 66 + 2 * kp]       = (aw1[i] & 0xffffu) | (bw1[i] << 16);
                *(unsigned int*)&T[1][(n0 + 1) * 66 + 2 * kp] = (aw1[i] >> 16) | (bw1[i] & 0xffff0000u);
            }
            __syncthreads();
            #pragma unroll
            for (int kcl = 0; kcl < 2; ++kcl) {
                int kc = ch * 2 + kcl;
                union { unsigned int w[4]; short8 v; } bb0, bb1;
                #pragma unroll
                for (int d = 0; d < 4; ++d) {
                    bb0.w[d] = *(const unsigned int*)&T[0][nL * 66 + kcl * 32 + quad * 8 + 2 * d];
                    bb1.w[d] = *(const unsigned int*)&T[1][nL * 66 + kcl * 32 + quad * 8 + 2 * d];
                }
                #pragma unroll
                for (int mt = 0; mt < 2; ++mt) {
                    const short8* ap = (const short8*)(FbB + (((kc * 2 + mt) * 64 + lane) << 4));
                    short8 Ah = ap[0], Al = ap[1];
                    acc[0][mt] = MFMA16(Ah, bb0.v, acc[0][mt]);
                    acc[0][mt] = MFMA16(Al, bb0.v, acc[0][mt]);
                    acc[1][mt] = MFMA16(Ah, bb1.v, acc[1][mt]);
                    acc[1][mt] = MFMA16(Al, bb1.v, acc[1][mt]);
                }
            }
        }
    }
    #pragma unroll
    for (int pi = 0; pi < 2; ++pi) {
        float* vp = (axis ? VfW : VfH) + (size_t)(p0 + pi) * 32 * 512;
        #pragma unroll
        for (int mt = 0; mt < 2; ++mt)
            #pragma unroll
            for (int r = 0; r < 4; ++r)
                vp[(size_t)(mt * 16 + quad * 4 + r) * 512 + n] = acc[pi][mt][r];
    }
}

// ---------------------------------------------------------------------------
// Merged mode mixing, both axes. Epilogue writes Vm SPLIT-PACKED u32 in the
// [p][y>>4][m][y&15][ri] layout: one 128-B contiguous line per (o,r) store.
// grid 512 (axis = bid>>8; m = bid&15, otile = (bid>>4)&15), block 256.
// R12: split_pack via cvt_pk (4 ops, was 10) in staging + epilogue.
// ---------------------------------------------------------------------------
__global__ __launch_bounds__(256) void k_mix2(const float* __restrict__ VfH, const float* __restrict__ VfW,
                                              const short* __restrict__ AmL,
                                              unsigned int* __restrict__ VmH, unsigned int* __restrict__ VmW) {
    __shared__ unsigned int BT[2 * 64 * 33];
    int bid = blockIdx.x;
    int axis = bid >> 8;
    int m  = bid & 15;
    int ot = (bid >> 4) & 15;
    const float* Vf = axis ? VfW : VfH;
    unsigned int* Vm = axis ? VmW : VmH;
    const short* Am = AmL + (size_t)axis * ASLAB;
    int t = threadIdx.x;
    #pragma unroll
    for (int it = 0; it < 16; ++it) {
        int idx = it * 256 + t;
        int oth = idx & 31, ri = (idx >> 5) & 1, i = idx >> 6;
        float v = Vf[((size_t)i * 32 + m * 2 + ri) * 512 + ot * 32 + oth];
        BT[(ri * 64 + i) * 33 + oth] = bf16_split_pack(v);
    }
    __syncthreads();
    int wv = t >> 6, lane = t & 63, quad = lane >> 4, l15 = lane & 15;
    int nt = wv & 1, mtp = wv >> 1;
    f32x4 aR[2], aI[2];
    aR[0]=(f32x4){0.f,0.f,0.f,0.f}; aR[1]=aR[0]; aI[0]=aR[0]; aI[1]=aR[0];
    #pragma unroll
    for (int kc = 0; kc < 2; ++kc) {
        short8 Brh, Brl, Bih, Bil;
        #pragma unroll
        for (int j = 0; j < 8; ++j) {
            int i = kc * 32 + quad * 8 + j;
            unsigned int br = BT[i * 33 + nt * 16 + l15];
            unsigned int bi = BT[(64 + i) * 33 + nt * 16 + l15];
            Brh[j] = (short)(br & 0xffffu); Brl[j] = (short)(br >> 16);
            Bih[j] = (short)(bi & 0xffffu); Bil[j] = (short)(bi >> 16);
        }
        #pragma unroll
        for (int mi = 0; mi < 2; ++mi) {
            int mt = mtp * 2 + mi;
            const short8* ap = (const short8*)(Am + ((size_t)(((m * 4 + mt) * 2 + kc) * 64 + lane)) * 48);
            short8 Arh = ap[0], Arl = ap[1], Aih = ap[2], Ail = ap[3], Anh = ap[4], Anl = ap[5];
            aR[mi] = MFMA16(Arh, Brh, aR[mi]);
            aR[mi] = MFMA16(Arl, Brh, aR[mi]);
            aR[mi] = MFMA16(Arh, Brl, aR[mi]);
            aR[mi] = MFMA16(Anh, Bih, aR[mi]);
            aR[mi] = MFMA16(Anl, Bih, aR[mi]);
            aR[mi] = MFMA16(Anh, Bil, aR[mi]);
            aI[mi] = MFMA16(Arh, Bih, aI[mi]);
            aI[mi] = MFMA16(Arl, Bih, aI[mi]);
            aI[mi] = MFMA16(Arh, Bil, aI[mi]);
            aI[mi] = MFMA16(Aih, Brh, aI[mi]);
            aI[mi] = MFMA16(Ail, Brh, aI[mi]);
            aI[mi] = MFMA16(Aih, Brl, aI[mi]);
        }
    }
    int yT = ot * 2 + nt;
    #pragma unroll
    for (int mi = 0; mi < 2; ++mi) {
        int o = (mtp * 2 + mi) * 16 + quad * 4;
        #pragma unroll
        for (int r = 0; r < 4; ++r) {
            uint2 v;
            v.x = bf16_split_pack(aR[mi][r]);
            v.y = bf16_split_pack(aI[mi][r]);
            *(uint2*)(Vm + VM_IDX(o + r, yT, m, l15)) = v;
        }
    }
}

// ---------------------------------------------------------------------------
// Fused inverse DFT -> s in [pix][ch] layout (R6).
// grid(32 xt, 32 yt): block = 16x16 pixel patch x ALL 64 channels.
// Results transposed through LDS with permuted pixel index pp=(r*16+x)*4+quad
// (store banks = perm mod 32, 2-way free), drained as FULL 128-B lines.
// R12: 1-op cvt_pk rne for sT stores (was 3-op bit-trick, 64/thread).
// ---------------------------------------------------------------------------
__global__ __launch_bounds__(256) void k_inv(const unsigned int* __restrict__ VmW, const unsigned int* __restrict__ VmH,
                                             const short* __restrict__ GbF, unsigned short* __restrict__ s) {
    __shared__ unsigned short sT[256 * 66];   // [pp][ch + pad], 33792 B
    int t = threadIdx.x;
    int xt = blockIdx.x, yt = blockIdx.y;
    int wv = t >> 6, lane = t & 63, quad = lane >> 4, l15 = lane & 15;
    const short8* gy = (const short8*)(GbF + ((yt * 64 + lane) << 4));
    short8 A1h = gy[0], A1l = gy[1];
    const short8* gx = (const short8*)(GbF + ((xt * 64 + lane) << 4));
    short8 B2h = gx[0], B2l = gx[1];
    int p0 = wv * 16;
    for (int pp = 0; pp < 16; ++pp) {
        int p = p0 + pp;
        unsigned int aw[8], bw[8];
        #pragma unroll
        for (int tt = 0; tt < 4; ++tt) {
            uint2 qa = *(const uint2*)(VmW + VM_IDX(p, yt, quad * 4 + tt, l15));
            uint2 qb = *(const uint2*)(VmH + VM_IDX(p, xt, quad * 4 + tt, l15));
            aw[2*tt] = qa.x; aw[2*tt+1] = qa.y;
            bw[2*tt] = qb.x; bw[2*tt+1] = qb.y;
        }
        short8 A2h, A2l, B1h, B1l;
        unzip8(aw, A2h, A2l);
        unzip8(bw, B1h, B1l);
        f32x4 acc = (f32x4){0.f,0.f,0.f,0.f};
        acc = MFMA16(A1h, B1h, acc);
        acc = MFMA16(A1l, B1h, acc);
        acc = MFMA16(A1h, B1l, acc);
        acc = MFMA16(A2h, B2h, acc);
        acc = MFMA16(A2l, B2h, acc);
        acc = MFMA16(A2h, B2l, acc);
        #pragma unroll
        for (int r = 0; r < 4; ++r)
            sT[(((r * 16 + l15) << 2) + quad) * 66 + p] = bf16_rne1(acc[r]);
    }
    __syncthreads();
    #pragma unroll
    for (int it = 0; it < 8; ++it) {
        int ppix = it * 32 + (t >> 3);
        int part = t & 7;
        const unsigned int* lp = (const unsigned int*)&sT[ppix * 66 + part * 8];
        uint4 v; v.x = lp[0]; v.y = lp[1]; v.z = lp[2]; v.w = lp[3];
        int q = ppix & 3, rx = ppix >> 2;
        int xl = rx & 15, r = rx >> 4;
        int y = yt * 16 + q * 4 + r;
        int x = xt * 16 + xl;
        *(uint4*)(s + (((size_t)y * 512 + x) << 6) + part * 8) = v;
    }
}

// ---------------------------------------------------------------------------
// MFMA FFN, 128-px tile (grid 2048): h(bf16) += gelu(W2.gelu(W1.s+b1)+b2).
// R9 structure (single-tile, no pre-GEMM barrier). s is [pix][ch]: GEMM1
// B-frags direct short8 global loads. tB own-wave rows (no barrier
// epi1->GEMM2); oTb aliases tB (barrier before epi2). (256,4), rcp-gelu.
// R10: cvt_pk for epi1 tB words and h-increment. R12: 1-op rne for epi2 oTb.
// ---------------------------------------------------------------------------
union FfnSmem {
    unsigned int  tB[128 * 33];     // 16896 B, GEMM1->GEMM2 bf16 pairs
    unsigned short oTb[64 * 136];   // 17408 B, epilogue2 bf16 transpose tile
    float         red[16 * 132];    // 8448 B, decoder partial sums
};

__global__ __launch_bounds__(256, 4) void k_ffn2m(const unsigned short* __restrict__ in, unsigned short* __restrict__ out,
                                                  const short* __restrict__ w1f, const float* __restrict__ b1v,
                                                  const short* __restrict__ w2f, const float* __restrict__ b2v,
                                                  const float* __restrict__ Wd, const float* __restrict__ bd,
                                                  float* __restrict__ dout, int last) {
    __shared__ __align__(16) FfnSmem u;
    int t = threadIdx.x;
    int pixBase = blockIdx.x * 128;
    int lane15 = t & 15;
    int quad   = (t >> 4) & 3;
    int wv     = t >> 6;
    int oct = t & 15;                          // store pixel oct 0..15
    int cg  = t >> 4;                          // store channel group 0..15

    // ---- GEMM1 B-fragments straight from global s[pix][ch] ----
    short8 bb0[2], bb1[2];
    #pragma unroll
    for (int kc = 0; kc < 2; ++kc) {
        int col = kc * 32 + quad * 8;
        bb0[kc] = *(const short8*)(in + (((size_t)(pixBase + wv * 32 + lane15)) << 6) + col);
        bb1[kc] = *(const short8*)(in + (((size_t)(pixBase + wv * 32 + 16 + lane15)) << 6) + col);
    }

    f32x4 acc[2][4];
    #pragma unroll
    for (int ns = 0; ns < 2; ++ns)
        #pragma unroll
        for (int mt = 0; mt < 4; ++mt) acc[ns][mt] = (f32x4){0.f, 0.f, 0.f, 0.f};

    // ---- GEMM1: 2-term, weights at use ----
    #pragma unroll
    for (int kc = 0; kc < 2; ++kc) {
        #pragma unroll
        for (int mt = 0; mt < 4; ++mt) {
            int s8 = mt * 2 + kc;
            const short8* wp = (const short8*)(w1f + (((size_t)s8 * 64 + (t & 63)) << 4));
            short8 wh = wp[0], wl = wp[1];
            acc[0][mt] = MFMA16(wh, bb0[kc], acc[0][mt]);
            acc[0][mt] = MFMA16(wl, bb0[kc], acc[0][mt]);
            acc[1][mt] = MFMA16(wh, bb1[kc], acc[1][mt]);
            acc[1][mt] = MFMA16(wl, bb1[kc], acc[1][mt]);
        }
    }

    // ---- epilogue1: gelu -> cvt_pk bf16 pairs -> tB (own-wave rows only) ----
    #pragma unroll
    for (int ns = 0; ns < 2; ++ns) {
        int row = wv * 32 + ns * 16 + lane15;
        #pragma unroll
        for (int mt = 0; mt < 4; ++mt) {
            const float* bp = b1v + mt * 16 + quad * 4;
            float g[4];
            #pragma unroll
            for (int r = 0; r < 4; ++r) g[r] = gelu_f(acc[ns][mt][r] + bp[r]);
            int cp = (mt * 16 + quad * 4) >> 1;
            u.tB[row * 33 + cp]     = cvt_pk_bf16(g[0], g[1]);
            u.tB[row * 33 + cp + 1] = cvt_pk_bf16(g[2], g[3]);
            acc[ns][mt] = (f32x4){0.f, 0.f, 0.f, 0.f};
        }
    }

    // NO barrier: GEMM2 reads only this wave's own rows, written above.

    // ---- GEMM2: 2-term, weights at use ----
    #pragma unroll
    for (int kc = 0; kc < 2; ++kc) {
        union { unsigned int w[4]; short8 v; } cb0, cb1;
        int row0 = wv * 32 + lane15;
        int row1 = wv * 32 + 16 + lane15;
        #pragma unroll
        for (int i = 0; i < 4; ++i) {
            cb0.w[i] = u.tB[row0 * 33 + kc * 16 + quad * 4 + i];
            cb1.w[i] = u.tB[row1 * 33 + kc * 16 + quad * 4 + i];
        }
        #pragma unroll
        for (int mt = 0; mt < 4; ++mt) {
            int s8 = mt * 2 + kc;
            const short8* wp = (const short8*)(w2f + (((size_t)s8 * 64 + (t & 63)) << 4));
            short8 wh = wp[0], wl = wp[1];
            acc[0][mt] = MFMA16(wh, cb0.v, acc[0][mt]);
            acc[0][mt] = MFMA16(wl, cb0.v, acc[0][mt]);
            acc[1][mt] = MFMA16(wh, cb1.v, acc[1][mt]);
            acc[1][mt] = MFMA16(wl, cb1.v, acc[1][mt]);
        }
    }

    // ---- h residual load (latency hidden by epilogue2 VALU) ----
    uint4 hr[4];
    #pragma unroll
    for (int j = 0; j < 4; ++j) {
        int c = cg + 16 * j;
        hr[j] = *(const uint4*)(out + (size_t)c * NPIX + pixBase + oct * 8);
    }

    __syncthreads();   // all waves done reading tB; oTb scatter may begin

    // ---- epilogue2: gelu -> bf16 oTb (aliases tB) ----
    #pragma unroll
    for (int ns = 0; ns < 2; ++ns) {
        int px = wv * 32 + ns * 16 + lane15;
        #pragma unroll
        for (int mt = 0; mt < 4; ++mt) {
            const float* bp = b2v + mt * 16 + quad * 4;
            #pragma unroll
            for (int r = 0; r < 4; ++r) {
                int c = mt * 16 + quad * 4 + r;
                u.oTb[c * 136 + px] = bf16_rne1(gelu_f(acc[ns][mt][r] + bp[r]));
            }
        }
    }
    __syncthreads();

    if (!last) {
        // ---- h(bf16) += increment: (c,oct) units, uint4, full 256-B sectors/wave ----
        #pragma unroll
        for (int j = 0; j < 4; ++j) {
            int c = cg + 16 * j;
            uint4 gv = *(const uint4*)&u.oTb[c * 136 + oct * 8];
            unsigned int hw[4] = {hr[j].x, hr[j].y, hr[j].z, hr[j].w};
            unsigned int gw[4] = {gv.x, gv.y, gv.z, gv.w};
            uint4 o;
            unsigned int* op = &o.x;
            #pragma unroll
            for (int i = 0; i < 4; ++i) {
                float f0 = bf16_tof((unsigned short)(hw[i] & 0xffffu)) + bf16_tof((unsigned short)(gw[i] & 0xffffu));
                float f1 = bf16_tof((unsigned short)(hw[i] >> 16))     + bf16_tof((unsigned short)(gw[i] >> 16));
                op[i] = cvt_pk_bf16(f0, f1);
            }
            *(uint4*)(out + (size_t)c * NPIX + pixBase + oct * 8) = o;
        }
    } else {
        // ---- fused decoder: dout = sum_c Wd[c]*(hres+gv) + bd ----
        float part[8] = {0.f,0.f,0.f,0.f,0.f,0.f,0.f,0.f};
        #pragma unroll
        for (int j = 0; j < 4; ++j) {
            int c = cg + 16 * j;
            float wd = Wd[c];
            uint4 gv = *(const uint4*)&u.oTb[c * 136 + oct * 8];
            unsigned int hw[4] = {hr[j].x, hr[j].y, hr[j].z, hr[j].w};
            unsigned int gw[4] = {gv.x, gv.y, gv.z, gv.w};
            #pragma unroll
            for (int i = 0; i < 4; ++i) {
                part[2*i]   += wd * (bf16_tof((unsigned short)(hw[i] & 0xffffu)) + bf16_tof((unsigned short)(gw[i] & 0xffffu)));
                part[2*i+1] += wd * (bf16_tof((unsigned short)(hw[i] >> 16))     + bf16_tof((unsigned short)(gw[i] >> 16)));
            }
        }
        __syncthreads();   // oTb reads done before red (aliases buffer) is written
        #pragma unroll
        for (int i = 0; i < 8; ++i)
            u.red[cg * 132 + oct * 8 + i] = part[i];
        __syncthreads();
        if (t < 128) {
            float sum = bd[0];
            #pragma unroll
            for (int gg = 0; gg < 16; ++gg)
                sum += u.red[gg * 132 + t];
            dout[pixBase + t] = sum;
        }
    }
}

extern "C" void kernel_launch(void* const* d_in, const int* in_sizes, int n_in,
                              void* d_out, int out_size, void* d_ws, size_t ws_size,
                              hipStream_t stream) {
    (void)in_sizes; (void)n_in; (void)out_size; (void)ws_size;
    const float* u   = (const float*)d_in[0];
    const float* xc  = (const float*)d_in[1];
    const float* We  = (const float*)d_in[2];
    const float* be  = (const float*)d_in[3];
    const float* W1  = (const float*)d_in[4];
    const float* b1  = (const float*)d_in[5];
    const float* W2  = (const float*)d_in[6];
    const float* b2  = (const float*)d_in[7];
    const float* Are = (const float*)d_in[8];
    const float* Aim = (const float*)d_in[9];
    const float* Wd  = (const float*)d_in[10];
    const float* bd  = (const float*)d_in[11];

    // workspace layout, ~93 MB used
    char* ws = (char*)d_ws;
    unsigned short* h = (unsigned short*)ws;                  // 32 MB (bf16) [ch][pix]
    unsigned short* s = (unsigned short*)(ws + (size_t)33554432); // 32 MB (bf16) [pix][ch]
    float* VfH = (float*)(ws + (size_t)67108864);             // 4 MB: [64][32][512]
    float* VfW = VfH + (size_t)1048576;                       // 4 MB
    unsigned int* VmH = (unsigned int*)(VfW + 1048576);       // 4 MB split-packed
    unsigned int* VmW = VmH + (size_t)1048576;                // 4 MB
    short* FbB = (short*)(VmW + 1048576);                     // 64 KB
    short* GbF = FbB + 32768;                                 // 64 KB
    short* Am  = GbF + 32768;                                 // 6 MB
    short* Wpk = Am  + (size_t)65536 * 48;                    // 128 KB

    k_setup<<<1312, 256, 0, stream>>>(W1, W2, Are, Aim, u, xc, We, be,
                                      FbB, GbF, Wpk, Am, h);

    for (int l = 0; l < 4; ++l) {
        k_fwd<<<dim3(32, 8, 2), 256, 0, stream>>>(h, FbB, VfH, VfW);
        k_mix2<<<512, 256, 0, stream>>>(VfH, VfW, Am + (size_t)(l * 2) * ASLAB, VmH, VmW);
        k_inv<<<dim3(32, 32), 256, 0, stream>>>(VmW, VmH, GbF, s);
        k_ffn2m<<<2048, 256, 0, stream>>>(s, h,
                                          Wpk + (size_t)(l * 2 + 0) * 8192, b1 + (size_t)l * 64,
                                          Wpk + (size_t)(l * 2 + 1) * 8192, b2 + (size_t)l * 64,
                                          Wd, bd, (float*)d_out, (l == 3) ? 1 : 0);
    }
}

// Round 15
// 356.054 us; speedup vs baseline: 1.1144x; 1.0640x over previous
//
#include <hip/hip_runtime.h>

#define NPIX (512*512)

typedef __attribute__((ext_vector_type(8))) short short8;   // 8 bf16 in 4 VGPRs
typedef __attribute__((ext_vector_type(4))) float f32x4;    // MFMA accumulator

#define MFMA16(A, B, C) __builtin_amdgcn_mfma_f32_16x16x32_bf16((A), (B), (C), 0, 0, 0)

// JAX gelu(approximate=True): x * sigmoid(2*sqrt(2/pi)*(x+0.044715x^3)).
// R7: exact f32 div -> v_rcp_f32 (rel-err ~2^-22 << bf16 ulp).
__device__ __forceinline__ float gelu_f(float x) {
    float z = 1.5957691216057308f * (x + 0.044715f * x * x * x);
    return x * __builtin_amdgcn_rcpf(1.0f + __expf(-z));
}

// f32 -> bf16 bits (RNE), bit-trick (k_setup only; launch-once)
__device__ __forceinline__ unsigned short bf16_rne(float x) {
    unsigned int b = __float_as_uint(x);
    unsigned int r = b + 0x7fffu + ((b >> 16) & 1u);
    return (unsigned short)(r >> 16);
}
__device__ __forceinline__ float bf16_tof(unsigned short h) {
    return __uint_as_float(((unsigned int)h) << 16);
}
// R10: packed 2xf32 -> 2xbf16 (RNE) in ONE VALU op. D[15:0]=bf16(lo),
// D[31:16]=bf16(hi). R12 validated bit-exact vs bit-trick (absmax canary).
__device__ __forceinline__ unsigned int cvt_pk_bf16(float lo, float hi) {
    unsigned int r;
    asm("v_cvt_pk_bf16_f32 %0, %1, %2" : "=v"(r) : "v"(lo), "v"(hi));
    return r;
}
// R12: 1-op scalar rne via cvt_pk (low 16 bits)
__device__ __forceinline__ unsigned short bf16_rne1(float x) {
    return (unsigned short)(cvt_pk_bf16(x, x) & 0xffffu);
}

#define ASLAB ((size_t)16 * 4 * 2 * 64 * 48)   // shorts per (l,ax) in Am

// R14: Vm stored as SEPARATE hi/lo planes, u32 = {R|I<<16} per (m,yL).
// Reader fragment word A2h.u[tt] == hi-plane word directly -> unzip8 GONE.
// u32 index: [p][y>>4][m][y&15]; writer: 16 lanes x 4 B = full 64-B sector.
#define VMS(p, yT, m, yL) ((((size_t)(p) * 32 + (yT)) * 16 + (m)) * 16 + (yL))

// ---------------------------------------------------------------------------
// Merged setup + encoder: blocks 0..15 basis tables, 16..31 FFN weights,
// 32..287 spectral A-weights, 288..1311 encoder (h stored bf16).
// ---------------------------------------------------------------------------
__global__ __launch_bounds__(256) void k_setup(const float* __restrict__ W1, const float* __restrict__ W2,
                                               const float* __restrict__ Are, const float* __restrict__ Aim,
                                               const float* __restrict__ u, const float* __restrict__ xc,
                                               const float* __restrict__ We, const float* __restrict__ be,
                                               short* __restrict__ FbB, short* __restrict__ GbF,
                                               short* __restrict__ Wpk, short* __restrict__ Am,
                                               unsigned short* __restrict__ h) {
    int b = blockIdx.x;
    int t = threadIdx.x;
    if (b < 16) {
        int id = b * 256 + t;
        int lane = id & 63;
        int quad = lane >> 4, l15 = lane & 15;
        short* dst;
        int n0, nstep, o0, ostep;
        float wscale = 1.0f;
        if (id < 2048) {
            int nt = (id >> 6) & 1, kc = id >> 7;
            dst = FbB + id * 16;
            n0 = kc * 32 + quad * 8; nstep = 1;
            o0 = nt * 16 + l15;      ostep = 0;
        } else {
            int id2 = id - 2048;
            dst = GbF + id2 * 16;
            int tt = id2 >> 6;
            n0 = tt * 16 + l15;      nstep = 0;
            o0 = quad * 8;           ostep = 1;
            wscale = 1.0f / 512.0f;
        }
        #pragma unroll
        for (int j = 0; j < 8; ++j) {
            int n = n0 + nstep * j;
            int o = o0 + ostep * j;
            int m = o >> 1, ri = o & 1;
            int k = (n * m) & 511;
            float sv, cv;
            sincosf(6.283185307179586f * (1.0f / 512.0f) * (float)k, &sv, &cv);
            float v = ri ? -sv : cv;
            if (id >= 2048) v *= (m == 0 ? 1.0f : 2.0f) * wscale;
            unsigned short hi = bf16_rne(v);
            dst[j]     = (short)hi;
            dst[8 + j] = (short)bf16_rne(v - bf16_tof(hi));
        }
    } else if (b < 32) {
        int tid = (b - 16) * 256 + t;
        int lane = tid & 63;
        int kc = (tid >> 6) & 1;
        int mt = (tid >> 7) & 3;
        int wg = tid >> 9;
        int layer = wg >> 1, which = wg & 1;
        const float* Wsrc = (which ? W2 : W1) + (size_t)layer * 4096;
        int o  = mt * 16 + (lane & 15);
        int c0 = kc * 32 + ((lane >> 4) & 3) * 8;
        short* dst = Wpk + (size_t)tid * 16;
        #pragma unroll
        for (int j = 0; j < 8; ++j) {
            float x = Wsrc[o * 64 + c0 + j];
            unsigned short hi = bf16_rne(x);
            dst[j]     = (short)hi;
            dst[8 + j] = (short)bf16_rne(x - bf16_tof(hi));
        }
    } else if (b < 288) {
        int id = (b - 32) * 256 + t;
        int lane = id & 63;
        int kc  = (id >> 6) & 1;
        int mt  = (id >> 7) & 3;
        int m   = (id >> 9) & 15;
        int lax = id >> 13;
        int l = lax >> 1, ax = lax & 1;
        int o  = mt * 16 + (lane & 15);
        int i0 = kc * 32 + ((lane >> 4) & 3) * 8;
        short* dst = Am + (size_t)id * 48;
        #pragma unroll
        for (int j = 0; j < 8; ++j) {
            size_t src = (((size_t)(l * 64 + o) * 64 + (i0 + j)) * 16 + m) * 2 + ax;
            float ar = Are[src], ai = Aim[src];
            unsigned short hh;
            hh = bf16_rne(ar);  dst[j]      = (short)hh; dst[8 + j]  = (short)bf16_rne(ar - bf16_tof(hh));
            hh = bf16_rne(ai);  dst[16 + j] = (short)hh; dst[24 + j] = (short)bf16_rne(ai - bf16_tof(hh));
            hh = bf16_rne(-ai); dst[32 + j] = (short)hh; dst[40 + j] = (short)bf16_rne(-ai - bf16_tof(hh));
        }
    } else {
        // encoder: h[p][pix] = bf16(We.x + be)
        int pix = (b - 288) * 256 + t;
        float x0 = xc[pix], x1 = xc[NPIX + pix], uu = u[pix];
        #pragma unroll 8
        for (int p = 0; p < 64; ++p) {
            float v = We[p * 3] * x0 + We[p * 3 + 1] * x1 + We[p * 3 + 2] * uu + be[p];
            h[(size_t)p * NPIX + pix] = bf16_rne(v);
        }
    }
}

// ---------------------------------------------------------------------------
// Merged forward DFT, both axes, h in bf16. R13: TWO CHANNELS (p) PER BLOCK,
// grid(32 p-pair, 8 ntile, 2 axis): each FbB A-fragment load feeds 4 MFMA.
// ---------------------------------------------------------------------------
__global__ __launch_bounds__(256) void k_fwd(const unsigned short* __restrict__ h, const short* __restrict__ FbB,
                                             float* __restrict__ VfH, float* __restrict__ VfW) {
    __shared__ unsigned short T[2][64 * 66];  // one tile per p, 2 x 8448 B
    int t = threadIdx.x;
    int ntb = blockIdx.y, axis = blockIdx.z;
    int p0 = blockIdx.x * 2;
    int wv = t >> 6, lane = t & 63, quad = lane >> 4, l15 = lane & 15;
    int n = ntb * 64 + wv * 16 + l15;
    int nL = wv * 16 + l15;
    f32x4 acc[2][2];   // [p][mt]
    #pragma unroll
    for (int pi = 0; pi < 2; ++pi)
        #pragma unroll
        for (int mt = 0; mt < 2; ++mt) acc[pi][mt] = (f32x4){0.f,0.f,0.f,0.f};
    if (axis == 1) {
        #pragma unroll 4
        for (int kc = 0; kc < 16; ++kc) {
            int kb = kc * 32 + quad * 8;
            short8 Bv0 = *(const short8*)(h + ((size_t)p0 * 512 + n) * 512 + kb);
            short8 Bv1 = *(const short8*)(h + ((size_t)(p0 + 1) * 512 + n) * 512 + kb);
            #pragma unroll
            for (int mt = 0; mt < 2; ++mt) {
                const short8* ap = (const short8*)(FbB + (((kc * 2 + mt) * 64 + lane) << 4));
                short8 Ah = ap[0], Al = ap[1];
                acc[0][mt] = MFMA16(Ah, Bv0, acc[0][mt]);
                acc[0][mt] = MFMA16(Al, Bv0, acc[0][mt]);
                acc[1][mt] = MFMA16(Ah, Bv1, acc[1][mt]);
                acc[1][mt] = MFMA16(Al, Bv1, acc[1][mt]);
            }
        }
    } else {
        int kp = t >> 3, c = t & 7;          // k-pair 0..31, n-oct 0..7
        for (int ch = 0; ch < 8; ++ch) {
            int k0 = ch * 64;
            const unsigned short* r0 = h + ((size_t)p0 * 512 + k0 + 2 * kp) * 512 + ntb * 64 + c * 8;
            const unsigned short* r1 = h + ((size_t)(p0 + 1) * 512 + k0 + 2 * kp) * 512 + ntb * 64 + c * 8;
            uint4 a0 = *(const uint4*)r0;
            uint4 b0 = *(const uint4*)(r0 + 512);
            uint4 a1 = *(const uint4*)r1;
            uint4 b1 = *(const uint4*)(r1 + 512);
            unsigned int aw0[4] = {a0.x, a0.y, a0.z, a0.w};
            unsigned int bw0[4] = {b0.x, b0.y, b0.z, b0.w};
            unsigned int aw1[4] = {a1.x, a1.y, a1.z, a1.w};
            unsigned int bw1[4] = {b1.x, b1.y, b1.z, b1.w};
            __syncthreads();                  // previous chunk fully consumed
            #pragma unroll
            for (int i = 0; i < 4; ++i) {
                int n0 = c * 8 + 2 * i;
                *(unsigned int*)&T[0][n0 * 66 + 2 * kp]       = (aw0[i] & 0xffffu) | (bw0[i] << 16);
                *(unsigned int*)&T[0][(n0 + 1) * 66 + 2 * kp] = (aw0[i] >> 16) | (bw0[i] & 0xffff0000u);
                *(unsigned int*)&T[1][n0 * 66 + 2 * kp]       = (aw1[i] & 0xffffu) | (bw1[i] << 16);
                *(unsigned int*)&T[1][(n0 + 1) * 66 + 2 * kp] = (aw1[i] >> 16) | (bw1[i] & 0xffff0000u);
            }
            __syncthreads();
            #pragma unroll
            for (int kcl = 0; kcl < 2; ++kcl) {
                int kc = ch * 2 + kcl;
                union { unsigned int w[4]; short8 v; } bb0, bb1;
                #pragma unroll
                for (int d = 0; d < 4; ++d) {
                    bb0.w[d] = *(const unsigned int*)&T[0][nL * 66 + kcl * 32 + quad * 8 + 2 * d];
                    bb1.w[d] = *(const unsigned int*)&T[1][nL * 66 + kcl * 32 + quad * 8 + 2 * d];
                }
                #pragma unroll
                for (int mt = 0; mt < 2; ++mt) {
                    const short8* ap = (const short8*)(FbB + (((kc * 2 + mt) * 64 + lane) << 4));
                    short8 Ah = ap[0], Al = ap[1];
                    acc[0][mt] = MFMA16(Ah, bb0.v, acc[0][mt]);
                    acc[0][mt] = MFMA16(Al, bb0.v, acc[0][mt]);
                    acc[1][mt] = MFMA16(Ah, bb1.v, acc[1][mt]);
                    acc[1][mt] = MFMA16(Al, bb1.v, acc[1][mt]);
                }
            }
        }
    }
    #pragma unroll
    for (int pi = 0; pi < 2; ++pi) {
        float* vp = (axis ? VfW : VfH) + (size_t)(p0 + pi) * 32 * 512;
        #pragma unroll
        for (int mt = 0; mt < 2; ++mt)
            #pragma unroll
            for (int r = 0; r < 4; ++r)
                vp[(size_t)(mt * 16 + quad * 4 + r) * 512 + n] = acc[pi][mt][r];
    }
}

// ---------------------------------------------------------------------------
// Merged mode mixing, both axes. R14: epilogue writes Vm as hi/lo PLANES:
// hi-word = cvt_pk(R,I) = {R_hi|I_hi<<16}; lo-word = cvt_pk(R-tofRhi,
// I-tofIhi). 6 VALU/elem (was 8); per-(o,r) store = 16 lanes x 4 B = one
// full 64-B sector per plane, single wave. Reader consumes words directly.
// grid 512 (axis = bid>>8; m = bid&15, otile = (bid>>4)&15), block 256.
// BT staging keeps the old intra-word split-pack (local to this kernel).
// ---------------------------------------------------------------------------
__global__ __launch_bounds__(256) void k_mix2(const float* __restrict__ VfH, const float* __restrict__ VfW,
                                              const short* __restrict__ AmL,
                                              unsigned int* __restrict__ VmH_hi, unsigned int* __restrict__ VmH_lo,
                                              unsigned int* __restrict__ VmW_hi, unsigned int* __restrict__ VmW_lo) {
    __shared__ unsigned int BT[2 * 64 * 33];
    int bid = blockIdx.x;
    int axis = bid >> 8;
    int m  = bid & 15;
    int ot = (bid >> 4) & 15;
    const float* Vf = axis ? VfW : VfH;
    unsigned int* Vhi = axis ? VmW_hi : VmH_hi;
    unsigned int* Vlo = axis ? VmW_lo : VmH_lo;
    const short* Am = AmL + (size_t)axis * ASLAB;
    int t = threadIdx.x;
    #pragma unroll
    for (int it = 0; it < 16; ++it) {
        int idx = it * 256 + t;
        int oth = idx & 31, ri = (idx >> 5) & 1, i = idx >> 6;
        float v = Vf[((size_t)i * 32 + m * 2 + ri) * 512 + ot * 32 + oth];
        // split-pack (hi | lo<<16), 4-op cvt_pk form (R12)
        unsigned int t1 = cvt_pk_bf16(v, v);
        float f_hi = __uint_as_float(t1 << 16);
        BT[(ri * 64 + i) * 33 + oth] = cvt_pk_bf16(v, v - f_hi);
    }
    __syncthreads();
    int wv = t >> 6, lane = t & 63, quad = lane >> 4, l15 = lane & 15;
    int nt = wv & 1, mtp = wv >> 1;
    f32x4 aR[2], aI[2];
    aR[0]=(f32x4){0.f,0.f,0.f,0.f}; aR[1]=aR[0]; aI[0]=aR[0]; aI[1]=aR[0];
    #pragma unroll
    for (int kc = 0; kc < 2; ++kc) {
        short8 Brh, Brl, Bih, Bil;
        #pragma unroll
        for (int j = 0; j < 8; ++j) {
            int i = kc * 32 + quad * 8 + j;
            unsigned int br = BT[i * 33 + nt * 16 + l15];
            unsigned int bi = BT[(64 + i) * 33 + nt * 16 + l15];
            Brh[j] = (short)(br & 0xffffu); Brl[j] = (short)(br >> 16);
            Bih[j] = (short)(bi & 0xffffu); Bil[j] = (short)(bi >> 16);
        }
        #pragma unroll
        for (int mi = 0; mi < 2; ++mi) {
            int mt = mtp * 2 + mi;
            const short8* ap = (const short8*)(Am + ((size_t)(((m * 4 + mt) * 2 + kc) * 64 + lane)) * 48);
            short8 Arh = ap[0], Arl = ap[1], Aih = ap[2], Ail = ap[3], Anh = ap[4], Anl = ap[5];
            aR[mi] = MFMA16(Arh, Brh, aR[mi]);
            aR[mi] = MFMA16(Arl, Brh, aR[mi]);
            aR[mi] = MFMA16(Arh, Brl, aR[mi]);
            aR[mi] = MFMA16(Anh, Bih, aR[mi]);
            aR[mi] = MFMA16(Anl, Bih, aR[mi]);
            aR[mi] = MFMA16(Anh, Bil, aR[mi]);
            aI[mi] = MFMA16(Arh, Bih, aI[mi]);
            aI[mi] = MFMA16(Arl, Bih, aI[mi]);
            aI[mi] = MFMA16(Arh, Bil, aI[mi]);
            aI[mi] = MFMA16(Aih, Brh, aI[mi]);
            aI[mi] = MFMA16(Ail, Brh, aI[mi]);
            aI[mi] = MFMA16(Aih, Brl, aI[mi]);
        }
    }
    int yT = ot * 2 + nt;
    #pragma unroll
    for (int mi = 0; mi < 2; ++mi) {
        int o = (mtp * 2 + mi) * 16 + quad * 4;
        #pragma unroll
        for (int r = 0; r < 4; ++r) {
            float R = aR[mi][r], I = aI[mi][r];
            unsigned int t1 = cvt_pk_bf16(R, I);          // {R_hi | I_hi<<16}
            float fR = __uint_as_float(t1 << 16);
            float fI = __uint_as_float(t1 & 0xffff0000u);
            unsigned int t2 = cvt_pk_bf16(R - fR, I - fI); // {R_lo | I_lo<<16}
            size_t idx = VMS(o + r, yT, m, l15);
            Vhi[idx] = t1;
            Vlo[idx] = t2;
        }
    }
}

// ---------------------------------------------------------------------------
// Fused inverse DFT -> s in [pix][ch] layout (R6). grid(32 xt, 32 yt).
// R14: Vm hi/lo planes -> MFMA fragment words loaded DIRECTLY (4 dwords per
// fragment); unzip8 (48 VALU/pp) eliminated.
// R12: 1-op cvt_pk rne for sT stores.
// ---------------------------------------------------------------------------
__global__ __launch_bounds__(256) void k_inv(const unsigned int* __restrict__ VmW_hi, const unsigned int* __restrict__ VmW_lo,
                                             const unsigned int* __restrict__ VmH_hi, const unsigned int* __restrict__ VmH_lo,
                                             const short* __restrict__ GbF, unsigned short* __restrict__ s) {
    __shared__ unsigned short sT[256 * 66];   // [pp][ch + pad], 33792 B
    int t = threadIdx.x;
    int xt = blockIdx.x, yt = blockIdx.y;
    int wv = t >> 6, lane = t & 63, quad = lane >> 4, l15 = lane & 15;
    const short8* gy = (const short8*)(GbF + ((yt * 64 + lane) << 4));
    short8 A1h = gy[0], A1l = gy[1];
    const short8* gx = (const short8*)(GbF + ((xt * 64 + lane) << 4));
    short8 B2h = gx[0], B2l = gx[1];
    int p0 = wv * 16;
    for (int pp = 0; pp < 16; ++pp) {
        int p = p0 + pp;
        union { unsigned int w[4]; short8 v; } A2h_, A2l_, B1h_, B1l_;
        #pragma unroll
        for (int tt = 0; tt < 4; ++tt) {
            size_t ia = VMS(p, yt, quad * 4 + tt, l15);
            size_t ib = VMS(p, xt, quad * 4 + tt, l15);
            A2h_.w[tt] = VmW_hi[ia];
            A2l_.w[tt] = VmW_lo[ia];
            B1h_.w[tt] = VmH_hi[ib];
            B1l_.w[tt] = VmH_lo[ib];
        }
        f32x4 acc = (f32x4){0.f,0.f,0.f,0.f};
        acc = MFMA16(A1h, B1h_.v, acc);
        acc = MFMA16(A1l, B1h_.v, acc);
        acc = MFMA16(A1h, B1l_.v, acc);
        acc = MFMA16(A2h_.v, B2h, acc);
        acc = MFMA16(A2l_.v, B2h, acc);
        acc = MFMA16(A2h_.v, B2l, acc);
        #pragma unroll
        for (int r = 0; r < 4; ++r)
            sT[(((r * 16 + l15) << 2) + quad) * 66 + p] = bf16_rne1(acc[r]);
    }
    __syncthreads();
    #pragma unroll
    for (int it = 0; it < 8; ++it) {
        int ppix = it * 32 + (t >> 3);
        int part = t & 7;
        const unsigned int* lp = (const unsigned int*)&sT[ppix * 66 + part * 8];
        uint4 v; v.x = lp[0]; v.y = lp[1]; v.z = lp[2]; v.w = lp[3];
        int q = ppix & 3, rx = ppix >> 2;
        int xl = rx & 15, r = rx >> 4;
        int y = yt * 16 + q * 4 + r;
        int x = xt * 16 + xl;
        *(uint4*)(s + (((size_t)y * 512 + x) << 6) + part * 8) = v;
    }
}

// ---------------------------------------------------------------------------
// MFMA FFN, 128-px tile (grid 2048): h(bf16) += gelu(W2.gelu(W1.s+b1)+b2).
// R9 structure (single-tile, no pre-GEMM barrier). s is [pix][ch]: GEMM1
// B-frags direct short8 global loads. tB own-wave rows (no barrier
// epi1->GEMM2); oTb aliases tB (barrier before epi2). (256,4), rcp-gelu.
// R10: cvt_pk for epi1 tB words and h-increment. R12: 1-op rne for epi2 oTb.
// ---------------------------------------------------------------------------
union FfnSmem {
    unsigned int  tB[128 * 33];     // 16896 B, GEMM1->GEMM2 bf16 pairs
    unsigned short oTb[64 * 136];   // 17408 B, epilogue2 bf16 transpose tile
    float         red[16 * 132];    // 8448 B, decoder partial sums
};

__global__ __launch_bounds__(256, 4) void k_ffn2m(const unsigned short* __restrict__ in, unsigned short* __restrict__ out,
                                                  const short* __restrict__ w1f, const float* __restrict__ b1v,
                                                  const short* __restrict__ w2f, const float* __restrict__ b2v,
                                                  const float* __restrict__ Wd, const float* __restrict__ bd,
                                                  float* __restrict__ dout, int last) {
    __shared__ __align__(16) FfnSmem u;
    int t = threadIdx.x;
    int pixBase = blockIdx.x * 128;
    int lane15 = t & 15;
    int quad   = (t >> 4) & 3;
    int wv     = t >> 6;
    int oct = t & 15;                          // store pixel oct 0..15
    int cg  = t >> 4;                          // store channel group 0..15

    // ---- GEMM1 B-fragments straight from global s[pix][ch] ----
    short8 bb0[2], bb1[2];
    #pragma unroll
    for (int kc = 0; kc < 2; ++kc) {
        int col = kc * 32 + quad * 8;
        bb0[kc] = *(const short8*)(in + (((size_t)(pixBase + wv * 32 + lane15)) << 6) + col);
        bb1[kc] = *(const short8*)(in + (((size_t)(pixBase + wv * 32 + 16 + lane15)) << 6) + col);
    }

    f32x4 acc[2][4];
    #pragma unroll
    for (int ns = 0; ns < 2; ++ns)
        #pragma unroll
        for (int mt = 0; mt < 4; ++mt) acc[ns][mt] = (f32x4){0.f, 0.f, 0.f, 0.f};

    // ---- GEMM1: 2-term, weights at use ----
    #pragma unroll
    for (int kc = 0; kc < 2; ++kc) {
        #pragma unroll
        for (int mt = 0; mt < 4; ++mt) {
            int s8 = mt * 2 + kc;
            const short8* wp = (const short8*)(w1f + (((size_t)s8 * 64 + (t & 63)) << 4));
            short8 wh = wp[0], wl = wp[1];
            acc[0][mt] = MFMA16(wh, bb0[kc], acc[0][mt]);
            acc[0][mt] = MFMA16(wl, bb0[kc], acc[0][mt]);
            acc[1][mt] = MFMA16(wh, bb1[kc], acc[1][mt]);
            acc[1][mt] = MFMA16(wl, bb1[kc], acc[1][mt]);
        }
    }

    // ---- epilogue1: gelu -> cvt_pk bf16 pairs -> tB (own-wave rows only) ----
    #pragma unroll
    for (int ns = 0; ns < 2; ++ns) {
        int row = wv * 32 + ns * 16 + lane15;
        #pragma unroll
        for (int mt = 0; mt < 4; ++mt) {
            const float* bp = b1v + mt * 16 + quad * 4;
            float g[4];
            #pragma unroll
            for (int r = 0; r < 4; ++r) g[r] = gelu_f(acc[ns][mt][r] + bp[r]);
            int cp = (mt * 16 + quad * 4) >> 1;
            u.tB[row * 33 + cp]     = cvt_pk_bf16(g[0], g[1]);
            u.tB[row * 33 + cp + 1] = cvt_pk_bf16(g[2], g[3]);
            acc[ns][mt] = (f32x4){0.f, 0.f, 0.f, 0.f};
        }
    }

    // NO barrier: GEMM2 reads only this wave's own rows, written above.

    // ---- GEMM2: 2-term, weights at use ----
    #pragma unroll
    for (int kc = 0; kc < 2; ++kc) {
        union { unsigned int w[4]; short8 v; } cb0, cb1;
        int row0 = wv * 32 + lane15;
        int row1 = wv * 32 + 16 + lane15;
        #pragma unroll
        for (int i = 0; i < 4; ++i) {
            cb0.w[i] = u.tB[row0 * 33 + kc * 16 + quad * 4 + i];
            cb1.w[i] = u.tB[row1 * 33 + kc * 16 + quad * 4 + i];
        }
        #pragma unroll
        for (int mt = 0; mt < 4; ++mt) {
            int s8 = mt * 2 + kc;
            const short8* wp = (const short8*)(w2f + (((size_t)s8 * 64 + (t & 63)) << 4));
            short8 wh = wp[0], wl = wp[1];
            acc[0][mt] = MFMA16(wh, cb0.v, acc[0][mt]);
            acc[0][mt] = MFMA16(wl, cb0.v, acc[0][mt]);
            acc[1][mt] = MFMA16(wh, cb1.v, acc[1][mt]);
            acc[1][mt] = MFMA16(wl, cb1.v, acc[1][mt]);
        }
    }

    // ---- h residual load (latency hidden by epilogue2 VALU) ----
    uint4 hr[4];
    #pragma unroll
    for (int j = 0; j < 4; ++j) {
        int c = cg + 16 * j;
        hr[j] = *(const uint4*)(out + (size_t)c * NPIX + pixBase + oct * 8);
    }

    __syncthreads();   // all waves done reading tB; oTb scatter may begin

    // ---- epilogue2: gelu -> bf16 oTb (aliases tB) ----
    #pragma unroll
    for (int ns = 0; ns < 2; ++ns) {
        int px = wv * 32 + ns * 16 + lane15;
        #pragma unroll
        for (int mt = 0; mt < 4; ++mt) {
            const float* bp = b2v + mt * 16 + quad * 4;
            #pragma unroll
            for (int r = 0; r < 4; ++r) {
                int c = mt * 16 + quad * 4 + r;
                u.oTb[c * 136 + px] = bf16_rne1(gelu_f(acc[ns][mt][r] + bp[r]));
            }
        }
    }
    __syncthreads();

    if (!last) {
        // ---- h(bf16) += increment: (c,oct) units, uint4, full 256-B sectors/wave ----
        #pragma unroll
        for (int j = 0; j < 4; ++j) {
            int c = cg + 16 * j;
            uint4 gv = *(const uint4*)&u.oTb[c * 136 + oct * 8];
            unsigned int hw[4] = {hr[j].x, hr[j].y, hr[j].z, hr[j].w};
            unsigned int gw[4] = {gv.x, gv.y, gv.z, gv.w};
            uint4 o;
            unsigned int* op = &o.x;
            #pragma unroll
            for (int i = 0; i < 4; ++i) {
                float f0 = bf16_tof((unsigned short)(hw[i] & 0xffffu)) + bf16_tof((unsigned short)(gw[i] & 0xffffu));
                float f1 = bf16_tof((unsigned short)(hw[i] >> 16))     + bf16_tof((unsigned short)(gw[i] >> 16));
                op[i] = cvt_pk_bf16(f0, f1);
            }
            *(uint4*)(out + (size_t)c * NPIX + pixBase + oct * 8) = o;
        }
    } else {
        // ---- fused decoder: dout = sum_c Wd[c]*(hres+gv) + bd ----
        float part[8] = {0.f,0.f,0.f,0.f,0.f,0.f,0.f,0.f};
        #pragma unroll
        for (int j = 0; j < 4; ++j) {
            int c = cg + 16 * j;
            float wd = Wd[c];
            uint4 gv = *(const uint4*)&u.oTb[c * 136 + oct * 8];
            unsigned int hw[4] = {hr[j].x, hr[j].y, hr[j].z, hr[j].w};
            unsigned int gw[4] = {gv.x, gv.y, gv.z, gv.w};
            #pragma unroll
            for (int i = 0; i < 4; ++i) {
                part[2*i]   += wd * (bf16_tof((unsigned short)(hw[i] & 0xffffu)) + bf16_tof((unsigned short)(gw[i] & 0xffffu)));
                part[2*i+1] += wd * (bf16_tof((unsigned short)(hw[i] >> 16))     + bf16_tof((unsigned short)(gw[i] >> 16)));
            }
        }
        __syncthreads();   // oTb reads done before red (aliases buffer) is written
        #pragma unroll
        for (int i = 0; i < 8; ++i)
            u.red[cg * 132 + oct * 8 + i] = part[i];
        __syncthreads();
        if (t < 128) {
            float sum = bd[0];
            #pragma unroll
            for (int gg = 0; gg < 16; ++gg)
                sum += u.red[gg * 132 + t];
            dout[pixBase + t] = sum;
        }
    }
}

extern "C" void kernel_launch(void* const* d_in, const int* in_sizes, int n_in,
                              void* d_out, int out_size, void* d_ws, size_t ws_size,
                              hipStream_t stream) {
    (void)in_sizes; (void)n_in; (void)out_size; (void)ws_size;
    const float* u   = (const float*)d_in[0];
    const float* xc  = (const float*)d_in[1];
    const float* We  = (const float*)d_in[2];
    const float* be  = (const float*)d_in[3];
    const float* W1  = (const float*)d_in[4];
    const float* b1  = (const float*)d_in[5];
    const float* W2  = (const float*)d_in[6];
    const float* b2  = (const float*)d_in[7];
    const float* Are = (const float*)d_in[8];
    const float* Aim = (const float*)d_in[9];
    const float* Wd  = (const float*)d_in[10];
    const float* bd  = (const float*)d_in[11];

    // workspace layout, ~93 MB used
    char* ws = (char*)d_ws;
    unsigned short* h = (unsigned short*)ws;                  // 32 MB (bf16) [ch][pix]
    unsigned short* s = (unsigned short*)(ws + (size_t)33554432); // 32 MB (bf16) [pix][ch]
    float* VfH = (float*)(ws + (size_t)67108864);             // 4 MB: [64][32][512]
    float* VfW = VfH + (size_t)1048576;                       // 4 MB
    unsigned int* VmH_hi = (unsigned int*)(VfW + 1048576);    // 2 MB plane
    unsigned int* VmH_lo = VmH_hi + 524288;                   // 2 MB
    unsigned int* VmW_hi = VmH_lo + 524288;                   // 2 MB
    unsigned int* VmW_lo = VmW_hi + 524288;                   // 2 MB
    short* FbB = (short*)(VmW_lo + 524288);                   // 64 KB
    short* GbF = FbB + 32768;                                 // 64 KB
    short* Am  = GbF + 32768;                                 // 6 MB
    short* Wpk = Am  + (size_t)65536 * 48;                    // 128 KB

    k_setup<<<1312, 256, 0, stream>>>(W1, W2, Are, Aim, u, xc, We, be,
                                      FbB, GbF, Wpk, Am, h);

    for (int l = 0; l < 4; ++l) {
        k_fwd<<<dim3(32, 8, 2), 256, 0, stream>>>(h, FbB, VfH, VfW);
        k_mix2<<<512, 256, 0, stream>>>(VfH, VfW, Am + (size_t)(l * 2) * ASLAB,
                                        VmH_hi, VmH_lo, VmW_hi, VmW_lo);
        k_inv<<<dim3(32, 32), 256, 0, stream>>>(VmW_hi, VmW_lo, VmH_hi, VmH_lo, GbF, s);
        k_ffn2m<<<2048, 256, 0, stream>>>(s, h,
                                          Wpk + (size_t)(l * 2 + 0) * 8192, b1 + (size_t)l * 64,
                                          Wpk + (size_t)(l * 2 + 1) * 8192, b2 + (size_t)l * 64,
                                          Wd, bd, (float*)d_out, (l == 3) ? 1 : 0);
    }
}

// Round 16
// 355.330 us; speedup vs baseline: 1.1167x; 1.0020x over previous
//
#include <hip/hip_runtime.h>

#define NPIX (512*512)

typedef __attribute__((ext_vector_type(8))) short short8;   // 8 bf16 in 4 VGPRs
typedef __attribute__((ext_vector_type(4))) float f32x4;    // MFMA accumulator

#define MFMA16(A, B, C) __builtin_amdgcn_mfma_f32_16x16x32_bf16((A), (B), (C), 0, 0, 0)

// JAX gelu(approximate=True): x * sigmoid(2*sqrt(2/pi)*(x+0.044715x^3)).
// R7: exact f32 div -> v_rcp_f32 (rel-err ~2^-22 << bf16 ulp).
__device__ __forceinline__ float gelu_f(float x) {
    float z = 1.5957691216057308f * (x + 0.044715f * x * x * x);
    return x * __builtin_amdgcn_rcpf(1.0f + __expf(-z));
}

// f32 -> bf16 bits (RNE), bit-trick (k_setup only; launch-once)
__device__ __forceinline__ unsigned short bf16_rne(float x) {
    unsigned int b = __float_as_uint(x);
    unsigned int r = b + 0x7fffu + ((b >> 16) & 1u);
    return (unsigned short)(r >> 16);
}
__device__ __forceinline__ float bf16_tof(unsigned short h) {
    return __uint_as_float(((unsigned int)h) << 16);
}
// R10: packed 2xf32 -> 2xbf16 (RNE) in ONE VALU op. D[15:0]=bf16(lo),
// D[31:16]=bf16(hi). R12 validated bit-exact vs bit-trick (absmax canary).
__device__ __forceinline__ unsigned int cvt_pk_bf16(float lo, float hi) {
    unsigned int r;
    asm("v_cvt_pk_bf16_f32 %0, %1, %2" : "=v"(r) : "v"(lo), "v"(hi));
    return r;
}
// R12: 1-op scalar rne via cvt_pk (low 16 bits)
__device__ __forceinline__ unsigned short bf16_rne1(float x) {
    return (unsigned short)(cvt_pk_bf16(x, x) & 0xffffu);
}

#define ASLAB ((size_t)16 * 4 * 2 * 64 * 48)   // shorts per (l,ax) in Am

// R14: Vm stored as SEPARATE hi/lo planes, u32 = {R|I<<16} per (m,yL).
// Reader fragment word == plane word directly (unzip8 gone).
// u32 index: [p][y>>4][m][y&15]; writer: 16 lanes x 4 B = full 64-B sector.
#define VMS(p, yT, m, yL) ((((size_t)(p) * 32 + (yT)) * 16 + (m)) * 16 + (yL))

// ---------------------------------------------------------------------------
// Merged setup + encoder: blocks 0..15 basis tables, 16..31 FFN weights,
// 32..287 spectral A-weights, 288..1311 encoder (h stored bf16).
// ---------------------------------------------------------------------------
__global__ __launch_bounds__(256) void k_setup(const float* __restrict__ W1, const float* __restrict__ W2,
                                               const float* __restrict__ Are, const float* __restrict__ Aim,
                                               const float* __restrict__ u, const float* __restrict__ xc,
                                               const float* __restrict__ We, const float* __restrict__ be,
                                               short* __restrict__ FbB, short* __restrict__ GbF,
                                               short* __restrict__ Wpk, short* __restrict__ Am,
                                               unsigned short* __restrict__ h) {
    int b = blockIdx.x;
    int t = threadIdx.x;
    if (b < 16) {
        int id = b * 256 + t;
        int lane = id & 63;
        int quad = lane >> 4, l15 = lane & 15;
        short* dst;
        int n0, nstep, o0, ostep;
        float wscale = 1.0f;
        if (id < 2048) {
            int nt = (id >> 6) & 1, kc = id >> 7;
            dst = FbB + id * 16;
            n0 = kc * 32 + quad * 8; nstep = 1;
            o0 = nt * 16 + l15;      ostep = 0;
        } else {
            int id2 = id - 2048;
            dst = GbF + id2 * 16;
            int tt = id2 >> 6;
            n0 = tt * 16 + l15;      nstep = 0;
            o0 = quad * 8;           ostep = 1;
            wscale = 1.0f / 512.0f;
        }
        #pragma unroll
        for (int j = 0; j < 8; ++j) {
            int n = n0 + nstep * j;
            int o = o0 + ostep * j;
            int m = o >> 1, ri = o & 1;
            int k = (n * m) & 511;
            float sv, cv;
            sincosf(6.283185307179586f * (1.0f / 512.0f) * (float)k, &sv, &cv);
            float v = ri ? -sv : cv;
            if (id >= 2048) v *= (m == 0 ? 1.0f : 2.0f) * wscale;
            unsigned short hi = bf16_rne(v);
            dst[j]     = (short)hi;
            dst[8 + j] = (short)bf16_rne(v - bf16_tof(hi));
        }
    } else if (b < 32) {
        int tid = (b - 16) * 256 + t;
        int lane = tid & 63;
        int kc = (tid >> 6) & 1;
        int mt = (tid >> 7) & 3;
        int wg = tid >> 9;
        int layer = wg >> 1, which = wg & 1;
        const float* Wsrc = (which ? W2 : W1) + (size_t)layer * 4096;
        int o  = mt * 16 + (lane & 15);
        int c0 = kc * 32 + ((lane >> 4) & 3) * 8;
        short* dst = Wpk + (size_t)tid * 16;
        #pragma unroll
        for (int j = 0; j < 8; ++j) {
            float x = Wsrc[o * 64 + c0 + j];
            unsigned short hi = bf16_rne(x);
            dst[j]     = (short)hi;
            dst[8 + j] = (short)bf16_rne(x - bf16_tof(hi));
        }
    } else if (b < 288) {
        int id = (b - 32) * 256 + t;
        int lane = id & 63;
        int kc  = (id >> 6) & 1;
        int mt  = (id >> 7) & 3;
        int m   = (id >> 9) & 15;
        int lax = id >> 13;
        int l = lax >> 1, ax = lax & 1;
        int o  = mt * 16 + (lane & 15);
        int i0 = kc * 32 + ((lane >> 4) & 3) * 8;
        short* dst = Am + (size_t)id * 48;
        #pragma unroll
        for (int j = 0; j < 8; ++j) {
            size_t src = (((size_t)(l * 64 + o) * 64 + (i0 + j)) * 16 + m) * 2 + ax;
            float ar = Are[src], ai = Aim[src];
            unsigned short hh;
            hh = bf16_rne(ar);  dst[j]      = (short)hh; dst[8 + j]  = (short)bf16_rne(ar - bf16_tof(hh));
            hh = bf16_rne(ai);  dst[16 + j] = (short)hh; dst[24 + j] = (short)bf16_rne(ai - bf16_tof(hh));
            hh = bf16_rne(-ai); dst[32 + j] = (short)hh; dst[40 + j] = (short)bf16_rne(-ai - bf16_tof(hh));
        }
    } else {
        // encoder: h[p][pix] = bf16(We.x + be)
        int pix = (b - 288) * 256 + t;
        float x0 = xc[pix], x1 = xc[NPIX + pix], uu = u[pix];
        #pragma unroll 8
        for (int p = 0; p < 64; ++p) {
            float v = We[p * 3] * x0 + We[p * 3 + 1] * x1 + We[p * 3 + 2] * uu + be[p];
            h[(size_t)p * NPIX + pix] = bf16_rne(v);
        }
    }
}

// ---------------------------------------------------------------------------
// Merged forward DFT, both axes, h in bf16. R13: TWO CHANNELS (p) PER BLOCK,
// grid(32 p-pair, 8 ntile, 2 axis): each FbB A-fragment load feeds 4 MFMA.
// ---------------------------------------------------------------------------
__global__ __launch_bounds__(256) void k_fwd(const unsigned short* __restrict__ h, const short* __restrict__ FbB,
                                             float* __restrict__ VfH, float* __restrict__ VfW) {
    __shared__ unsigned short T[2][64 * 66];  // one tile per p, 2 x 8448 B
    int t = threadIdx.x;
    int ntb = blockIdx.y, axis = blockIdx.z;
    int p0 = blockIdx.x * 2;
    int wv = t >> 6, lane = t & 63, quad = lane >> 4, l15 = lane & 15;
    int n = ntb * 64 + wv * 16 + l15;
    int nL = wv * 16 + l15;
    f32x4 acc[2][2];   // [p][mt]
    #pragma unroll
    for (int pi = 0; pi < 2; ++pi)
        #pragma unroll
        for (int mt = 0; mt < 2; ++mt) acc[pi][mt] = (f32x4){0.f,0.f,0.f,0.f};
    if (axis == 1) {
        #pragma unroll 4
        for (int kc = 0; kc < 16; ++kc) {
            int kb = kc * 32 + quad * 8;
            short8 Bv0 = *(const short8*)(h + ((size_t)p0 * 512 + n) * 512 + kb);
            short8 Bv1 = *(const short8*)(h + ((size_t)(p0 + 1) * 512 + n) * 512 + kb);
            #pragma unroll
            for (int mt = 0; mt < 2; ++mt) {
                const short8* ap = (const short8*)(FbB + (((kc * 2 + mt) * 64 + lane) << 4));
                short8 Ah = ap[0], Al = ap[1];
                acc[0][mt] = MFMA16(Ah, Bv0, acc[0][mt]);
                acc[0][mt] = MFMA16(Al, Bv0, acc[0][mt]);
                acc[1][mt] = MFMA16(Ah, Bv1, acc[1][mt]);
                acc[1][mt] = MFMA16(Al, Bv1, acc[1][mt]);
            }
        }
    } else {
        int kp = t >> 3, c = t & 7;          // k-pair 0..31, n-oct 0..7
        for (int ch = 0; ch < 8; ++ch) {
            int k0 = ch * 64;
            const unsigned short* r0 = h + ((size_t)p0 * 512 + k0 + 2 * kp) * 512 + ntb * 64 + c * 8;
            const unsigned short* r1 = h + ((size_t)(p0 + 1) * 512 + k0 + 2 * kp) * 512 + ntb * 64 + c * 8;
            uint4 a0 = *(const uint4*)r0;
            uint4 b0 = *(const uint4*)(r0 + 512);
            uint4 a1 = *(const uint4*)r1;
            uint4 b1 = *(const uint4*)(r1 + 512);
            unsigned int aw0[4] = {a0.x, a0.y, a0.z, a0.w};
            unsigned int bw0[4] = {b0.x, b0.y, b0.z, b0.w};
            unsigned int aw1[4] = {a1.x, a1.y, a1.z, a1.w};
            unsigned int bw1[4] = {b1.x, b1.y, b1.z, b1.w};
            __syncthreads();                  // previous chunk fully consumed
            #pragma unroll
            for (int i = 0; i < 4; ++i) {
                int n0 = c * 8 + 2 * i;
                *(unsigned int*)&T[0][n0 * 66 + 2 * kp]       = (aw0[i] & 0xffffu) | (bw0[i] << 16);
                *(unsigned int*)&T[0][(n0 + 1) * 66 + 2 * kp] = (aw0[i] >> 16) | (bw0[i] & 0xffff0000u);
                *(unsigned int*)&T[1][n0 * 66 + 2 * kp]       = (aw1[i] & 0xffffu) | (bw1[i] << 16);
                *(unsigned int*)&T[1][(n0 + 1) * 66 + 2 * kp] = (aw1[i] >> 16) | (bw1[i] & 0xffff0000u);
            }
            __syncthreads();
            #pragma unroll
            for (int kcl = 0; kcl < 2; ++kcl) {
                int kc = ch * 2 + kcl;
                union { unsigned int w[4]; short8 v; } bb0, bb1;
                #pragma unroll
                for (int d = 0; d < 4; ++d) {
                    bb0.w[d] = *(const unsigned int*)&T[0][nL * 66 + kcl * 32 + quad * 8 + 2 * d];
                    bb1.w[d] = *(const unsigned int*)&T[1][nL * 66 + kcl * 32 + quad * 8 + 2 * d];
                }
                #pragma unroll
                for (int mt = 0; mt < 2; ++mt) {
                    const short8* ap = (const short8*)(FbB + (((kc * 2 + mt) * 64 + lane) << 4));
                    short8 Ah = ap[0], Al = ap[1];
                    acc[0][mt] = MFMA16(Ah, bb0.v, acc[0][mt]);
                    acc[0][mt] = MFMA16(Al, bb0.v, acc[0][mt]);
                    acc[1][mt] = MFMA16(Ah, bb1.v, acc[1][mt]);
                    acc[1][mt] = MFMA16(Al, bb1.v, acc[1][mt]);
                }
            }
        }
    }
    #pragma unroll
    for (int pi = 0; pi < 2; ++pi) {
        float* vp = (axis ? VfW : VfH) + (size_t)(p0 + pi) * 32 * 512;
        #pragma unroll
        for (int mt = 0; mt < 2; ++mt)
            #pragma unroll
            for (int r = 0; r < 4; ++r)
                vp[(size_t)(mt * 16 + quad * 4 + r) * 512 + n] = acc[pi][mt][r];
    }
}

// ---------------------------------------------------------------------------
// Merged mode mixing, both axes. R14: Vm epilogue as hi/lo planes.
// R15: BT staging as FOUR u16 PLANES [oth][i] (real/imag x hi/lo, stride 72
// for 16-B alignment): each MFMA B-fragment is ONE ds_read_b128 (8 total)
// instead of 32 b32 reads + ~96 extract VALU. Same values, bit-exact.
// grid 512 (axis = bid>>8; m = bid&15, otile = (bid>>4)&15), block 256.
// ---------------------------------------------------------------------------
__global__ __launch_bounds__(256) void k_mix2(const float* __restrict__ VfH, const float* __restrict__ VfW,
                                              const short* __restrict__ AmL,
                                              unsigned int* __restrict__ VmH_hi, unsigned int* __restrict__ VmH_lo,
                                              unsigned int* __restrict__ VmW_hi, unsigned int* __restrict__ VmW_lo) {
    __shared__ __align__(16) unsigned short BThr[32 * 72];  // real hi, 4608 B
    __shared__ __align__(16) unsigned short BTlr[32 * 72];  // real lo
    __shared__ __align__(16) unsigned short BThi[32 * 72];  // imag hi
    __shared__ __align__(16) unsigned short BTli[32 * 72];  // imag lo
    int bid = blockIdx.x;
    int axis = bid >> 8;
    int m  = bid & 15;
    int ot = (bid >> 4) & 15;
    const float* Vf = axis ? VfW : VfH;
    unsigned int* Vhi = axis ? VmW_hi : VmH_hi;
    unsigned int* Vlo = axis ? VmW_lo : VmH_lo;
    const short* Am = AmL + (size_t)axis * ASLAB;
    int t = threadIdx.x;
    #pragma unroll
    for (int it = 0; it < 16; ++it) {
        int idx = it * 256 + t;
        int oth = idx & 31, ri = (idx >> 5) & 1, i = idx >> 6;
        float v = Vf[((size_t)i * 32 + m * 2 + ri) * 512 + ot * 32 + oth];
        unsigned int t1 = cvt_pk_bf16(v, v);             // low16 = hi bits
        float f_hi = __uint_as_float(t1 << 16);
        unsigned int t2 = cvt_pk_bf16(v - f_hi, v - f_hi); // low16 = lo bits
        unsigned short* dh = ri ? BThi : BThr;
        unsigned short* dl = ri ? BTli : BTlr;
        dh[oth * 72 + i] = (unsigned short)t1;
        dl[oth * 72 + i] = (unsigned short)t2;
    }
    __syncthreads();
    int wv = t >> 6, lane = t & 63, quad = lane >> 4, l15 = lane & 15;
    int nt = wv & 1, mtp = wv >> 1;
    f32x4 aR[2], aI[2];
    aR[0]=(f32x4){0.f,0.f,0.f,0.f}; aR[1]=aR[0]; aI[0]=aR[0]; aI[1]=aR[0];
    int ro = (nt * 16 + l15) * 72;
    #pragma unroll
    for (int kc = 0; kc < 2; ++kc) {
        int col = ro + kc * 32 + quad * 8;
        short8 Brh = *(const short8*)&BThr[col];
        short8 Brl = *(const short8*)&BTlr[col];
        short8 Bih = *(const short8*)&BThi[col];
        short8 Bil = *(const short8*)&BTli[col];
        #pragma unroll
        for (int mi = 0; mi < 2; ++mi) {
            int mt = mtp * 2 + mi;
            const short8* ap = (const short8*)(Am + ((size_t)(((m * 4 + mt) * 2 + kc) * 64 + lane)) * 48);
            short8 Arh = ap[0], Arl = ap[1], Aih = ap[2], Ail = ap[3], Anh = ap[4], Anl = ap[5];
            aR[mi] = MFMA16(Arh, Brh, aR[mi]);
            aR[mi] = MFMA16(Arl, Brh, aR[mi]);
            aR[mi] = MFMA16(Arh, Brl, aR[mi]);
            aR[mi] = MFMA16(Anh, Bih, aR[mi]);
            aR[mi] = MFMA16(Anl, Bih, aR[mi]);
            aR[mi] = MFMA16(Anh, Bil, aR[mi]);
            aI[mi] = MFMA16(Arh, Bih, aI[mi]);
            aI[mi] = MFMA16(Arl, Bih, aI[mi]);
            aI[mi] = MFMA16(Arh, Bil, aI[mi]);
            aI[mi] = MFMA16(Aih, Brh, aI[mi]);
            aI[mi] = MFMA16(Ail, Brh, aI[mi]);
            aI[mi] = MFMA16(Aih, Brl, aI[mi]);
        }
    }
    int yT = ot * 2 + nt;
    #pragma unroll
    for (int mi = 0; mi < 2; ++mi) {
        int o = (mtp * 2 + mi) * 16 + quad * 4;
        #pragma unroll
        for (int r = 0; r < 4; ++r) {
            float R = aR[mi][r], I = aI[mi][r];
            unsigned int t1 = cvt_pk_bf16(R, I);          // {R_hi | I_hi<<16}
            float fR = __uint_as_float(t1 << 16);
            float fI = __uint_as_float(t1 & 0xffff0000u);
            unsigned int t2 = cvt_pk_bf16(R - fR, I - fI); // {R_lo | I_lo<<16}
            size_t idx = VMS(o + r, yT, m, l15);
            Vhi[idx] = t1;
            Vlo[idx] = t2;
        }
    }
}

// ---------------------------------------------------------------------------
// Fused inverse DFT -> s in [pix][ch] layout (R6). grid(32 xt, 32 yt).
// R14: Vm hi/lo planes -> MFMA fragment words loaded DIRECTLY (4 dwords per
// fragment); unzip8 eliminated. R12: 1-op cvt_pk rne for sT stores.
// ---------------------------------------------------------------------------
__global__ __launch_bounds__(256) void k_inv(const unsigned int* __restrict__ VmW_hi, const unsigned int* __restrict__ VmW_lo,
                                             const unsigned int* __restrict__ VmH_hi, const unsigned int* __restrict__ VmH_lo,
                                             const short* __restrict__ GbF, unsigned short* __restrict__ s) {
    __shared__ unsigned short sT[256 * 66];   // [pp][ch + pad], 33792 B
    int t = threadIdx.x;
    int xt = blockIdx.x, yt = blockIdx.y;
    int wv = t >> 6, lane = t & 63, quad = lane >> 4, l15 = lane & 15;
    const short8* gy = (const short8*)(GbF + ((yt * 64 + lane) << 4));
    short8 A1h = gy[0], A1l = gy[1];
    const short8* gx = (const short8*)(GbF + ((xt * 64 + lane) << 4));
    short8 B2h = gx[0], B2l = gx[1];
    int p0 = wv * 16;
    for (int pp = 0; pp < 16; ++pp) {
        int p = p0 + pp;
        union { unsigned int w[4]; short8 v; } A2h_, A2l_, B1h_, B1l_;
        #pragma unroll
        for (int tt = 0; tt < 4; ++tt) {
            size_t ia = VMS(p, yt, quad * 4 + tt, l15);
            size_t ib = VMS(p, xt, quad * 4 + tt, l15);
            A2h_.w[tt] = VmW_hi[ia];
            A2l_.w[tt] = VmW_lo[ia];
            B1h_.w[tt] = VmH_hi[ib];
            B1l_.w[tt] = VmH_lo[ib];
        }
        f32x4 acc = (f32x4){0.f,0.f,0.f,0.f};
        acc = MFMA16(A1h, B1h_.v, acc);
        acc = MFMA16(A1l, B1h_.v, acc);
        acc = MFMA16(A1h, B1l_.v, acc);
        acc = MFMA16(A2h_.v, B2h, acc);
        acc = MFMA16(A2l_.v, B2h, acc);
        acc = MFMA16(A2h_.v, B2l, acc);
        #pragma unroll
        for (int r = 0; r < 4; ++r)
            sT[(((r * 16 + l15) << 2) + quad) * 66 + p] = bf16_rne1(acc[r]);
    }
    __syncthreads();
    #pragma unroll
    for (int it = 0; it < 8; ++it) {
        int ppix = it * 32 + (t >> 3);
        int part = t & 7;
        const unsigned int* lp = (const unsigned int*)&sT[ppix * 66 + part * 8];
        uint4 v; v.x = lp[0]; v.y = lp[1]; v.z = lp[2]; v.w = lp[3];
        int q = ppix & 3, rx = ppix >> 2;
        int xl = rx & 15, r = rx >> 4;
        int y = yt * 16 + q * 4 + r;
        int x = xt * 16 + xl;
        *(uint4*)(s + (((size_t)y * 512 + x) << 6) + part * 8) = v;
    }
}

// ---------------------------------------------------------------------------
// MFMA FFN, 128-px tile (grid 2048): h(bf16) += gelu(W2.gelu(W1.s+b1)+b2).
// R9 structure (single-tile, no pre-GEMM barrier). s is [pix][ch]: GEMM1
// B-frags direct short8 global loads. tB own-wave rows (no barrier
// epi1->GEMM2); oTb aliases tB (barrier before epi2). (256,4), rcp-gelu.
// R10: cvt_pk for epi1 tB words and h-increment. R12: 1-op rne for epi2 oTb.
// ---------------------------------------------------------------------------
union FfnSmem {
    unsigned int  tB[128 * 33];     // 16896 B, GEMM1->GEMM2 bf16 pairs
    unsigned short oTb[64 * 136];   // 17408 B, epilogue2 bf16 transpose tile
    float         red[16 * 132];    // 8448 B, decoder partial sums
};

__global__ __launch_bounds__(256, 4) void k_ffn2m(const unsigned short* __restrict__ in, unsigned short* __restrict__ out,
                                                  const short* __restrict__ w1f, const float* __restrict__ b1v,
                                                  const short* __restrict__ w2f, const float* __restrict__ b2v,
                                                  const float* __restrict__ Wd, const float* __restrict__ bd,
                                                  float* __restrict__ dout, int last) {
    __shared__ __align__(16) FfnSmem u;
    int t = threadIdx.x;
    int pixBase = blockIdx.x * 128;
    int lane15 = t & 15;
    int quad   = (t >> 4) & 3;
    int wv     = t >> 6;
    int oct = t & 15;                          // store pixel oct 0..15
    int cg  = t >> 4;                          // store channel group 0..15

    // ---- GEMM1 B-fragments straight from global s[pix][ch] ----
    short8 bb0[2], bb1[2];
    #pragma unroll
    for (int kc = 0; kc < 2; ++kc) {
        int col = kc * 32 + quad * 8;
        bb0[kc] = *(const short8*)(in + (((size_t)(pixBase + wv * 32 + lane15)) << 6) + col);
        bb1[kc] = *(const short8*)(in + (((size_t)(pixBase + wv * 32 + 16 + lane15)) << 6) + col);
    }

    f32x4 acc[2][4];
    #pragma unroll
    for (int ns = 0; ns < 2; ++ns)
        #pragma unroll
        for (int mt = 0; mt < 4; ++mt) acc[ns][mt] = (f32x4){0.f, 0.f, 0.f, 0.f};

    // ---- GEMM1: 2-term, weights at use ----
    #pragma unroll
    for (int kc = 0; kc < 2; ++kc) {
        #pragma unroll
        for (int mt = 0; mt < 4; ++mt) {
            int s8 = mt * 2 + kc;
            const short8* wp = (const short8*)(w1f + (((size_t)s8 * 64 + (t & 63)) << 4));
            short8 wh = wp[0], wl = wp[1];
            acc[0][mt] = MFMA16(wh, bb0[kc], acc[0][mt]);
            acc[0][mt] = MFMA16(wl, bb0[kc], acc[0][mt]);
            acc[1][mt] = MFMA16(wh, bb1[kc], acc[1][mt]);
            acc[1][mt] = MFMA16(wl, bb1[kc], acc[1][mt]);
        }
    }

    // ---- epilogue1: gelu -> cvt_pk bf16 pairs -> tB (own-wave rows only) ----
    #pragma unroll
    for (int ns = 0; ns < 2; ++ns) {
        int row = wv * 32 + ns * 16 + lane15;
        #pragma unroll
        for (int mt = 0; mt < 4; ++mt) {
            const float* bp = b1v + mt * 16 + quad * 4;
            float g[4];
            #pragma unroll
            for (int r = 0; r < 4; ++r) g[r] = gelu_f(acc[ns][mt][r] + bp[r]);
            int cp = (mt * 16 + quad * 4) >> 1;
            u.tB[row * 33 + cp]     = cvt_pk_bf16(g[0], g[1]);
            u.tB[row * 33 + cp + 1] = cvt_pk_bf16(g[2], g[3]);
            acc[ns][mt] = (f32x4){0.f, 0.f, 0.f, 0.f};
        }
    }

    // NO barrier: GEMM2 reads only this wave's own rows, written above.

    // ---- GEMM2: 2-term, weights at use ----
    #pragma unroll
    for (int kc = 0; kc < 2; ++kc) {
        union { unsigned int w[4]; short8 v; } cb0, cb1;
        int row0 = wv * 32 + lane15;
        int row1 = wv * 32 + 16 + lane15;
        #pragma unroll
        for (int i = 0; i < 4; ++i) {
            cb0.w[i] = u.tB[row0 * 33 + kc * 16 + quad * 4 + i];
            cb1.w[i] = u.tB[row1 * 33 + kc * 16 + quad * 4 + i];
        }
        #pragma unroll
        for (int mt = 0; mt < 4; ++mt) {
            int s8 = mt * 2 + kc;
            const short8* wp = (const short8*)(w2f + (((size_t)s8 * 64 + (t & 63)) << 4));
            short8 wh = wp[0], wl = wp[1];
            acc[0][mt] = MFMA16(wh, cb0.v, acc[0][mt]);
            acc[0][mt] = MFMA16(wl, cb0.v, acc[0][mt]);
            acc[1][mt] = MFMA16(wh, cb1.v, acc[1][mt]);
            acc[1][mt] = MFMA16(wl, cb1.v, acc[1][mt]);
        }
    }

    // ---- h residual load (latency hidden by epilogue2 VALU) ----
    uint4 hr[4];
    #pragma unroll
    for (int j = 0; j < 4; ++j) {
        int c = cg + 16 * j;
        hr[j] = *(const uint4*)(out + (size_t)c * NPIX + pixBase + oct * 8);
    }

    __syncthreads();   // all waves done reading tB; oTb scatter may begin

    // ---- epilogue2: gelu -> bf16 oTb (aliases tB) ----
    #pragma unroll
    for (int ns = 0; ns < 2; ++ns) {
        int px = wv * 32 + ns * 16 + lane15;
        #pragma unroll
        for (int mt = 0; mt < 4; ++mt) {
            const float* bp = b2v + mt * 16 + quad * 4;
            #pragma unroll
            for (int r = 0; r < 4; ++r) {
                int c = mt * 16 + quad * 4 + r;
                u.oTb[c * 136 + px] = bf16_rne1(gelu_f(acc[ns][mt][r] + bp[r]));
            }
        }
    }
    __syncthreads();

    if (!last) {
        // ---- h(bf16) += increment: (c,oct) units, uint4, full 256-B sectors/wave ----
        #pragma unroll
        for (int j = 0; j < 4; ++j) {
            int c = cg + 16 * j;
            uint4 gv = *(const uint4*)&u.oTb[c * 136 + oct * 8];
            unsigned int hw[4] = {hr[j].x, hr[j].y, hr[j].z, hr[j].w};
            unsigned int gw[4] = {gv.x, gv.y, gv.z, gv.w};
            uint4 o;
            unsigned int* op = &o.x;
            #pragma unroll
            for (int i = 0; i < 4; ++i) {
                float f0 = bf16_tof((unsigned short)(hw[i] & 0xffffu)) + bf16_tof((unsigned short)(gw[i] & 0xffffu));
                float f1 = bf16_tof((unsigned short)(hw[i] >> 16))     + bf16_tof((unsigned short)(gw[i] >> 16));
                op[i] = cvt_pk_bf16(f0, f1);
            }
            *(uint4*)(out + (size_t)c * NPIX + pixBase + oct * 8) = o;
        }
    } else {
        // ---- fused decoder: dout = sum_c Wd[c]*(hres+gv) + bd ----
        float part[8] = {0.f,0.f,0.f,0.f,0.f,0.f,0.f,0.f};
        #pragma unroll
        for (int j = 0; j < 4; ++j) {
            int c = cg + 16 * j;
            float wd = Wd[c];
            uint4 gv = *(const uint4*)&u.oTb[c * 136 + oct * 8];
            unsigned int hw[4] = {hr[j].x, hr[j].y, hr[j].z, hr[j].w};
            unsigned int gw[4] = {gv.x, gv.y, gv.z, gv.w};
            #pragma unroll
            for (int i = 0; i < 4; ++i) {
                part[2*i]   += wd * (bf16_tof((unsigned short)(hw[i] & 0xffffu)) + bf16_tof((unsigned short)(gw[i] & 0xffffu)));
                part[2*i+1] += wd * (bf16_tof((unsigned short)(hw[i] >> 16))     + bf16_tof((unsigned short)(gw[i] >> 16)));
            }
        }
        __syncthreads();   // oTb reads done before red (aliases buffer) is written
        #pragma unroll
        for (int i = 0; i < 8; ++i)
            u.red[cg * 132 + oct * 8 + i] = part[i];
        __syncthreads();
        if (t < 128) {
            float sum = bd[0];
            #pragma unroll
            for (int gg = 0; gg < 16; ++gg)
                sum += u.red[gg * 132 + t];
            dout[pixBase + t] = sum;
        }
    }
}

extern "C" void kernel_launch(void* const* d_in, const int* in_sizes, int n_in,
                              void* d_out, int out_size, void* d_ws, size_t ws_size,
                              hipStream_t stream) {
    (void)in_sizes; (void)n_in; (void)out_size; (void)ws_size;
    const float* u   = (const float*)d_in[0];
    const float* xc  = (const float*)d_in[1];
    const float* We  = (const float*)d_in[2];
    const float* be  = (const float*)d_in[3];
    const float* W1  = (const float*)d_in[4];
    const float* b1  = (const float*)d_in[5];
    const float* W2  = (const float*)d_in[6];
    const float* b2  = (const float*)d_in[7];
    const float* Are = (const float*)d_in[8];
    const float* Aim = (const float*)d_in[9];
    const float* Wd  = (const float*)d_in[10];
    const float* bd  = (const float*)d_in[11];

    // workspace layout, ~93 MB used
    char* ws = (char*)d_ws;
    unsigned short* h = (unsigned short*)ws;                  // 32 MB (bf16) [ch][pix]
    unsigned short* s = (unsigned short*)(ws + (size_t)33554432); // 32 MB (bf16) [pix][ch]
    float* VfH = (float*)(ws + (size_t)67108864);             // 4 MB: [64][32][512]
    float* VfW = VfH + (size_t)1048576;                       // 4 MB
    unsigned int* VmH_hi = (unsigned int*)(VfW + 1048576);    // 2 MB plane
    unsigned int* VmH_lo = VmH_hi + 524288;                   // 2 MB
    unsigned int* VmW_hi = VmH_lo + 524288;                   // 2 MB
    unsigned int* VmW_lo = VmW_hi + 524288;                   // 2 MB
    short* FbB = (short*)(VmW_lo + 524288);                   // 64 KB
    short* GbF = FbB + 32768;                                 // 64 KB
    short* Am  = GbF + 32768;                                 // 6 MB
    short* Wpk = Am  + (size_t)65536 * 48;                    // 128 KB

    k_setup<<<1312, 256, 0, stream>>>(W1, W2, Are, Aim, u, xc, We, be,
                                      FbB, GbF, Wpk, Am, h);

    for (int l = 0; l < 4; ++l) {
        k_fwd<<<dim3(32, 8, 2), 256, 0, stream>>>(h, FbB, VfH, VfW);
        k_mix2<<<512, 256, 0, stream>>>(VfH, VfW, Am + (size_t)(l * 2) * ASLAB,
                                        VmH_hi, VmH_lo, VmW_hi, VmW_lo);
        k_inv<<<dim3(32, 32), 256, 0, stream>>>(VmW_hi, VmW_lo, VmH_hi, VmH_lo, GbF, s);
        k_ffn2m<<<2048, 256, 0, stream>>>(s, h,
                                          Wpk + (size_t)(l * 2 + 0) * 8192, b1 + (size_t)l * 64,
                                          Wpk + (size_t)(l * 2 + 1) * 8192, b2 + (size_t)l * 64,
                                          Wd, bd, (float*)d_out, (l == 3) ? 1 : 0);
    }
}